// Round 11
// baseline (967.380 us; speedup 1.0000x reference)
//
#include <hip/hip_runtime.h>
#include <math.h>

#define N_VARS 40000
#define FEAT 128
#define N_EDGES 200000
#define N_MSG (2*N_EDGES)
#define N_CONFP 100000
#define T_ITERS 3
#define EPSF 1e-5f

#define NB_CONF 782              // ceil(200000/256)
#define NB_LOSS 3517             // ceil(900000/256)
#define NB_STAT 157              // ceil(40000/256)
#define OUT_TOTAL 1120003
#define NCONF_SLOT 1120002       // sequential carve: 1+1+480000+600000+40000

typedef short short8 __attribute__((ext_vector_type(8)));
typedef float floatx4 __attribute__((ext_vector_type(4)));
typedef unsigned short ushort4v __attribute__((ext_vector_type(4)));

__device__ __forceinline__ float scrub0(float x){
  unsigned u = __float_as_uint(x);
  return ((u & 0x7F800000u) == 0x7F800000u) ? 0.f : x;
}
__device__ __forceinline__ unsigned short f2bf_rne(float x){
  unsigned u = __float_as_uint(x);
  u += 0x7FFFu + ((u >> 16) & 1u);
  return (unsigned short)(u >> 16);
}
__device__ __forceinline__ float bf2f(unsigned short h){
  return __uint_as_float(((unsigned)h) << 16);
}

__global__ __launch_bounds__(256) void k_zero_out(float* __restrict__ out, int n){
  int i = blockIdx.x*256 + threadIdx.x;
  if (i < n) out[i] = 0.f;
}
__global__ __launch_bounds__(256) void k_zero_agg(float4* __restrict__ p){
  p[blockIdx.x*256 + threadIdx.x] = make_float4(0.f,0.f,0.f,0.f);
}
__global__ __launch_bounds__(256) void k_zero_int(int* __restrict__ p, int n){
  int i = blockIdx.x*256 + threadIdx.x;
  if (i < n) p[i] = 0;
}

// ---- CSR build over message ids m in [0,2E): target = m<E ? idxL[m] : idxR[m-E]
__global__ __launch_bounds__(256) void k_hist(const int* __restrict__ idxL,
    const int* __restrict__ idxR, int* __restrict__ cnt){
  int m = blockIdx.x*256 + threadIdx.x;
  if (m < N_MSG){
    int t = (m < N_EDGES) ? idxL[m] : idxR[m - N_EDGES];
    atomicAdd(&cnt[t], 1);
  }
}
__global__ __launch_bounds__(256) void k_scan(const int* __restrict__ cnt,
    int* __restrict__ row_ptr, int* __restrict__ pos){
  const int tid = threadIdx.x;
  const int CH = (N_VARS + 255)/256;   // 157
  const int base = tid*CH;
  int s = 0;
  for (int i = 0; i < CH; ++i){
    int idx = base + i;
    if (idx < N_VARS) s += cnt[idx];
  }
  __shared__ int sh[256];
  __shared__ int off[256];
  sh[tid] = s;
  __syncthreads();
  if (tid == 0){
    int acc = 0;
    for (int i = 0; i < 256; ++i){ off[i] = acc; acc += sh[i]; }
  }
  __syncthreads();
  int acc = off[tid];
  for (int i = 0; i < CH; ++i){
    int idx = base + i;
    if (idx < N_VARS){
      int c = cnt[idx];
      row_ptr[idx] = acc;
      pos[idx] = acc;
      acc += c;
    }
  }
  if (tid == 255) row_ptr[N_VARS] = N_MSG;
}
__global__ __launch_bounds__(256) void k_fill(const int* __restrict__ idxL,
    const int* __restrict__ idxR, int* __restrict__ pos, int* __restrict__ elist){
  int m = blockIdx.x*256 + threadIdx.x;
  if (m < N_MSG){
    int t = (m < N_EDGES) ? idxL[m] : idxR[m - N_EDGES];
    int slot = atomicAdd(&pos[t], 1);
    elist[slot] = m;
  }
}

// ---- pack W2 (128x128 f32) into B-fragment-ordered bf16 (8 ntiles) ----
__global__ __launch_bounds__(256) void k_prep(const float* __restrict__ W2,
                                              unsigned short* __restrict__ W2pack){
  int gid = blockIdx.x*256 + threadIdx.x;   // 0..2047
  int lane = gid & 63;
  int ks = (gid >> 6) & 3;
  int ntg = gid >> 8;
  int kbase = ks*32 + (lane >> 4)*8;
  int n = ntg*16 + (lane & 15);
#pragma unroll
  for (int j = 0; j < 8; ++j)
    W2pack[gid*8 + j] = f2bf_rne(W2[(kbase + j)*FEAT + n]);
}
// ---- pack W1 (256x128 f32) into combined 128x256 B-fragment bf16 (16 ntiles) ----
__global__ __launch_bounds__(256) void k_prep_w1(const float* __restrict__ W1,
                                                 unsigned short* __restrict__ W1pack){
  int gid = blockIdx.x*256 + threadIdx.x;   // 0..4095
  int lane = gid & 63;
  int ks = (gid >> 6) & 3;
  int ntg = gid >> 8;                        // 0..15
  int kbase = ks*32 + (lane >> 4)*8;
  int n = ntg*16 + (lane & 15);
#pragma unroll
  for (int j = 0; j < 8; ++j){
    int k = kbase + j;
    float v = (n < 128) ? W1[k*FEAT + n] : W1[(128 + k)*FEAT + (n - 128)];
    W1pack[gid*8 + j] = f2bf_rne(v);
  }
}

// ---- PQ = x @ [W1top | W1bot] via MFMA bf16 -> bf16 store; x = f32 (t=0) or bf16 state ----
#define X_STRIDE 136
__global__ __launch_bounds__(256) void k_pq(const float* __restrict__ xf,
                                            const unsigned short* __restrict__ xb,
                                            int src_f32,
                                            const unsigned short* __restrict__ W1pack,
                                            unsigned short* __restrict__ PQb){
  __shared__ __align__(16) unsigned short Xbf[32*X_STRIDE];
  const int tid = threadIdx.x;
  const int row0 = blockIdx.x * 32;
  if (src_f32){
    const int c4 = (tid & 31)*4, g8 = tid >> 5;
#pragma unroll
    for (int r = 0; r < 4; ++r){
      int row = g8*4 + r;
      const float4 v = *(const float4*)&xf[(row0 + row)*FEAT + c4];
      ushort4v u;
      u.x = f2bf_rne(v.x); u.y = f2bf_rne(v.y);
      u.z = f2bf_rne(v.z); u.w = f2bf_rne(v.w);
      *(ushort4v*)&Xbf[row*X_STRIDE + c4] = u;
    }
  } else {
    const int c8 = (tid & 15)*8, g16 = tid >> 4;
#pragma unroll
    for (int r = 0; r < 2; ++r){
      int row = r*16 + g16;
      *(short8*)&Xbf[row*X_STRIDE + c8] = *(const short8*)&xb[(row0 + row)*FEAT + c8];
    }
  }
  __syncthreads();
  const int w = tid >> 6, lane = tid & 63;
  const int quad = lane >> 4, mcol = lane & 15;
#pragma unroll
  for (int mt = 0; mt < 2; ++mt){
    floatx4 a0 = {0.f,0.f,0.f,0.f};
    floatx4 a1 = {0.f,0.f,0.f,0.f};
    floatx4 a2 = {0.f,0.f,0.f,0.f};
    floatx4 a3 = {0.f,0.f,0.f,0.f};
#pragma unroll
    for (int ks = 0; ks < 4; ++ks){
      short8 a = *(const short8*)&Xbf[(mt*16 + mcol)*X_STRIDE + ks*32 + quad*8];
      const unsigned short* bp = W1pack + ((w*16 + ks)*64 + lane)*8;
      short8 b0 = *(const short8*)(bp);
      short8 b1 = *(const short8*)(bp + 2048);
      short8 b2 = *(const short8*)(bp + 4096);
      short8 b3 = *(const short8*)(bp + 6144);
      a0 = __builtin_amdgcn_mfma_f32_16x16x32_bf16(a, b0, a0, 0, 0, 0);
      a1 = __builtin_amdgcn_mfma_f32_16x16x32_bf16(a, b1, a1, 0, 0, 0);
      a2 = __builtin_amdgcn_mfma_f32_16x16x32_bf16(a, b2, a2, 0, 0, 0);
      a3 = __builtin_amdgcn_mfma_f32_16x16x32_bf16(a, b3, a3, 0, 0, 0);
    }
#pragma unroll
    for (int nt = 0; nt < 4; ++nt){
      floatx4 acc = (nt == 0) ? a0 : (nt == 1) ? a1 : (nt == 2) ? a2 : a3;
      int n = w*64 + nt*16 + mcol;
#pragma unroll
      for (int reg = 0; reg < 4; ++reg)
        PQb[(row0 + mt*16 + quad*4 + reg)*(2*FEAT) + n] = f2bf_rne(acc[reg]);
    }
  }
}

#define U_STRIDE 136   // bf16 elems
#define Z_STRIDE 132   // f32 elems

// ================= shared edge-MLP body (macro to keep both variants in sync) ======
#define EDGE_BODY_PROLOG() \
  __shared__ __align__(16) unsigned char smem[32*Z_STRIDE*4]; \
  unsigned short* Ubf = (unsigned short*)smem; \
  float* sZ = (float*)smem; \
  __shared__ int sTa[32], sTb[32]; \
  const int tid = threadIdx.x; \
  const int m0 = blockIdx.x * 32; \
  if (tid < 32){ \
    int m = m0 + tid; \
    int e = (m < N_EDGES) ? m : (m - N_EDGES); \
    int l = idxL[e], r = idxR[e]; \
    sTa[tid] = (m < N_EDGES) ? l : r; \
    sTb[tid] = (m < N_EDGES) ? r : l; \
  } \
  __syncthreads(); \
  { \
    const int c8 = (tid & 15)*8, g16 = tid >> 4; \
    const float4 b1a = *(const float4*)&b1v[c8]; \
    const float4 b1b = *(const float4*)&b1v[c8 + 4]; \
    _Pragma("unroll") \
    for (int r = 0; r < 2; ++r){ \
      int row = r*16 + g16; \
      short8 pb = *(const short8*)&PQb[sTb[row]*(2*FEAT) + c8]; \
      short8 qb = *(const short8*)&PQb[sTa[row]*(2*FEAT) + FEAT + c8]; \
      ushort4v u0, u1; \
      u0.x = f2bf_rne(fmaxf(bf2f(pb[0]) + bf2f(qb[0]) + b1a.x, 0.f)); \
      u0.y = f2bf_rne(fmaxf(bf2f(pb[1]) + bf2f(qb[1]) + b1a.y, 0.f)); \
      u0.z = f2bf_rne(fmaxf(bf2f(pb[2]) + bf2f(qb[2]) + b1a.z, 0.f)); \
      u0.w = f2bf_rne(fmaxf(bf2f(pb[3]) + bf2f(qb[3]) + b1a.w, 0.f)); \
      u1.x = f2bf_rne(fmaxf(bf2f(pb[4]) + bf2f(qb[4]) + b1b.x, 0.f)); \
      u1.y = f2bf_rne(fmaxf(bf2f(pb[5]) + bf2f(qb[5]) + b1b.y, 0.f)); \
      u1.z = f2bf_rne(fmaxf(bf2f(pb[6]) + bf2f(qb[6]) + b1b.z, 0.f)); \
      u1.w = f2bf_rne(fmaxf(bf2f(pb[7]) + bf2f(qb[7]) + b1b.w, 0.f)); \
      *(ushort4v*)&Ubf[row*U_STRIDE + c8]     = u0; \
      *(ushort4v*)&Ubf[row*U_STRIDE + c8 + 4] = u1; \
    } \
  } \
  __syncthreads(); \
  const int w = tid >> 6, lane = tid & 63; \
  const int mt = w & 1, nhalf = w >> 1; \
  const int quad = lane >> 4, mcol = lane & 15; \
  floatx4 acc0 = {0.f,0.f,0.f,0.f}; \
  floatx4 acc1 = {0.f,0.f,0.f,0.f}; \
  floatx4 acc2 = {0.f,0.f,0.f,0.f}; \
  floatx4 acc3 = {0.f,0.f,0.f,0.f}; \
  _Pragma("unroll") \
  for (int ks = 0; ks < 4; ++ks){ \
    short8 a = *(const short8*)&Ubf[(mt*16 + mcol)*U_STRIDE + ks*32 + quad*8]; \
    const unsigned short* bp = W2pack + ((nhalf*4*256) + ks*64 + lane)*8; \
    short8 bq0 = *(const short8*)(bp); \
    short8 bq1 = *(const short8*)(bp + 2048); \
    short8 bq2 = *(const short8*)(bp + 4096); \
    short8 bq3 = *(const short8*)(bp + 6144); \
    acc0 = __builtin_amdgcn_mfma_f32_16x16x32_bf16(a, bq0, acc0, 0, 0, 0); \
    acc1 = __builtin_amdgcn_mfma_f32_16x16x32_bf16(a, bq1, acc1, 0, 0, 0); \
    acc2 = __builtin_amdgcn_mfma_f32_16x16x32_bf16(a, bq2, acc2, 0, 0, 0); \
    acc3 = __builtin_amdgcn_mfma_f32_16x16x32_bf16(a, bq3, acc3, 0, 0, 0); \
  } \
  __syncthreads(); \
  _Pragma("unroll") \
  for (int nt = 0; nt < 4; ++nt){ \
    floatx4 a4 = (nt == 0) ? acc0 : (nt == 1) ? acc1 : (nt == 2) ? acc2 : acc3; \
    int n = nhalf*64 + nt*16 + mcol; \
    float bb = b2v[n]; \
    _Pragma("unroll") \
    for (int reg = 0; reg < 4; ++reg){ \
      int row = mt*16 + quad*4 + reg; \
      sZ[row*Z_STRIDE + n] = fmaxf(a4[reg] + bb, 0.f); \
    } \
  } \
  __syncthreads();

// ---- fallback: edge MLP + LN + atomic scatter ----
__global__ __launch_bounds__(256) void k_edge(const unsigned short* __restrict__ PQb,
    const unsigned short* __restrict__ W2pack, const float* __restrict__ b1v,
    const float* __restrict__ b2v, const float* __restrict__ ln_g, const float* __restrict__ ln_b,
    const int* __restrict__ idxL, const int* __restrict__ idxR,
    float* __restrict__ agg){
  EDGE_BODY_PROLOG()
  const int wv = tid >> 6, l = tid & 63;
  const float g0 = ln_g[l],  g1 = ln_g[l+64];
  const float be0 = ln_b[l], be1 = ln_b[l+64];
#pragma unroll
  for (int r8 = 0; r8 < 8; ++r8){
    int r = wv*8 + r8;
    float v0 = sZ[r*Z_STRIDE + l], v1 = sZ[r*Z_STRIDE + l + 64];
    float s = v0 + v1, q = v0*v0 + v1*v1;
#pragma unroll
    for (int o = 32; o > 0; o >>= 1){ s += __shfl_xor(s, o); q += __shfl_xor(q, o); }
    float mu = s * (1.f/FEAT);
    float var = fmaxf(q * (1.f/FEAT) - mu*mu, 0.f);
    float rv = rsqrtf(var + EPSF);
    int a = sTa[r];
    float o0 = scrub0(g0*(v0-mu)*rv + be0);
    float o1 = scrub0(g1*(v1-mu)*rv + be1);
    atomicAdd(&agg[a*FEAT + l],      o0);
    atomicAdd(&agg[a*FEAT + l + 64], o1);
  }
}

// ---- CSR phase 1: edge MLP + LN -> streaming bf16 msg store (no atomics) ----
__global__ __launch_bounds__(256) void k_msg(const unsigned short* __restrict__ PQb,
    const unsigned short* __restrict__ W2pack, const float* __restrict__ b1v,
    const float* __restrict__ b2v, const float* __restrict__ ln_g, const float* __restrict__ ln_b,
    const int* __restrict__ idxL, const int* __restrict__ idxR,
    unsigned short* __restrict__ msg){
  EDGE_BODY_PROLOG()
  const int wv = tid >> 6, l = tid & 63;
  const float g0 = ln_g[l],  g1 = ln_g[l+64];
  const float be0 = ln_b[l], be1 = ln_b[l+64];
#pragma unroll
  for (int r8 = 0; r8 < 8; ++r8){
    int r = wv*8 + r8;
    float v0 = sZ[r*Z_STRIDE + l], v1 = sZ[r*Z_STRIDE + l + 64];
    float s = v0 + v1, q = v0*v0 + v1*v1;
#pragma unroll
    for (int o = 32; o > 0; o >>= 1){ s += __shfl_xor(s, o); q += __shfl_xor(q, o); }
    float mu = s * (1.f/FEAT);
    float var = fmaxf(q * (1.f/FEAT) - mu*mu, 0.f);
    float rv = rsqrtf(var + EPSF);
    int m = m0 + r;
    float o0 = scrub0(g0*(v0-mu)*rv + be0);
    float o1 = scrub0(g1*(v1-mu)*rv + be1);
    msg[(size_t)m*FEAT + l]      = f2bf_rne(o0);
    msg[(size_t)m*FEAT + l + 64] = f2bf_rne(o1);
  }
}

// ---- CSR phase 2: per-node gather of msg rows, fp32 accumulate -> rec = sum/deg ----
__global__ __launch_bounds__(256) void k_gather(const unsigned short* __restrict__ msg,
    const int* __restrict__ row_ptr, const int* __restrict__ elist,
    const float* __restrict__ degrees, float* __restrict__ rec){
  const int n = blockIdx.x*2 + (threadIdx.x >> 7);
  const int j = threadIdx.x & 127;
  const int s0 = row_ptr[n], s1 = row_ptr[n+1];
  float acc = 0.f;
  for (int s = s0; s < s1; ++s){
    int m = elist[s];
    acc += bf2f(msg[(size_t)m*FEAT + j]);
  }
  rec[n*FEAT + j] = acc / degrees[n];
}

// ---- BN stats: per-block fp32 partials of rec (divide flag for fallback) ----
__global__ __launch_bounds__(256) void k_stats(const float* __restrict__ src,
    const float* __restrict__ degrees, int divide, float* __restrict__ red_part){
  const int tid = threadIdx.x;
  const int j = tid & 127, half_sel = tid >> 7;
  const int n0 = blockIdx.x * 256;
  float s1 = 0.f, s2 = 0.f;
  for (int i = half_sel; i < 256; i += 2){
    int n = n0 + i;
    if (n < N_VARS){
      float v = src[n*FEAT + j];
      if (divide) v /= degrees[n];
      s1 += v;
      s2 += v*v;
    }
  }
  __shared__ float sh1[256], sh2[256];
  sh1[tid] = s1; sh2[tid] = s2;
  __syncthreads();
  if (half_sel == 0){
    red_part[blockIdx.x*256 + j]       = sh1[tid] + sh1[tid+128];
    red_part[blockIdx.x*256 + 128 + j] = sh2[tid] + sh2[tid+128];
  }
}

// ---- reduce red_part -> red[256] (Kahan, single block, deterministic) ----
__global__ __launch_bounds__(256) void k_red(const float* __restrict__ red_part,
                                             float* __restrict__ red){
  const int tid = threadIdx.x;
  float s = 0.f, c = 0.f;
  for (int b = 0; b < NB_STAT; ++b){
    float y = red_part[b*256 + tid] - c;
    float t = s + y;
    c = (t - s) - y;
    s = t;
  }
  red[tid] = s;
}

// ---- BN apply + logits + softmax + argmax; one wave per row; bf16 state out ----
__global__ __launch_bounds__(256) void k_bn(const float* __restrict__ src,
    const float* __restrict__ degrees, int divide, const float* __restrict__ red,
    const float* __restrict__ bn_g, const float* __restrict__ bn_b,
    const float* __restrict__ Wd, const float* __restrict__ bd,
    unsigned short* __restrict__ state_bf, int* __restrict__ asg,
    float* __restrict__ out_phi, float* __restrict__ out_asg, int t){
  const int w = threadIdx.x >> 6, l = threadIdx.x & 63;
  const int n = blockIdx.x*4 + w;
  const float invN = 1.f / (float)N_VARS;
  float mu0 = red[l]*invN,     mu1 = red[l+64]*invN;
  float v0  = fmaxf(red[128+l]*invN    - mu0*mu0, 0.f);
  float v1  = fmaxf(red[128+l+64]*invN - mu1*mu1, 0.f);
  float rv0 = rsqrtf(v0 + EPSF);
  float rv1 = rsqrtf(v1 + EPSF);
  float dinv = divide ? (1.f / degrees[n]) : 1.f;
  float r0 = src[n*FEAT + l]    * dinv;
  float r1 = src[n*FEAT + l+64] * dinv;
  float s0 = scrub0(bn_g[l]   *(r0 - mu0)*rv0 + bn_b[l]);
  float s1 = scrub0(bn_g[l+64]*(r1 - mu1)*rv1 + bn_b[l+64]);
  state_bf[n*FEAT + l]    = f2bf_rne(s0);
  state_bf[n*FEAT + l+64] = f2bf_rne(s1);
  float p[4];
#pragma unroll
  for (int d = 0; d < 4; ++d)
    p[d] = s0*Wd[l*4 + d] + s1*Wd[(l+64)*4 + d];
#pragma unroll
  for (int o = 32; o > 0; o >>= 1){
#pragma unroll
    for (int d = 0; d < 4; ++d) p[d] += __shfl_xor(p[d], o);
  }
  if (l == 0){
    float lg[4];
#pragma unroll
    for (int d = 0; d < 4; ++d) lg[d] = scrub0(p[d] + bd[d]);
    float mx = fmaxf(fmaxf(lg[0],lg[1]), fmaxf(lg[2],lg[3]));
    float ex[4]; float ssum = 0.f;
#pragma unroll
    for (int d = 0; d < 4; ++d){ ex[d] = expf(lg[d] - mx); ssum += ex[d]; }
    float inv = 1.f / ssum;
    int am = 0; float bv = -1.f;
#pragma unroll
    for (int d = 0; d < 4; ++d){
      float pv = scrub0(ex[d]*inv);
      out_phi[n*12 + t*4 + d] = pv;
      if (pv > bv){ bv = pv; am = d; }
    }
    asg[n*3 + t] = am;
    if (t == 2) out_asg[n] = (float)am;
  }
}

// ---- edge conflicts -> out_ec + per-block partial of t=2 column ----
__global__ __launch_bounds__(256) void k_conf(const int* __restrict__ asg,
    const int* __restrict__ idxL, const int* __restrict__ idxR,
    const float* __restrict__ relation, float* __restrict__ out_ec,
    float* __restrict__ part_conf){
  const int e = blockIdx.x*256 + threadIdx.x;
  float c2 = 0.f;
  if (e < N_EDGES){
    int l = idxL[e], r = idxR[e];
#pragma unroll
    for (int tt = 0; tt < 3; ++tt){
      int ai = asg[l*3+tt] & 3, bi = asg[r*3+tt] & 3;
      float c = scrub0(1.f - relation[ai*4 + bi]);
      out_ec[e*3 + tt] = c;
      if (tt == 2) c2 = c;
    }
  }
  __shared__ float sh[256];
  sh[threadIdx.x] = c2;
  __syncthreads();
  for (int k = 128; k > 0; k >>= 1){
    if (threadIdx.x < k) sh[threadIdx.x] += sh[threadIdx.x + k];
    __syncthreads();
  }
  if (threadIdx.x == 0) part_conf[blockIdx.x] = sh[0];
}

__global__ __launch_bounds__(256) void k_fconf(const float* __restrict__ part_conf,
                                               float* __restrict__ out){
  const int tid = threadIdx.x;
  float s = 0.f;
  for (int i = tid; i < NB_CONF; i += 256) s += part_conf[i];
  __shared__ float sh[256];
  sh[tid] = s;
  __syncthreads();
  for (int k = 128; k > 0; k >>= 1){
    if (tid < k) sh[tid] += sh[tid + k];
    __syncthreads();
  }
  if (tid == 0){
    float nc = sh[0];
    out[NCONF_SLOT] = nc;
    out[1] = nc / (float)N_EDGES;
  }
}

// ---- pair losses from fp32 phi (in d_out): per-block partials ----
__global__ __launch_bounds__(256) void k_loss(const float* __restrict__ phi,
    const int* __restrict__ iL, const int* __restrict__ iR,
    const int* __restrict__ iLp, const int* __restrict__ iRp,
    const float* __restrict__ rel, const float* __restrict__ conf,
    float* __restrict__ part_l1, float* __restrict__ part_l2){
  const int m = blockIdx.x*256 + threadIdx.x;
  float p1 = 0.f, p2 = 0.f;
  if (m < N_EDGES*3){
    int e = m/3, tt = m - e*3;
    const float* pl = phi + iL[e]*12 + tt*4;
    const float* pr = phi + iR[e]*12 + tt*4;
    float s = 0.f;
#pragma unroll
    for (int j = 0; j < 4; ++j){
      float tj = 0.f;
#pragma unroll
      for (int i = 0; i < 4; ++i) tj += pl[i]*rel[i*4+j];
      s += tj*pr[j];
    }
    s = scrub0(s); s = fmaxf(s, 1e-35f);
    p1 = -logf(s);
  } else {
    int m2 = m - N_EDGES*3;
    if (m2 < N_CONFP*3){
      int e = m2/3, tt = m2 - e*3;
      const float* pl = phi + iLp[e]*12 + tt*4;
      const float* pr = phi + iRp[e]*12 + tt*4;
      float s = 0.f;
#pragma unroll
      for (int j = 0; j < 4; ++j){
        float tj = 0.f;
#pragma unroll
        for (int i = 0; i < 4; ++i) tj += pl[i]*conf[i*4+j];
        s += tj*pr[j];
      }
      s = scrub0(s); s = fmaxf(s, 1e-35f);
      p2 = -logf(s);
    }
  }
  __shared__ float sh1[256], sh2[256];
  sh1[threadIdx.x] = p1; sh2[threadIdx.x] = p2;
  __syncthreads();
  for (int k = 128; k > 0; k >>= 1){
    if (threadIdx.x < k){
      sh1[threadIdx.x] += sh1[threadIdx.x + k];
      sh2[threadIdx.x] += sh2[threadIdx.x + k];
    }
    __syncthreads();
  }
  if (threadIdx.x == 0){
    part_l1[blockIdx.x] = sh1[0];
    part_l2[blockIdx.x] = sh2[0];
  }
}

__global__ __launch_bounds__(256) void k_floss(const float* __restrict__ part_l1,
    const float* __restrict__ part_l2, float* __restrict__ out){
  const int tid = threadIdx.x;
  float a = 0.f, ca = 0.f, b = 0.f, cb = 0.f;
  for (int i = tid; i < NB_LOSS; i += 256){
    float y = part_l1[i] - ca; float t = a + y; ca = (t - a) - y; a = t;
    float y2 = part_l2[i] - cb; float t2 = b + y2; cb = (t2 - b) - y2; b = t2;
  }
  __shared__ float sh1[256], sh2[256];
  sh1[tid] = a; sh2[tid] = b;
  __syncthreads();
  for (int k = 128; k > 0; k >>= 1){
    if (tid < k){ sh1[tid] += sh1[tid + k]; sh2[tid] += sh2[tid + k]; }
    __syncthreads();
  }
  if (tid == 0)
    out[0] = sh1[0]/(float)N_EDGES + sh2[0]/(10.f*(float)N_CONFP);
}

extern "C" void kernel_launch(void* const* d_in, const int* in_sizes, int n_in,
                              void* d_out, int out_size, void* d_ws, size_t ws_size,
                              hipStream_t stream){
  const float* state0  = (const float*)d_in[0];
  const float* W1      = (const float*)d_in[1];
  const float* b1v     = (const float*)d_in[2];
  const float* W2      = (const float*)d_in[3];
  const float* b2v     = (const float*)d_in[4];
  const float* ln_g    = (const float*)d_in[5];
  const float* ln_b    = (const float*)d_in[6];
  const float* bn_g    = (const float*)d_in[7];
  const float* bn_b    = (const float*)d_in[8];
  const float* Wd      = (const float*)d_in[9];
  const float* bd      = (const float*)d_in[10];
  const float* rel     = (const float*)d_in[11];
  const float* confm   = (const float*)d_in[12];
  const float* degrees = (const float*)d_in[13];
  const int* idxL = (const int*)d_in[14];
  const int* idxR = (const int*)d_in[15];
  const int* iLp  = (const int*)d_in[16];
  const int* iRp  = (const int*)d_in[17];

  char* ws = (char*)d_ws;
  unsigned short* state_bf = (unsigned short*)(ws);          // 10,240,000
  unsigned short* PQb  = (unsigned short*)(ws + 10240000);   // 20,480,000
  float*  recagg    = (float*)(ws + 30720000);               // 20,480,000 (rec or agg)
  int*    asg       = (int*)  (ws + 51200000);               //    480,000
  float*  red_part  = (float*)(ws + 51680000);               //    160,768
  float*  red       = (float*)(ws + 51840768);               //      1,024
  float*  part_l1   = (float*)(ws + 51841792);               //     14,068
  float*  part_l2   = (float*)(ws + 51855860);               //     14,068
  float*  part_conf = (float*)(ws + 51869928);               //      3,128
  unsigned short* W2pack = (unsigned short*)(ws + 51873056); //     32,768
  unsigned short* W1pack = (unsigned short*)(ws + 51905824); //     65,536
  // CSR extension (only touched when ws_size is big enough)
  int*    row_ptr   = (int*)(ws + 51971360);                 //    160,016
  int*    pos       = (int*)(ws + 52131376);                 //    160,000
  int*    elist     = (int*)(ws + 52291376);                 //  1,600,000
  int*    cnt       = (int*)(ws + 53891376);                 //    160,000
  unsigned short* msg = (unsigned short*)(ws + 54051376);    // 102,400,000
  const int use_csr = (ws_size >= (size_t)156451376) ? 1 : 0;

  float* out     = (float*)d_out;
  float* out_phi = out + 2;
  float* out_ec  = out + 480002;
  float* out_asg = out + 1080002;

  k_zero_out<<<(OUT_TOTAL + 255)/256, 256, 0, stream>>>(out, OUT_TOTAL);
  k_prep<<<8, 256, 0, stream>>>(W2, W2pack);
  k_prep_w1<<<16, 256, 0, stream>>>(W1, W1pack);

  if (use_csr){
    k_zero_int<<<NB_STAT, 256, 0, stream>>>(cnt, N_VARS);
    k_hist<<<(N_MSG + 255)/256, 256, 0, stream>>>(idxL, idxR, cnt);
    k_scan<<<1, 256, 0, stream>>>(cnt, row_ptr, pos);
    k_fill<<<(N_MSG + 255)/256, 256, 0, stream>>>(idxL, idxR, pos, elist);
  }

  for (int t = 0; t < T_ITERS; ++t){
    k_pq<<<N_VARS/32, 256, 0, stream>>>(state0, state_bf, (t == 0) ? 1 : 0, W1pack, PQb);
    if (use_csr){
      k_msg<<<N_MSG/32, 256, 0, stream>>>(PQb, W2pack, b1v, b2v, ln_g, ln_b, idxL, idxR, msg);
      k_gather<<<N_VARS/2, 256, 0, stream>>>(msg, row_ptr, elist, degrees, recagg);
      k_stats<<<NB_STAT, 256, 0, stream>>>(recagg, degrees, 0, red_part);
    } else {
      k_zero_agg<<<5000, 256, 0, stream>>>((float4*)recagg);
      k_edge<<<N_MSG/32, 256, 0, stream>>>(PQb, W2pack, b1v, b2v, ln_g, ln_b, idxL, idxR, recagg);
      k_stats<<<NB_STAT, 256, 0, stream>>>(recagg, degrees, 1, red_part);
    }
    k_red<<<1, 256, 0, stream>>>(red_part, red);
    k_bn<<<N_VARS/4, 256, 0, stream>>>(recagg, degrees, use_csr ? 0 : 1, red, bn_g, bn_b, Wd, bd,
                                       state_bf, asg, out_phi, out_asg, t);
  }
  k_conf<<<NB_CONF, 256, 0, stream>>>(asg, idxL, idxR, rel, out_ec, part_conf);
  k_fconf<<<1, 256, 0, stream>>>(part_conf, out);
  k_loss<<<NB_LOSS, 256, 0, stream>>>(out_phi, idxL, idxR, iLp, iRp, rel, confm, part_l1, part_l2);
  k_floss<<<1, 256, 0, stream>>>(part_l1, part_l2, out);
}

// Round 12
// 771.312 us; speedup vs baseline: 1.2542x; 1.2542x over previous
//
#include <hip/hip_runtime.h>
#include <math.h>

#define N_VARS 40000
#define FEAT 128
#define N_EDGES 200000
#define N_MSG (2*N_EDGES)
#define N_CONFP 100000
#define T_ITERS 3
#define EPSF 1e-5f

#define NB_CONF 782              // ceil(200000/256)
#define NB_LOSS 3517             // ceil(900000/256)
#define NB_STAT 157              // ceil(40000/256)
#define OUT_TOTAL 1120003
#define NCONF_SLOT 1120002       // sequential carve: 1+1+480000+600000+40000

typedef short short8 __attribute__((ext_vector_type(8)));
typedef float floatx4 __attribute__((ext_vector_type(4)));
typedef unsigned short ushort4v __attribute__((ext_vector_type(4)));

__device__ __forceinline__ float scrub0(float x){
  unsigned u = __float_as_uint(x);
  return ((u & 0x7F800000u) == 0x7F800000u) ? 0.f : x;
}
__device__ __forceinline__ unsigned short f2bf_rne(float x){
  unsigned u = __float_as_uint(x);
  u += 0x7FFFu + ((u >> 16) & 1u);
  return (unsigned short)(u >> 16);
}
__device__ __forceinline__ float bf2f(unsigned short h){
  return __uint_as_float(((unsigned)h) << 16);
}

__global__ __launch_bounds__(256) void k_zero_out(float* __restrict__ out, int n){
  int i = blockIdx.x*256 + threadIdx.x;
  if (i < n) out[i] = 0.f;
}
__global__ __launch_bounds__(256) void k_zero_agg(float4* __restrict__ p){
  p[blockIdx.x*256 + threadIdx.x] = make_float4(0.f,0.f,0.f,0.f);
}
__global__ __launch_bounds__(256) void k_zero_int(int* __restrict__ p, int n){
  int i = blockIdx.x*256 + threadIdx.x;
  if (i < n) p[i] = 0;
}

// ---- CSR build over message ids m in [0,2E): target = m<E ? idxL[m] : idxR[m-E]
__global__ __launch_bounds__(256) void k_hist(const int* __restrict__ idxL,
    const int* __restrict__ idxR, int* __restrict__ cnt){
  int m = blockIdx.x*256 + threadIdx.x;
  if (m < N_MSG){
    int t = (m < N_EDGES) ? idxL[m] : idxR[m - N_EDGES];
    atomicAdd(&cnt[t], 1);
  }
}
// phase 1: per-block exclusive scan of cnt -> pos (local), block totals -> blk_tot
__global__ __launch_bounds__(256) void k_scan1(const int* __restrict__ cnt,
    int* __restrict__ pos, int* __restrict__ blk_tot){
  const int tid = threadIdx.x;
  const int idx = blockIdx.x*256 + tid;
  int v = (idx < N_VARS) ? cnt[idx] : 0;
  __shared__ int sh[256];
  sh[tid] = v;
  __syncthreads();
#pragma unroll
  for (int o = 1; o < 256; o <<= 1){
    int add = (tid >= o) ? sh[tid - o] : 0;
    __syncthreads();
    sh[tid] += add;
    __syncthreads();
  }
  if (idx < N_VARS) pos[idx] = sh[tid] - v;   // exclusive
  if (tid == 255) blk_tot[blockIdx.x] = sh[255];
}
// phase 2: exclusive scan of 157 block totals (single block)
__global__ __launch_bounds__(256) void k_scan2(const int* __restrict__ blk_tot,
    int* __restrict__ blk_off){
  const int tid = threadIdx.x;
  int v = (tid < NB_STAT) ? blk_tot[tid] : 0;
  __shared__ int sh[256];
  sh[tid] = v;
  __syncthreads();
#pragma unroll
  for (int o = 1; o < 256; o <<= 1){
    int add = (tid >= o) ? sh[tid - o] : 0;
    __syncthreads();
    sh[tid] += add;
    __syncthreads();
  }
  if (tid < NB_STAT) blk_off[tid] = sh[tid] - v;
}
// phase 3: add block offsets in place
__global__ __launch_bounds__(256) void k_scan3(int* __restrict__ pos,
    const int* __restrict__ blk_off){
  const int idx = blockIdx.x*256 + threadIdx.x;
  if (idx < N_VARS) pos[idx] += blk_off[blockIdx.x];
}
// fill: mslot[m] = CSR slot; post-fill pos[n] = end of span n
__global__ __launch_bounds__(256) void k_fill(const int* __restrict__ idxL,
    const int* __restrict__ idxR, int* __restrict__ pos, int* __restrict__ mslot){
  int m = blockIdx.x*256 + threadIdx.x;
  if (m < N_MSG){
    int t = (m < N_EDGES) ? idxL[m] : idxR[m - N_EDGES];
    mslot[m] = atomicAdd(&pos[t], 1);
  }
}

// ---- pack W2 (128x128 f32) into B-fragment-ordered bf16 (8 ntiles) ----
__global__ __launch_bounds__(256) void k_prep(const float* __restrict__ W2,
                                              unsigned short* __restrict__ W2pack){
  int gid = blockIdx.x*256 + threadIdx.x;   // 0..2047
  int lane = gid & 63;
  int ks = (gid >> 6) & 3;
  int ntg = gid >> 8;
  int kbase = ks*32 + (lane >> 4)*8;
  int n = ntg*16 + (lane & 15);
#pragma unroll
  for (int j = 0; j < 8; ++j)
    W2pack[gid*8 + j] = f2bf_rne(W2[(kbase + j)*FEAT + n]);
}
// ---- pack W1 (256x128 f32) into combined 128x256 B-fragment bf16 (16 ntiles) ----
__global__ __launch_bounds__(256) void k_prep_w1(const float* __restrict__ W1,
                                                 unsigned short* __restrict__ W1pack){
  int gid = blockIdx.x*256 + threadIdx.x;   // 0..4095
  int lane = gid & 63;
  int ks = (gid >> 6) & 3;
  int ntg = gid >> 8;                        // 0..15
  int kbase = ks*32 + (lane >> 4)*8;
  int n = ntg*16 + (lane & 15);
#pragma unroll
  for (int j = 0; j < 8; ++j){
    int k = kbase + j;
    float v = (n < 128) ? W1[k*FEAT + n] : W1[(128 + k)*FEAT + (n - 128)];
    W1pack[gid*8 + j] = f2bf_rne(v);
  }
}

// ---- PQ = x @ [W1top | W1bot] via MFMA bf16 -> bf16 store ----
#define X_STRIDE 136
__global__ __launch_bounds__(256) void k_pq(const float* __restrict__ xf,
                                            const unsigned short* __restrict__ xb,
                                            int src_f32,
                                            const unsigned short* __restrict__ W1pack,
                                            unsigned short* __restrict__ PQb){
  __shared__ __align__(16) unsigned short Xbf[32*X_STRIDE];
  const int tid = threadIdx.x;
  const int row0 = blockIdx.x * 32;
  if (src_f32){
    const int c4 = (tid & 31)*4, g8 = tid >> 5;
#pragma unroll
    for (int r = 0; r < 4; ++r){
      int row = g8*4 + r;
      const float4 v = *(const float4*)&xf[(row0 + row)*FEAT + c4];
      ushort4v u;
      u.x = f2bf_rne(v.x); u.y = f2bf_rne(v.y);
      u.z = f2bf_rne(v.z); u.w = f2bf_rne(v.w);
      *(ushort4v*)&Xbf[row*X_STRIDE + c4] = u;
    }
  } else {
    const int c8 = (tid & 15)*8, g16 = tid >> 4;
#pragma unroll
    for (int r = 0; r < 2; ++r){
      int row = r*16 + g16;
      *(short8*)&Xbf[row*X_STRIDE + c8] = *(const short8*)&xb[(row0 + row)*FEAT + c8];
    }
  }
  __syncthreads();
  const int w = tid >> 6, lane = tid & 63;
  const int quad = lane >> 4, mcol = lane & 15;
#pragma unroll
  for (int mt = 0; mt < 2; ++mt){
    floatx4 a0 = {0.f,0.f,0.f,0.f};
    floatx4 a1 = {0.f,0.f,0.f,0.f};
    floatx4 a2 = {0.f,0.f,0.f,0.f};
    floatx4 a3 = {0.f,0.f,0.f,0.f};
#pragma unroll
    for (int ks = 0; ks < 4; ++ks){
      short8 a = *(const short8*)&Xbf[(mt*16 + mcol)*X_STRIDE + ks*32 + quad*8];
      const unsigned short* bp = W1pack + ((w*16 + ks)*64 + lane)*8;
      short8 b0 = *(const short8*)(bp);
      short8 b1 = *(const short8*)(bp + 2048);
      short8 b2 = *(const short8*)(bp + 4096);
      short8 b3 = *(const short8*)(bp + 6144);
      a0 = __builtin_amdgcn_mfma_f32_16x16x32_bf16(a, b0, a0, 0, 0, 0);
      a1 = __builtin_amdgcn_mfma_f32_16x16x32_bf16(a, b1, a1, 0, 0, 0);
      a2 = __builtin_amdgcn_mfma_f32_16x16x32_bf16(a, b2, a2, 0, 0, 0);
      a3 = __builtin_amdgcn_mfma_f32_16x16x32_bf16(a, b3, a3, 0, 0, 0);
    }
#pragma unroll
    for (int nt = 0; nt < 4; ++nt){
      floatx4 acc = (nt == 0) ? a0 : (nt == 1) ? a1 : (nt == 2) ? a2 : a3;
      int n = w*64 + nt*16 + mcol;
#pragma unroll
      for (int reg = 0; reg < 4; ++reg)
        PQb[(row0 + mt*16 + quad*4 + reg)*(2*FEAT) + n] = f2bf_rne(acc[reg]);
    }
  }
}

#define U_STRIDE 136   // bf16 elems
#define Z_STRIDE 132   // f32 elems

#define EDGE_BODY_PROLOG() \
  __shared__ __align__(16) unsigned char smem[32*Z_STRIDE*4]; \
  unsigned short* Ubf = (unsigned short*)smem; \
  float* sZ = (float*)smem; \
  __shared__ int sTa[32], sTb[32]; \
  const int tid = threadIdx.x; \
  const int m0 = blockIdx.x * 32; \
  if (tid < 32){ \
    int m = m0 + tid; \
    int e = (m < N_EDGES) ? m : (m - N_EDGES); \
    int l = idxL[e], r = idxR[e]; \
    sTa[tid] = (m < N_EDGES) ? l : r; \
    sTb[tid] = (m < N_EDGES) ? r : l; \
  } \
  __syncthreads(); \
  { \
    const int c8 = (tid & 15)*8, g16 = tid >> 4; \
    const float4 b1a = *(const float4*)&b1v[c8]; \
    const float4 b1b = *(const float4*)&b1v[c8 + 4]; \
    _Pragma("unroll") \
    for (int r = 0; r < 2; ++r){ \
      int row = r*16 + g16; \
      short8 pb = *(const short8*)&PQb[sTb[row]*(2*FEAT) + c8]; \
      short8 qb = *(const short8*)&PQb[sTa[row]*(2*FEAT) + FEAT + c8]; \
      ushort4v u0, u1; \
      u0.x = f2bf_rne(fmaxf(bf2f(pb[0]) + bf2f(qb[0]) + b1a.x, 0.f)); \
      u0.y = f2bf_rne(fmaxf(bf2f(pb[1]) + bf2f(qb[1]) + b1a.y, 0.f)); \
      u0.z = f2bf_rne(fmaxf(bf2f(pb[2]) + bf2f(qb[2]) + b1a.z, 0.f)); \
      u0.w = f2bf_rne(fmaxf(bf2f(pb[3]) + bf2f(qb[3]) + b1a.w, 0.f)); \
      u1.x = f2bf_rne(fmaxf(bf2f(pb[4]) + bf2f(qb[4]) + b1b.x, 0.f)); \
      u1.y = f2bf_rne(fmaxf(bf2f(pb[5]) + bf2f(qb[5]) + b1b.y, 0.f)); \
      u1.z = f2bf_rne(fmaxf(bf2f(pb[6]) + bf2f(qb[6]) + b1b.z, 0.f)); \
      u1.w = f2bf_rne(fmaxf(bf2f(pb[7]) + bf2f(qb[7]) + b1b.w, 0.f)); \
      *(ushort4v*)&Ubf[row*U_STRIDE + c8]     = u0; \
      *(ushort4v*)&Ubf[row*U_STRIDE + c8 + 4] = u1; \
    } \
  } \
  __syncthreads(); \
  const int w = tid >> 6, lane = tid & 63; \
  const int mt = w & 1, nhalf = w >> 1; \
  const int quad = lane >> 4, mcol = lane & 15; \
  floatx4 acc0 = {0.f,0.f,0.f,0.f}; \
  floatx4 acc1 = {0.f,0.f,0.f,0.f}; \
  floatx4 acc2 = {0.f,0.f,0.f,0.f}; \
  floatx4 acc3 = {0.f,0.f,0.f,0.f}; \
  _Pragma("unroll") \
  for (int ks = 0; ks < 4; ++ks){ \
    short8 a = *(const short8*)&Ubf[(mt*16 + mcol)*U_STRIDE + ks*32 + quad*8]; \
    const unsigned short* bp = W2pack + ((nhalf*4*256) + ks*64 + lane)*8; \
    short8 bq0 = *(const short8*)(bp); \
    short8 bq1 = *(const short8*)(bp + 2048); \
    short8 bq2 = *(const short8*)(bp + 4096); \
    short8 bq3 = *(const short8*)(bp + 6144); \
    acc0 = __builtin_amdgcn_mfma_f32_16x16x32_bf16(a, bq0, acc0, 0, 0, 0); \
    acc1 = __builtin_amdgcn_mfma_f32_16x16x32_bf16(a, bq1, acc1, 0, 0, 0); \
    acc2 = __builtin_amdgcn_mfma_f32_16x16x32_bf16(a, bq2, acc2, 0, 0, 0); \
    acc3 = __builtin_amdgcn_mfma_f32_16x16x32_bf16(a, bq3, acc3, 0, 0, 0); \
  } \
  __syncthreads(); \
  _Pragma("unroll") \
  for (int nt = 0; nt < 4; ++nt){ \
    floatx4 a4 = (nt == 0) ? acc0 : (nt == 1) ? acc1 : (nt == 2) ? acc2 : acc3; \
    int n = nhalf*64 + nt*16 + mcol; \
    float bb = b2v[n]; \
    _Pragma("unroll") \
    for (int reg = 0; reg < 4; ++reg){ \
      int row = mt*16 + quad*4 + reg; \
      sZ[row*Z_STRIDE + n] = fmaxf(a4[reg] + bb, 0.f); \
    } \
  } \
  __syncthreads();

// ---- fallback: edge MLP + LN + atomic scatter ----
__global__ __launch_bounds__(256) void k_edge(const unsigned short* __restrict__ PQb,
    const unsigned short* __restrict__ W2pack, const float* __restrict__ b1v,
    const float* __restrict__ b2v, const float* __restrict__ ln_g, const float* __restrict__ ln_b,
    const int* __restrict__ idxL, const int* __restrict__ idxR,
    float* __restrict__ agg){
  EDGE_BODY_PROLOG()
  const int wv = tid >> 6, l = tid & 63;
  const float g0 = ln_g[l],  g1 = ln_g[l+64];
  const float be0 = ln_b[l], be1 = ln_b[l+64];
#pragma unroll
  for (int r8 = 0; r8 < 8; ++r8){
    int r = wv*8 + r8;
    float v0 = sZ[r*Z_STRIDE + l], v1 = sZ[r*Z_STRIDE + l + 64];
    float s = v0 + v1, q = v0*v0 + v1*v1;
#pragma unroll
    for (int o = 32; o > 0; o >>= 1){ s += __shfl_xor(s, o); q += __shfl_xor(q, o); }
    float mu = s * (1.f/FEAT);
    float var = fmaxf(q * (1.f/FEAT) - mu*mu, 0.f);
    float rv = rsqrtf(var + EPSF);
    int a = sTa[r];
    float o0 = scrub0(g0*(v0-mu)*rv + be0);
    float o1 = scrub0(g1*(v1-mu)*rv + be1);
    atomicAdd(&agg[a*FEAT + l],      o0);
    atomicAdd(&agg[a*FEAT + l + 64], o1);
  }
}

// ---- CSR phase 1: edge MLP + LN -> slot-ordered bf16 msg store (no atomics) ----
__global__ __launch_bounds__(256) void k_msg(const unsigned short* __restrict__ PQb,
    const unsigned short* __restrict__ W2pack, const float* __restrict__ b1v,
    const float* __restrict__ b2v, const float* __restrict__ ln_g, const float* __restrict__ ln_b,
    const int* __restrict__ idxL, const int* __restrict__ idxR,
    const int* __restrict__ mslot, unsigned short* __restrict__ msg){
  EDGE_BODY_PROLOG()
  const int wv = tid >> 6, l = tid & 63;
  const float g0 = ln_g[l],  g1 = ln_g[l+64];
  const float be0 = ln_b[l], be1 = ln_b[l+64];
#pragma unroll
  for (int r8 = 0; r8 < 8; ++r8){
    int r = wv*8 + r8;
    float v0 = sZ[r*Z_STRIDE + l], v1 = sZ[r*Z_STRIDE + l + 64];
    float s = v0 + v1, q = v0*v0 + v1*v1;
#pragma unroll
    for (int o = 32; o > 0; o >>= 1){ s += __shfl_xor(s, o); q += __shfl_xor(q, o); }
    float mu = s * (1.f/FEAT);
    float var = fmaxf(q * (1.f/FEAT) - mu*mu, 0.f);
    float rv = rsqrtf(var + EPSF);
    int slot = mslot[m0 + r];
    float o0 = scrub0(g0*(v0-mu)*rv + be0);
    float o1 = scrub0(g1*(v1-mu)*rv + be1);
    msg[(size_t)slot*FEAT + l]      = f2bf_rne(o0);
    msg[(size_t)slot*FEAT + l + 64] = f2bf_rne(o1);
  }
}

// ---- CSR phase 2: sequential span gather, fp32 accumulate -> rec = sum/deg ----
__global__ __launch_bounds__(256) void k_gather(const unsigned short* __restrict__ msg,
    const int* __restrict__ pos, const float* __restrict__ degrees, float* __restrict__ rec){
  const int n = blockIdx.x*2 + (threadIdx.x >> 7);
  const int j = threadIdx.x & 127;
  const int s0 = (n == 0) ? 0 : pos[n-1];
  const int s1 = pos[n];
  float acc = 0.f;
  for (int s = s0; s < s1; ++s)
    acc += bf2f(msg[(size_t)s*FEAT + j]);
  rec[n*FEAT + j] = acc / degrees[n];
}

// ---- BN stats: per-block fp32 partials (divide flag for fallback) ----
__global__ __launch_bounds__(256) void k_stats(const float* __restrict__ src,
    const float* __restrict__ degrees, int divide, float* __restrict__ red_part){
  const int tid = threadIdx.x;
  const int j = tid & 127, half_sel = tid >> 7;
  const int n0 = blockIdx.x * 256;
  float s1 = 0.f, s2 = 0.f;
  for (int i = half_sel; i < 256; i += 2){
    int n = n0 + i;
    if (n < N_VARS){
      float v = src[n*FEAT + j];
      if (divide) v /= degrees[n];
      s1 += v;
      s2 += v*v;
    }
  }
  __shared__ float sh1[256], sh2[256];
  sh1[tid] = s1; sh2[tid] = s2;
  __syncthreads();
  if (half_sel == 0){
    red_part[blockIdx.x*256 + j]       = sh1[tid] + sh1[tid+128];
    red_part[blockIdx.x*256 + 128 + j] = sh2[tid] + sh2[tid+128];
  }
}

__global__ __launch_bounds__(256) void k_red(const float* __restrict__ red_part,
                                             float* __restrict__ red){
  const int tid = threadIdx.x;
  float s = 0.f, c = 0.f;
  for (int b = 0; b < NB_STAT; ++b){
    float y = red_part[b*256 + tid] - c;
    float t = s + y;
    c = (t - s) - y;
    s = t;
  }
  red[tid] = s;
}

// ---- BN apply + logits + softmax + argmax; bf16 state out ----
__global__ __launch_bounds__(256) void k_bn(const float* __restrict__ src,
    const float* __restrict__ degrees, int divide, const float* __restrict__ red,
    const float* __restrict__ bn_g, const float* __restrict__ bn_b,
    const float* __restrict__ Wd, const float* __restrict__ bd,
    unsigned short* __restrict__ state_bf, int* __restrict__ asg,
    float* __restrict__ out_phi, float* __restrict__ out_asg, int t){
  const int w = threadIdx.x >> 6, l = threadIdx.x & 63;
  const int n = blockIdx.x*4 + w;
  const float invN = 1.f / (float)N_VARS;
  float mu0 = red[l]*invN,     mu1 = red[l+64]*invN;
  float v0  = fmaxf(red[128+l]*invN    - mu0*mu0, 0.f);
  float v1  = fmaxf(red[128+l+64]*invN - mu1*mu1, 0.f);
  float rv0 = rsqrtf(v0 + EPSF);
  float rv1 = rsqrtf(v1 + EPSF);
  float dinv = divide ? (1.f / degrees[n]) : 1.f;
  float r0 = src[n*FEAT + l]    * dinv;
  float r1 = src[n*FEAT + l+64] * dinv;
  float s0 = scrub0(bn_g[l]   *(r0 - mu0)*rv0 + bn_b[l]);
  float s1 = scrub0(bn_g[l+64]*(r1 - mu1)*rv1 + bn_b[l+64]);
  state_bf[n*FEAT + l]    = f2bf_rne(s0);
  state_bf[n*FEAT + l+64] = f2bf_rne(s1);
  float p[4];
#pragma unroll
  for (int d = 0; d < 4; ++d)
    p[d] = s0*Wd[l*4 + d] + s1*Wd[(l+64)*4 + d];
#pragma unroll
  for (int o = 32; o > 0; o >>= 1){
#pragma unroll
    for (int d = 0; d < 4; ++d) p[d] += __shfl_xor(p[d], o);
  }
  if (l == 0){
    float lg[4];
#pragma unroll
    for (int d = 0; d < 4; ++d) lg[d] = scrub0(p[d] + bd[d]);
    float mx = fmaxf(fmaxf(lg[0],lg[1]), fmaxf(lg[2],lg[3]));
    float ex[4]; float ssum = 0.f;
#pragma unroll
    for (int d = 0; d < 4; ++d){ ex[d] = expf(lg[d] - mx); ssum += ex[d]; }
    float inv = 1.f / ssum;
    int am = 0; float bv = -1.f;
#pragma unroll
    for (int d = 0; d < 4; ++d){
      float pv = scrub0(ex[d]*inv);
      out_phi[n*12 + t*4 + d] = pv;
      if (pv > bv){ bv = pv; am = d; }
    }
    asg[n*3 + t] = am;
    if (t == 2) out_asg[n] = (float)am;
  }
}

// ---- edge conflicts -> out_ec + per-block partial of t=2 column ----
__global__ __launch_bounds__(256) void k_conf(const int* __restrict__ asg,
    const int* __restrict__ idxL, const int* __restrict__ idxR,
    const float* __restrict__ relation, float* __restrict__ out_ec,
    float* __restrict__ part_conf){
  const int e = blockIdx.x*256 + threadIdx.x;
  float c2 = 0.f;
  if (e < N_EDGES){
    int l = idxL[e], r = idxR[e];
#pragma unroll
    for (int tt = 0; tt < 3; ++tt){
      int ai = asg[l*3+tt] & 3, bi = asg[r*3+tt] & 3;
      float c = scrub0(1.f - relation[ai*4 + bi]);
      out_ec[e*3 + tt] = c;
      if (tt == 2) c2 = c;
    }
  }
  __shared__ float sh[256];
  sh[threadIdx.x] = c2;
  __syncthreads();
  for (int k = 128; k > 0; k >>= 1){
    if (threadIdx.x < k) sh[threadIdx.x] += sh[threadIdx.x + k];
    __syncthreads();
  }
  if (threadIdx.x == 0) part_conf[blockIdx.x] = sh[0];
}

__global__ __launch_bounds__(256) void k_fconf(const float* __restrict__ part_conf,
                                               float* __restrict__ out){
  const int tid = threadIdx.x;
  float s = 0.f;
  for (int i = tid; i < NB_CONF; i += 256) s += part_conf[i];
  __shared__ float sh[256];
  sh[tid] = s;
  __syncthreads();
  for (int k = 128; k > 0; k >>= 1){
    if (tid < k) sh[tid] += sh[tid + k];
    __syncthreads();
  }
  if (tid == 0){
    float nc = sh[0];
    out[NCONF_SLOT] = nc;
    out[1] = nc / (float)N_EDGES;
  }
}

// ---- pair losses from fp32 phi (in d_out): per-block partials ----
__global__ __launch_bounds__(256) void k_loss(const float* __restrict__ phi,
    const int* __restrict__ iL, const int* __restrict__ iR,
    const int* __restrict__ iLp, const int* __restrict__ iRp,
    const float* __restrict__ rel, const float* __restrict__ conf,
    float* __restrict__ part_l1, float* __restrict__ part_l2){
  const int m = blockIdx.x*256 + threadIdx.x;
  float p1 = 0.f, p2 = 0.f;
  if (m < N_EDGES*3){
    int e = m/3, tt = m - e*3;
    const float* pl = phi + iL[e]*12 + tt*4;
    const float* pr = phi + iR[e]*12 + tt*4;
    float s = 0.f;
#pragma unroll
    for (int j = 0; j < 4; ++j){
      float tj = 0.f;
#pragma unroll
      for (int i = 0; i < 4; ++i) tj += pl[i]*rel[i*4+j];
      s += tj*pr[j];
    }
    s = scrub0(s); s = fmaxf(s, 1e-35f);
    p1 = -logf(s);
  } else {
    int m2 = m - N_EDGES*3;
    if (m2 < N_CONFP*3){
      int e = m2/3, tt = m2 - e*3;
      const float* pl = phi + iLp[e]*12 + tt*4;
      const float* pr = phi + iRp[e]*12 + tt*4;
      float s = 0.f;
#pragma unroll
      for (int j = 0; j < 4; ++j){
        float tj = 0.f;
#pragma unroll
        for (int i = 0; i < 4; ++i) tj += pl[i]*conf[i*4+j];
        s += tj*pr[j];
      }
      s = scrub0(s); s = fmaxf(s, 1e-35f);
      p2 = -logf(s);
    }
  }
  __shared__ float sh1[256], sh2[256];
  sh1[threadIdx.x] = p1; sh2[threadIdx.x] = p2;
  __syncthreads();
  for (int k = 128; k > 0; k >>= 1){
    if (threadIdx.x < k){
      sh1[threadIdx.x] += sh1[threadIdx.x + k];
      sh2[threadIdx.x] += sh2[threadIdx.x + k];
    }
    __syncthreads();
  }
  if (threadIdx.x == 0){
    part_l1[blockIdx.x] = sh1[0];
    part_l2[blockIdx.x] = sh2[0];
  }
}

__global__ __launch_bounds__(256) void k_floss(const float* __restrict__ part_l1,
    const float* __restrict__ part_l2, float* __restrict__ out){
  const int tid = threadIdx.x;
  float a = 0.f, ca = 0.f, b = 0.f, cb = 0.f;
  for (int i = tid; i < NB_LOSS; i += 256){
    float y = part_l1[i] - ca; float t = a + y; ca = (t - a) - y; a = t;
    float y2 = part_l2[i] - cb; float t2 = b + y2; cb = (t2 - b) - y2; b = t2;
  }
  __shared__ float sh1[256], sh2[256];
  sh1[tid] = a; sh2[tid] = b;
  __syncthreads();
  for (int k = 128; k > 0; k >>= 1){
    if (tid < k){ sh1[tid] += sh1[tid + k]; sh2[tid] += sh2[tid + k]; }
    __syncthreads();
  }
  if (tid == 0)
    out[0] = sh1[0]/(float)N_EDGES + sh2[0]/(10.f*(float)N_CONFP);
}

extern "C" void kernel_launch(void* const* d_in, const int* in_sizes, int n_in,
                              void* d_out, int out_size, void* d_ws, size_t ws_size,
                              hipStream_t stream){
  const float* state0  = (const float*)d_in[0];
  const float* W1      = (const float*)d_in[1];
  const float* b1v     = (const float*)d_in[2];
  const float* W2      = (const float*)d_in[3];
  const float* b2v     = (const float*)d_in[4];
  const float* ln_g    = (const float*)d_in[5];
  const float* ln_b    = (const float*)d_in[6];
  const float* bn_g    = (const float*)d_in[7];
  const float* bn_b    = (const float*)d_in[8];
  const float* Wd      = (const float*)d_in[9];
  const float* bd      = (const float*)d_in[10];
  const float* rel     = (const float*)d_in[11];
  const float* confm   = (const float*)d_in[12];
  const float* degrees = (const float*)d_in[13];
  const int* idxL = (const int*)d_in[14];
  const int* idxR = (const int*)d_in[15];
  const int* iLp  = (const int*)d_in[16];
  const int* iRp  = (const int*)d_in[17];

  char* ws = (char*)d_ws;
  unsigned short* state_bf = (unsigned short*)(ws);          // 10,240,000
  unsigned short* PQb  = (unsigned short*)(ws + 10240000);   // 20,480,000
  float*  recagg    = (float*)(ws + 30720000);               // 20,480,000
  int*    asg       = (int*)  (ws + 51200000);               //    480,000
  float*  red_part  = (float*)(ws + 51680000);               //    160,768
  float*  red       = (float*)(ws + 51840768);               //      1,024
  float*  part_l1   = (float*)(ws + 51841792);               //     14,068
  float*  part_l2   = (float*)(ws + 51855860);               //     14,068
  float*  part_conf = (float*)(ws + 51869928);               //      3,128
  unsigned short* W2pack = (unsigned short*)(ws + 51873056); //     32,768
  unsigned short* W1pack = (unsigned short*)(ws + 51905824); //     65,536
  // CSR extension (only touched when ws_size is big enough)
  int*    pos       = (int*)(ws + 51971360);                 //    160,000
  int*    cnt       = (int*)(ws + 52131360);                 //    160,000
  int*    mslot     = (int*)(ws + 52291360);                 //  1,600,000
  int*    blk_tot   = (int*)(ws + 53891360);                 //      1,024
  int*    blk_off   = (int*)(ws + 53892384);                 //      1,024
  unsigned short* msg = (unsigned short*)(ws + 53893408);    // 102,400,000 -> ends 156,293,408
  const int use_csr = (ws_size >= (size_t)156451376) ? 1 : 0;  // same proven threshold as R11

  float* out     = (float*)d_out;
  float* out_phi = out + 2;
  float* out_ec  = out + 480002;
  float* out_asg = out + 1080002;

  k_zero_out<<<(OUT_TOTAL + 255)/256, 256, 0, stream>>>(out, OUT_TOTAL);
  k_prep<<<8, 256, 0, stream>>>(W2, W2pack);
  k_prep_w1<<<16, 256, 0, stream>>>(W1, W1pack);

  if (use_csr){
    k_zero_int<<<NB_STAT, 256, 0, stream>>>(cnt, N_VARS);
    k_hist<<<(N_MSG + 255)/256, 256, 0, stream>>>(idxL, idxR, cnt);
    k_scan1<<<NB_STAT, 256, 0, stream>>>(cnt, pos, blk_tot);
    k_scan2<<<1, 256, 0, stream>>>(blk_tot, blk_off);
    k_scan3<<<NB_STAT, 256, 0, stream>>>(pos, blk_off);
    k_fill<<<(N_MSG + 255)/256, 256, 0, stream>>>(idxL, idxR, pos, mslot);
  }

  for (int t = 0; t < T_ITERS; ++t){
    k_pq<<<N_VARS/32, 256, 0, stream>>>(state0, state_bf, (t == 0) ? 1 : 0, W1pack, PQb);
    if (use_csr){
      k_msg<<<N_MSG/32, 256, 0, stream>>>(PQb, W2pack, b1v, b2v, ln_g, ln_b, idxL, idxR, mslot, msg);
      k_gather<<<N_VARS/2, 256, 0, stream>>>(msg, pos, degrees, recagg);
      k_stats<<<NB_STAT, 256, 0, stream>>>(recagg, degrees, 0, red_part);
    } else {
      k_zero_agg<<<5000, 256, 0, stream>>>((float4*)recagg);
      k_edge<<<N_MSG/32, 256, 0, stream>>>(PQb, W2pack, b1v, b2v, ln_g, ln_b, idxL, idxR, recagg);
      k_stats<<<NB_STAT, 256, 0, stream>>>(recagg, degrees, 1, red_part);
    }
    k_red<<<1, 256, 0, stream>>>(red_part, red);
    k_bn<<<N_VARS/4, 256, 0, stream>>>(recagg, degrees, use_csr ? 0 : 1, red, bn_g, bn_b, Wd, bd,
                                       state_bf, asg, out_phi, out_asg, t);
  }
  k_conf<<<NB_CONF, 256, 0, stream>>>(asg, idxL, idxR, rel, out_ec, part_conf);
  k_fconf<<<1, 256, 0, stream>>>(part_conf, out);
  k_loss<<<NB_LOSS, 256, 0, stream>>>(out_phi, idxL, idxR, iLp, iRp, rel, confm, part_l1, part_l2);
  k_floss<<<1, 256, 0, stream>>>(part_l1, part_l2, out);
}

// Round 13
// 732.130 us; speedup vs baseline: 1.3213x; 1.0535x over previous
//
#include <hip/hip_runtime.h>
#include <math.h>

#define N_VARS 40000
#define FEAT 128
#define N_EDGES 200000
#define N_MSG (2*N_EDGES)
#define N_CONFP 100000
#define T_ITERS 3
#define EPSF 1e-5f

#define NB_CONF 782              // ceil(200000/256)
#define NB_LOSS 3517             // ceil(900000/256)
#define NB_STAT 157              // ceil(40000/256)
#define OUT_TOTAL 1120003
#define NCONF_SLOT 1120002       // sequential carve: 1+1+480000+600000+40000

typedef short short8 __attribute__((ext_vector_type(8)));
typedef float floatx4 __attribute__((ext_vector_type(4)));
typedef unsigned short ushort4v __attribute__((ext_vector_type(4)));

__device__ __forceinline__ float scrub0(float x){
  unsigned u = __float_as_uint(x);
  return ((u & 0x7F800000u) == 0x7F800000u) ? 0.f : x;
}
__device__ __forceinline__ unsigned short f2bf_rne(float x){
  unsigned u = __float_as_uint(x);
  u += 0x7FFFu + ((u >> 16) & 1u);
  return (unsigned short)(u >> 16);
}
__device__ __forceinline__ float bf2f(unsigned short h){
  return __uint_as_float(((unsigned)h) << 16);
}

__global__ __launch_bounds__(256) void k_zero_agg(float4* __restrict__ p){
  p[blockIdx.x*256 + threadIdx.x] = make_float4(0.f,0.f,0.f,0.f);
}
__global__ __launch_bounds__(256) void k_zero_int(int* __restrict__ p, int n){
  int i = blockIdx.x*256 + threadIdx.x;
  if (i < n) p[i] = 0;
}

// ---- CSR build over message ids m in [0,2E): target = m<E ? idxL[m] : idxR[m-E]
__global__ __launch_bounds__(256) void k_hist(const int* __restrict__ idxL,
    const int* __restrict__ idxR, int* __restrict__ cnt){
  int m = blockIdx.x*256 + threadIdx.x;
  if (m < N_MSG){
    int t = (m < N_EDGES) ? idxL[m] : idxR[m - N_EDGES];
    atomicAdd(&cnt[t], 1);
  }
}
__global__ __launch_bounds__(256) void k_scan1(const int* __restrict__ cnt,
    int* __restrict__ pos, int* __restrict__ blk_tot){
  const int tid = threadIdx.x;
  const int idx = blockIdx.x*256 + tid;
  int v = (idx < N_VARS) ? cnt[idx] : 0;
  __shared__ int sh[256];
  sh[tid] = v;
  __syncthreads();
#pragma unroll
  for (int o = 1; o < 256; o <<= 1){
    int add = (tid >= o) ? sh[tid - o] : 0;
    __syncthreads();
    sh[tid] += add;
    __syncthreads();
  }
  if (idx < N_VARS) pos[idx] = sh[tid] - v;
  if (tid == 255) blk_tot[blockIdx.x] = sh[255];
}
__global__ __launch_bounds__(256) void k_scan2(const int* __restrict__ blk_tot,
    int* __restrict__ blk_off){
  const int tid = threadIdx.x;
  int v = (tid < NB_STAT) ? blk_tot[tid] : 0;
  __shared__ int sh[256];
  sh[tid] = v;
  __syncthreads();
#pragma unroll
  for (int o = 1; o < 256; o <<= 1){
    int add = (tid >= o) ? sh[tid - o] : 0;
    __syncthreads();
    sh[tid] += add;
    __syncthreads();
  }
  if (tid < NB_STAT) blk_off[tid] = sh[tid] - v;
}
__global__ __launch_bounds__(256) void k_scan3(int* __restrict__ pos,
    const int* __restrict__ blk_off){
  const int idx = blockIdx.x*256 + threadIdx.x;
  if (idx < N_VARS) pos[idx] += blk_off[blockIdx.x];
}
__global__ __launch_bounds__(256) void k_fill(const int* __restrict__ idxL,
    const int* __restrict__ idxR, int* __restrict__ pos, int* __restrict__ mslot){
  int m = blockIdx.x*256 + threadIdx.x;
  if (m < N_MSG){
    int t = (m < N_EDGES) ? idxL[m] : idxR[m - N_EDGES];
    mslot[m] = atomicAdd(&pos[t], 1);
  }
}

// ---- pack W2 (128x128 f32) into B-fragment-ordered bf16 (8 ntiles) ----
__global__ __launch_bounds__(256) void k_prep(const float* __restrict__ W2,
                                              unsigned short* __restrict__ W2pack){
  int gid = blockIdx.x*256 + threadIdx.x;
  int lane = gid & 63;
  int ks = (gid >> 6) & 3;
  int ntg = gid >> 8;
  int kbase = ks*32 + (lane >> 4)*8;
  int n = ntg*16 + (lane & 15);
#pragma unroll
  for (int j = 0; j < 8; ++j)
    W2pack[gid*8 + j] = f2bf_rne(W2[(kbase + j)*FEAT + n]);
}
__global__ __launch_bounds__(256) void k_prep_w1(const float* __restrict__ W1,
                                                 unsigned short* __restrict__ W1pack){
  int gid = blockIdx.x*256 + threadIdx.x;
  int lane = gid & 63;
  int ks = (gid >> 6) & 3;
  int ntg = gid >> 8;
  int kbase = ks*32 + (lane >> 4)*8;
  int n = ntg*16 + (lane & 15);
#pragma unroll
  for (int j = 0; j < 8; ++j){
    int k = kbase + j;
    float v = (n < 128) ? W1[k*FEAT + n] : W1[(128 + k)*FEAT + (n - 128)];
    W1pack[gid*8 + j] = f2bf_rne(v);
  }
}

// ---- PQ = x @ [W1top | W1bot] via MFMA bf16 -> bf16 store ----
#define X_STRIDE 136
__global__ __launch_bounds__(256) void k_pq(const float* __restrict__ xf,
                                            const unsigned short* __restrict__ xb,
                                            int src_f32,
                                            const unsigned short* __restrict__ W1pack,
                                            unsigned short* __restrict__ PQb){
  __shared__ __align__(16) unsigned short Xbf[32*X_STRIDE];
  const int tid = threadIdx.x;
  const int row0 = blockIdx.x * 32;
  if (src_f32){
    const int c4 = (tid & 31)*4, g8 = tid >> 5;
#pragma unroll
    for (int r = 0; r < 4; ++r){
      int row = g8*4 + r;
      const float4 v = *(const float4*)&xf[(row0 + row)*FEAT + c4];
      ushort4v u;
      u.x = f2bf_rne(v.x); u.y = f2bf_rne(v.y);
      u.z = f2bf_rne(v.z); u.w = f2bf_rne(v.w);
      *(ushort4v*)&Xbf[row*X_STRIDE + c4] = u;
    }
  } else {
    const int c8 = (tid & 15)*8, g16 = tid >> 4;
#pragma unroll
    for (int r = 0; r < 2; ++r){
      int row = r*16 + g16;
      *(short8*)&Xbf[row*X_STRIDE + c8] = *(const short8*)&xb[(row0 + row)*FEAT + c8];
    }
  }
  __syncthreads();
  const int w = tid >> 6, lane = tid & 63;
  const int quad = lane >> 4, mcol = lane & 15;
#pragma unroll
  for (int mt = 0; mt < 2; ++mt){
    floatx4 a0 = {0.f,0.f,0.f,0.f};
    floatx4 a1 = {0.f,0.f,0.f,0.f};
    floatx4 a2 = {0.f,0.f,0.f,0.f};
    floatx4 a3 = {0.f,0.f,0.f,0.f};
#pragma unroll
    for (int ks = 0; ks < 4; ++ks){
      short8 a = *(const short8*)&Xbf[(mt*16 + mcol)*X_STRIDE + ks*32 + quad*8];
      const unsigned short* bp = W1pack + ((w*16 + ks)*64 + lane)*8;
      short8 b0 = *(const short8*)(bp);
      short8 b1 = *(const short8*)(bp + 2048);
      short8 b2 = *(const short8*)(bp + 4096);
      short8 b3 = *(const short8*)(bp + 6144);
      a0 = __builtin_amdgcn_mfma_f32_16x16x32_bf16(a, b0, a0, 0, 0, 0);
      a1 = __builtin_amdgcn_mfma_f32_16x16x32_bf16(a, b1, a1, 0, 0, 0);
      a2 = __builtin_amdgcn_mfma_f32_16x16x32_bf16(a, b2, a2, 0, 0, 0);
      a3 = __builtin_amdgcn_mfma_f32_16x16x32_bf16(a, b3, a3, 0, 0, 0);
    }
#pragma unroll
    for (int nt = 0; nt < 4; ++nt){
      floatx4 acc = (nt == 0) ? a0 : (nt == 1) ? a1 : (nt == 2) ? a2 : a3;
      int n = w*64 + nt*16 + mcol;
#pragma unroll
      for (int reg = 0; reg < 4; ++reg)
        PQb[(row0 + mt*16 + quad*4 + reg)*(2*FEAT) + n] = f2bf_rne(acc[reg]);
    }
  }
}

#define U_STRIDE 136   // bf16 elems

// Core: index staging + U staging + MFMA + relu/bias + in-register LN stats.
// Ends with: z[nt][reg], colv[], lgv[], lbv[], muv[reg], rvv[reg], sTa[], m0, mt, quad, mcol, nhalf.
#define EDGE_CORE() \
  __shared__ __align__(16) unsigned short Ubf[32*U_STRIDE]; \
  __shared__ float sS[64], sQ[64]; \
  __shared__ int sTa[32], sTb[32]; \
  const int tid = threadIdx.x; \
  const int m0 = blockIdx.x * 32; \
  if (tid < 32){ \
    int m = m0 + tid; \
    int e = (m < N_EDGES) ? m : (m - N_EDGES); \
    int l = idxL[e], r = idxR[e]; \
    sTa[tid] = (m < N_EDGES) ? l : r; \
    sTb[tid] = (m < N_EDGES) ? r : l; \
  } \
  __syncthreads(); \
  { \
    const int c8 = (tid & 15)*8, g16 = tid >> 4; \
    const float4 b1a = *(const float4*)&b1v[c8]; \
    const float4 b1b = *(const float4*)&b1v[c8 + 4]; \
    _Pragma("unroll") \
    for (int r = 0; r < 2; ++r){ \
      int row = r*16 + g16; \
      short8 pb = *(const short8*)&PQb[sTb[row]*(2*FEAT) + c8]; \
      short8 qb = *(const short8*)&PQb[sTa[row]*(2*FEAT) + FEAT + c8]; \
      ushort4v u0, u1; \
      u0.x = f2bf_rne(fmaxf(bf2f(pb[0]) + bf2f(qb[0]) + b1a.x, 0.f)); \
      u0.y = f2bf_rne(fmaxf(bf2f(pb[1]) + bf2f(qb[1]) + b1a.y, 0.f)); \
      u0.z = f2bf_rne(fmaxf(bf2f(pb[2]) + bf2f(qb[2]) + b1a.z, 0.f)); \
      u0.w = f2bf_rne(fmaxf(bf2f(pb[3]) + bf2f(qb[3]) + b1a.w, 0.f)); \
      u1.x = f2bf_rne(fmaxf(bf2f(pb[4]) + bf2f(qb[4]) + b1b.x, 0.f)); \
      u1.y = f2bf_rne(fmaxf(bf2f(pb[5]) + bf2f(qb[5]) + b1b.y, 0.f)); \
      u1.z = f2bf_rne(fmaxf(bf2f(pb[6]) + bf2f(qb[6]) + b1b.z, 0.f)); \
      u1.w = f2bf_rne(fmaxf(bf2f(pb[7]) + bf2f(qb[7]) + b1b.w, 0.f)); \
      *(ushort4v*)&Ubf[row*U_STRIDE + c8]     = u0; \
      *(ushort4v*)&Ubf[row*U_STRIDE + c8 + 4] = u1; \
    } \
  } \
  __syncthreads(); \
  const int w = tid >> 6, lane = tid & 63; \
  const int mt = w & 1, nhalf = w >> 1; \
  const int quad = lane >> 4, mcol = lane & 15; \
  floatx4 acc0 = {0.f,0.f,0.f,0.f}; \
  floatx4 acc1 = {0.f,0.f,0.f,0.f}; \
  floatx4 acc2 = {0.f,0.f,0.f,0.f}; \
  floatx4 acc3 = {0.f,0.f,0.f,0.f}; \
  _Pragma("unroll") \
  for (int ks = 0; ks < 4; ++ks){ \
    short8 a = *(const short8*)&Ubf[(mt*16 + mcol)*U_STRIDE + ks*32 + quad*8]; \
    const unsigned short* bp = W2pack + ((nhalf*4*256) + ks*64 + lane)*8; \
    short8 bq0 = *(const short8*)(bp); \
    short8 bq1 = *(const short8*)(bp + 2048); \
    short8 bq2 = *(const short8*)(bp + 4096); \
    short8 bq3 = *(const short8*)(bp + 6144); \
    acc0 = __builtin_amdgcn_mfma_f32_16x16x32_bf16(a, bq0, acc0, 0, 0, 0); \
    acc1 = __builtin_amdgcn_mfma_f32_16x16x32_bf16(a, bq1, acc1, 0, 0, 0); \
    acc2 = __builtin_amdgcn_mfma_f32_16x16x32_bf16(a, bq2, acc2, 0, 0, 0); \
    acc3 = __builtin_amdgcn_mfma_f32_16x16x32_bf16(a, bq3, acc3, 0, 0, 0); \
  } \
  float z[4][4]; \
  _Pragma("unroll") \
  for (int nt = 0; nt < 4; ++nt){ \
    floatx4 a4 = (nt == 0) ? acc0 : (nt == 1) ? acc1 : (nt == 2) ? acc2 : acc3; \
    float bb = b2v[nhalf*64 + nt*16 + mcol]; \
    _Pragma("unroll") \
    for (int reg = 0; reg < 4; ++reg) z[nt][reg] = fmaxf(a4[reg] + bb, 0.f); \
  } \
  float ps[4], pq[4]; \
  _Pragma("unroll") \
  for (int reg = 0; reg < 4; ++reg){ \
    ps[reg] = z[0][reg] + z[1][reg] + z[2][reg] + z[3][reg]; \
    pq[reg] = z[0][reg]*z[0][reg] + z[1][reg]*z[1][reg] + z[2][reg]*z[2][reg] + z[3][reg]*z[3][reg]; \
  } \
  _Pragma("unroll") \
  for (int o = 1; o < 16; o <<= 1){ \
    _Pragma("unroll") \
    for (int reg = 0; reg < 4; ++reg){ \
      ps[reg] += __shfl_xor(ps[reg], o); \
      pq[reg] += __shfl_xor(pq[reg], o); \
    } \
  } \
  if (mcol == 0){ \
    _Pragma("unroll") \
    for (int reg = 0; reg < 4; ++reg){ \
      int row = mt*16 + quad*4 + reg; \
      sS[nhalf*32 + row] = ps[reg]; \
      sQ[nhalf*32 + row] = pq[reg]; \
    } \
  } \
  __syncthreads(); \
  int colv[4]; float lgv[4], lbv[4]; \
  _Pragma("unroll") \
  for (int nt = 0; nt < 4; ++nt){ \
    colv[nt] = nhalf*64 + nt*16 + mcol; \
    lgv[nt] = ln_g[colv[nt]]; \
    lbv[nt] = ln_b[colv[nt]]; \
  } \
  float muv[4], rvv[4]; \
  _Pragma("unroll") \
  for (int reg = 0; reg < 4; ++reg){ \
    int row = mt*16 + quad*4 + reg; \
    float s = sS[row] + sS[32 + row]; \
    float q = sQ[row] + sQ[32 + row]; \
    float mu = s * (1.f/FEAT); \
    float var = fmaxf(q * (1.f/FEAT) - mu*mu, 0.f); \
    muv[reg] = mu; \
    rvv[reg] = rsqrtf(var + EPSF); \
  }

// ---- fallback: edge MLP + LN + atomic scatter ----
__global__ __launch_bounds__(256) void k_edge(const unsigned short* __restrict__ PQb,
    const unsigned short* __restrict__ W2pack, const float* __restrict__ b1v,
    const float* __restrict__ b2v, const float* __restrict__ ln_g, const float* __restrict__ ln_b,
    const int* __restrict__ idxL, const int* __restrict__ idxR,
    float* __restrict__ agg){
  EDGE_CORE()
#pragma unroll
  for (int reg = 0; reg < 4; ++reg){
    int row = mt*16 + quad*4 + reg;
    int a = sTa[row];
#pragma unroll
    for (int nt = 0; nt < 4; ++nt){
      float o = scrub0(lgv[nt]*(z[nt][reg] - muv[reg])*rvv[reg] + lbv[nt]);
      atomicAdd(&agg[a*FEAT + colv[nt]], o);
    }
  }
}

// ---- CSR phase 1: edge MLP + LN -> slot-ordered bf16 msg store from registers ----
__global__ __launch_bounds__(256) void k_msg(const unsigned short* __restrict__ PQb,
    const unsigned short* __restrict__ W2pack, const float* __restrict__ b1v,
    const float* __restrict__ b2v, const float* __restrict__ ln_g, const float* __restrict__ ln_b,
    const int* __restrict__ idxL, const int* __restrict__ idxR,
    const int* __restrict__ mslot, unsigned short* __restrict__ msg){
  EDGE_CORE()
#pragma unroll
  for (int reg = 0; reg < 4; ++reg){
    int row = mt*16 + quad*4 + reg;
    size_t base = (size_t)mslot[m0 + row]*FEAT;
#pragma unroll
    for (int nt = 0; nt < 4; ++nt){
      float o = scrub0(lgv[nt]*(z[nt][reg] - muv[reg])*rvv[reg] + lbv[nt]);
      msg[base + colv[nt]] = f2bf_rne(o);
    }
  }
}

// ---- CSR phase 2: sequential span gather, fp32 accumulate -> rec = sum/deg ----
__global__ __launch_bounds__(256) void k_gather(const unsigned short* __restrict__ msg,
    const int* __restrict__ pos, const float* __restrict__ degrees, float* __restrict__ rec){
  const int n = blockIdx.x*2 + (threadIdx.x >> 7);
  const int j = threadIdx.x & 127;
  const int s0 = (n == 0) ? 0 : pos[n-1];
  const int s1 = pos[n];
  float acc = 0.f;
  for (int s = s0; s < s1; ++s)
    acc += bf2f(msg[(size_t)s*FEAT + j]);
  rec[n*FEAT + j] = acc / degrees[n];
}

// ---- BN stats ----
__global__ __launch_bounds__(256) void k_stats(const float* __restrict__ src,
    const float* __restrict__ degrees, int divide, float* __restrict__ red_part){
  const int tid = threadIdx.x;
  const int j = tid & 127, half_sel = tid >> 7;
  const int n0 = blockIdx.x * 256;
  float s1 = 0.f, s2 = 0.f;
  for (int i = half_sel; i < 256; i += 2){
    int n = n0 + i;
    if (n < N_VARS){
      float v = src[n*FEAT + j];
      if (divide) v /= degrees[n];
      s1 += v;
      s2 += v*v;
    }
  }
  __shared__ float sh1[256], sh2[256];
  sh1[tid] = s1; sh2[tid] = s2;
  __syncthreads();
  if (half_sel == 0){
    red_part[blockIdx.x*256 + j]       = sh1[tid] + sh1[tid+128];
    red_part[blockIdx.x*256 + 128 + j] = sh2[tid] + sh2[tid+128];
  }
}

__global__ __launch_bounds__(256) void k_red(const float* __restrict__ red_part,
                                             float* __restrict__ red){
  const int tid = threadIdx.x;
  float s = 0.f, c = 0.f;
  for (int b = 0; b < NB_STAT; ++b){
    float y = red_part[b*256 + tid] - c;
    float t = s + y;
    c = (t - s) - y;
    s = t;
  }
  red[tid] = s;
}

// ---- BN apply + logits + softmax + argmax; bf16 state out ----
__global__ __launch_bounds__(256) void k_bn(const float* __restrict__ src,
    const float* __restrict__ degrees, int divide, const float* __restrict__ red,
    const float* __restrict__ bn_g, const float* __restrict__ bn_b,
    const float* __restrict__ Wd, const float* __restrict__ bd,
    unsigned short* __restrict__ state_bf, int* __restrict__ asg,
    float* __restrict__ out_phi, float* __restrict__ out_asg, int t){
  const int w = threadIdx.x >> 6, l = threadIdx.x & 63;
  const int n = blockIdx.x*4 + w;
  const float invN = 1.f / (float)N_VARS;
  float mu0 = red[l]*invN,     mu1 = red[l+64]*invN;
  float v0  = fmaxf(red[128+l]*invN    - mu0*mu0, 0.f);
  float v1  = fmaxf(red[128+l+64]*invN - mu1*mu1, 0.f);
  float rv0 = rsqrtf(v0 + EPSF);
  float rv1 = rsqrtf(v1 + EPSF);
  float dinv = divide ? (1.f / degrees[n]) : 1.f;
  float r0 = src[n*FEAT + l]    * dinv;
  float r1 = src[n*FEAT + l+64] * dinv;
  float s0 = scrub0(bn_g[l]   *(r0 - mu0)*rv0 + bn_b[l]);
  float s1 = scrub0(bn_g[l+64]*(r1 - mu1)*rv1 + bn_b[l+64]);
  state_bf[n*FEAT + l]    = f2bf_rne(s0);
  state_bf[n*FEAT + l+64] = f2bf_rne(s1);
  float p[4];
#pragma unroll
  for (int d = 0; d < 4; ++d)
    p[d] = s0*Wd[l*4 + d] + s1*Wd[(l+64)*4 + d];
#pragma unroll
  for (int o = 32; o > 0; o >>= 1){
#pragma unroll
    for (int d = 0; d < 4; ++d) p[d] += __shfl_xor(p[d], o);
  }
  if (l == 0){
    float lg[4];
#pragma unroll
    for (int d = 0; d < 4; ++d) lg[d] = scrub0(p[d] + bd[d]);
    float mx = fmaxf(fmaxf(lg[0],lg[1]), fmaxf(lg[2],lg[3]));
    float ex[4]; float ssum = 0.f;
#pragma unroll
    for (int d = 0; d < 4; ++d){ ex[d] = expf(lg[d] - mx); ssum += ex[d]; }
    float inv = 1.f / ssum;
    int am = 0; float bv = -1.f;
#pragma unroll
    for (int d = 0; d < 4; ++d){
      float pv = scrub0(ex[d]*inv);
      out_phi[n*12 + t*4 + d] = pv;
      if (pv > bv){ bv = pv; am = d; }
    }
    asg[n*3 + t] = am;
    if (t == 2) out_asg[n] = (float)am;
  }
}

// ---- edge conflicts -> out_ec + per-block partial of t=2 column ----
__global__ __launch_bounds__(256) void k_conf(const int* __restrict__ asg,
    const int* __restrict__ idxL, const int* __restrict__ idxR,
    const float* __restrict__ relation, float* __restrict__ out_ec,
    float* __restrict__ part_conf){
  const int e = blockIdx.x*256 + threadIdx.x;
  float c2 = 0.f;
  if (e < N_EDGES){
    int l = idxL[e], r = idxR[e];
#pragma unroll
    for (int tt = 0; tt < 3; ++tt){
      int ai = asg[l*3+tt] & 3, bi = asg[r*3+tt] & 3;
      float c = scrub0(1.f - relation[ai*4 + bi]);
      out_ec[e*3 + tt] = c;
      if (tt == 2) c2 = c;
    }
  }
  __shared__ float sh[256];
  sh[threadIdx.x] = c2;
  __syncthreads();
  for (int k = 128; k > 0; k >>= 1){
    if (threadIdx.x < k) sh[threadIdx.x] += sh[threadIdx.x + k];
    __syncthreads();
  }
  if (threadIdx.x == 0) part_conf[blockIdx.x] = sh[0];
}

__global__ __launch_bounds__(256) void k_fconf(const float* __restrict__ part_conf,
                                               float* __restrict__ out){
  const int tid = threadIdx.x;
  float s = 0.f;
  for (int i = tid; i < NB_CONF; i += 256) s += part_conf[i];
  __shared__ float sh[256];
  sh[tid] = s;
  __syncthreads();
  for (int k = 128; k > 0; k >>= 1){
    if (tid < k) sh[tid] += sh[tid + k];
    __syncthreads();
  }
  if (tid == 0){
    float nc = sh[0];
    out[NCONF_SLOT] = nc;
    out[1] = nc / (float)N_EDGES;
  }
}

// ---- pair losses from fp32 phi (in d_out): per-block partials ----
__global__ __launch_bounds__(256) void k_loss(const float* __restrict__ phi,
    const int* __restrict__ iL, const int* __restrict__ iR,
    const int* __restrict__ iLp, const int* __restrict__ iRp,
    const float* __restrict__ rel, const float* __restrict__ conf,
    float* __restrict__ part_l1, float* __restrict__ part_l2){
  const int m = blockIdx.x*256 + threadIdx.x;
  float p1 = 0.f, p2 = 0.f;
  if (m < N_EDGES*3){
    int e = m/3, tt = m - e*3;
    const float* pl = phi + iL[e]*12 + tt*4;
    const float* pr = phi + iR[e]*12 + tt*4;
    float s = 0.f;
#pragma unroll
    for (int j = 0; j < 4; ++j){
      float tj = 0.f;
#pragma unroll
      for (int i = 0; i < 4; ++i) tj += pl[i]*rel[i*4+j];
      s += tj*pr[j];
    }
    s = scrub0(s); s = fmaxf(s, 1e-35f);
    p1 = -logf(s);
  } else {
    int m2 = m - N_EDGES*3;
    if (m2 < N_CONFP*3){
      int e = m2/3, tt = m2 - e*3;
      const float* pl = phi + iLp[e]*12 + tt*4;
      const float* pr = phi + iRp[e]*12 + tt*4;
      float s = 0.f;
#pragma unroll
      for (int j = 0; j < 4; ++j){
        float tj = 0.f;
#pragma unroll
        for (int i = 0; i < 4; ++i) tj += pl[i]*conf[i*4+j];
        s += tj*pr[j];
      }
      s = scrub0(s); s = fmaxf(s, 1e-35f);
      p2 = -logf(s);
    }
  }
  __shared__ float sh1[256], sh2[256];
  sh1[threadIdx.x] = p1; sh2[threadIdx.x] = p2;
  __syncthreads();
  for (int k = 128; k > 0; k >>= 1){
    if (threadIdx.x < k){
      sh1[threadIdx.x] += sh1[threadIdx.x + k];
      sh2[threadIdx.x] += sh2[threadIdx.x + k];
    }
    __syncthreads();
  }
  if (threadIdx.x == 0){
    part_l1[blockIdx.x] = sh1[0];
    part_l2[blockIdx.x] = sh2[0];
  }
}

__global__ __launch_bounds__(256) void k_floss(const float* __restrict__ part_l1,
    const float* __restrict__ part_l2, float* __restrict__ out){
  const int tid = threadIdx.x;
  float a = 0.f, ca = 0.f, b = 0.f, cb = 0.f;
  for (int i = tid; i < NB_LOSS; i += 256){
    float y = part_l1[i] - ca; float t = a + y; ca = (t - a) - y; a = t;
    float y2 = part_l2[i] - cb; float t2 = b + y2; cb = (t2 - b) - y2; b = t2;
  }
  __shared__ float sh1[256], sh2[256];
  sh1[tid] = a; sh2[tid] = b;
  __syncthreads();
  for (int k = 128; k > 0; k >>= 1){
    if (tid < k){ sh1[tid] += sh1[tid + k]; sh2[tid] += sh2[tid + k]; }
    __syncthreads();
  }
  if (tid == 0)
    out[0] = sh1[0]/(float)N_EDGES + sh2[0]/(10.f*(float)N_CONFP);
}

extern "C" void kernel_launch(void* const* d_in, const int* in_sizes, int n_in,
                              void* d_out, int out_size, void* d_ws, size_t ws_size,
                              hipStream_t stream){
  const float* state0  = (const float*)d_in[0];
  const float* W1      = (const float*)d_in[1];
  const float* b1v     = (const float*)d_in[2];
  const float* W2      = (const float*)d_in[3];
  const float* b2v     = (const float*)d_in[4];
  const float* ln_g    = (const float*)d_in[5];
  const float* ln_b    = (const float*)d_in[6];
  const float* bn_g    = (const float*)d_in[7];
  const float* bn_b    = (const float*)d_in[8];
  const float* Wd      = (const float*)d_in[9];
  const float* bd      = (const float*)d_in[10];
  const float* rel     = (const float*)d_in[11];
  const float* confm   = (const float*)d_in[12];
  const float* degrees = (const float*)d_in[13];
  const int* idxL = (const int*)d_in[14];
  const int* idxR = (const int*)d_in[15];
  const int* iLp  = (const int*)d_in[16];
  const int* iRp  = (const int*)d_in[17];

  char* ws = (char*)d_ws;
  unsigned short* state_bf = (unsigned short*)(ws);          // 10,240,000
  unsigned short* PQb  = (unsigned short*)(ws + 10240000);   // 20,480,000
  float*  recagg    = (float*)(ws + 30720000);               // 20,480,000
  int*    asg       = (int*)  (ws + 51200000);               //    480,000
  float*  red_part  = (float*)(ws + 51680000);               //    160,768
  float*  red       = (float*)(ws + 51840768);               //      1,024
  float*  part_l1   = (float*)(ws + 51841792);               //     14,068
  float*  part_l2   = (float*)(ws + 51855860);               //     14,068
  float*  part_conf = (float*)(ws + 51869928);               //      3,128
  unsigned short* W2pack = (unsigned short*)(ws + 51873056); //     32,768
  unsigned short* W1pack = (unsigned short*)(ws + 51905824); //     65,536
  int*    pos       = (int*)(ws + 51971360);                 //    160,000
  int*    cnt       = (int*)(ws + 52131360);                 //    160,000
  int*    mslot     = (int*)(ws + 52291360);                 //  1,600,000
  int*    blk_tot   = (int*)(ws + 53891360);                 //      1,024
  int*    blk_off   = (int*)(ws + 53892384);                 //      1,024
  unsigned short* msg = (unsigned short*)(ws + 53893408);    // 102,400,000
  const int use_csr = (ws_size >= (size_t)156451376) ? 1 : 0;

  float* out     = (float*)d_out;
  float* out_phi = out + 2;
  float* out_ec  = out + 480002;
  float* out_asg = out + 1080002;

  // NOTE: no output-zeroing needed — every out element is written each launch:
  // out[0] (k_floss), out[1]+out[NCONF_SLOT] (k_fconf), phi 480000 (k_bn x3),
  // ec 600000 (k_conf), asg 40000 (k_bn t=2). Total = 1,120,003 = OUT_TOTAL.
  k_prep<<<8, 256, 0, stream>>>(W2, W2pack);
  k_prep_w1<<<16, 256, 0, stream>>>(W1, W1pack);

  if (use_csr){
    k_zero_int<<<NB_STAT, 256, 0, stream>>>(cnt, N_VARS);
    k_hist<<<(N_MSG + 255)/256, 256, 0, stream>>>(idxL, idxR, cnt);
    k_scan1<<<NB_STAT, 256, 0, stream>>>(cnt, pos, blk_tot);
    k_scan2<<<1, 256, 0, stream>>>(blk_tot, blk_off);
    k_scan3<<<NB_STAT, 256, 0, stream>>>(pos, blk_off);
    k_fill<<<(N_MSG + 255)/256, 256, 0, stream>>>(idxL, idxR, pos, mslot);
  }

  for (int t = 0; t < T_ITERS; ++t){
    k_pq<<<N_VARS/32, 256, 0, stream>>>(state0, state_bf, (t == 0) ? 1 : 0, W1pack, PQb);
    if (use_csr){
      k_msg<<<N_MSG/32, 256, 0, stream>>>(PQb, W2pack, b1v, b2v, ln_g, ln_b, idxL, idxR, mslot, msg);
      k_gather<<<N_VARS/2, 256, 0, stream>>>(msg, pos, degrees, recagg);
      k_stats<<<NB_STAT, 256, 0, stream>>>(recagg, degrees, 0, red_part);
    } else {
      k_zero_agg<<<5000, 256, 0, stream>>>((float4*)recagg);
      k_edge<<<N_MSG/32, 256, 0, stream>>>(PQb, W2pack, b1v, b2v, ln_g, ln_b, idxL, idxR, recagg);
      k_stats<<<NB_STAT, 256, 0, stream>>>(recagg, degrees, 1, red_part);
    }
    k_red<<<1, 256, 0, stream>>>(red_part, red);
    k_bn<<<N_VARS/4, 256, 0, stream>>>(recagg, degrees, use_csr ? 0 : 1, red, bn_g, bn_b, Wd, bd,
                                       state_bf, asg, out_phi, out_asg, t);
  }
  k_conf<<<NB_CONF, 256, 0, stream>>>(asg, idxL, idxR, rel, out_ec, part_conf);
  k_fconf<<<1, 256, 0, stream>>>(part_conf, out);
  k_loss<<<NB_LOSS, 256, 0, stream>>>(out_phi, idxL, idxR, iLp, iRp, rel, confm, part_l1, part_l2);
  k_floss<<<1, 256, 0, stream>>>(part_l1, part_l2, out);
}

// Round 14
// 694.717 us; speedup vs baseline: 1.3925x; 1.0539x over previous
//
#include <hip/hip_runtime.h>
#include <math.h>

#define N_VARS 40000
#define FEAT 128
#define N_EDGES 200000
#define N_MSG (2*N_EDGES)
#define N_CONFP 100000
#define T_ITERS 3
#define EPSF 1e-5f

#define NB_CONF 782              // ceil(200000/256)
#define NB_LOSS 3517             // ceil(900000/256)
#define NB_STAT 157              // ceil(40000/256)
#define NB_GATH 1250             // 40000/32
#define OUT_TOTAL 1120003
#define NCONF_SLOT 1120002       // sequential carve: 1+1+480000+600000+40000

typedef short short8 __attribute__((ext_vector_type(8)));
typedef float floatx4 __attribute__((ext_vector_type(4)));
typedef unsigned short ushort4v __attribute__((ext_vector_type(4)));

__device__ __forceinline__ float scrub0(float x){
  unsigned u = __float_as_uint(x);
  return ((u & 0x7F800000u) == 0x7F800000u) ? 0.f : x;
}
__device__ __forceinline__ unsigned short f2bf_rne(float x){
  unsigned u = __float_as_uint(x);
  u += 0x7FFFu + ((u >> 16) & 1u);
  return (unsigned short)(u >> 16);
}
__device__ __forceinline__ float bf2f(unsigned short h){
  return __uint_as_float(((unsigned)h) << 16);
}

__global__ __launch_bounds__(256) void k_zero_agg(float4* __restrict__ p){
  p[blockIdx.x*256 + threadIdx.x] = make_float4(0.f,0.f,0.f,0.f);
}
__global__ __launch_bounds__(256) void k_zero_int(int* __restrict__ p, int n){
  int i = blockIdx.x*256 + threadIdx.x;
  if (i < n) p[i] = 0;
}

// ---- CSR build over message ids m in [0,2E): target = m<E ? idxL[m] : idxR[m-E]
__global__ __launch_bounds__(256) void k_hist(const int* __restrict__ idxL,
    const int* __restrict__ idxR, int* __restrict__ cnt){
  int m = blockIdx.x*256 + threadIdx.x;
  if (m < N_MSG){
    int t = (m < N_EDGES) ? idxL[m] : idxR[m - N_EDGES];
    atomicAdd(&cnt[t], 1);
  }
}
__global__ __launch_bounds__(256) void k_scan1(const int* __restrict__ cnt,
    int* __restrict__ pos, int* __restrict__ blk_tot){
  const int tid = threadIdx.x;
  const int idx = blockIdx.x*256 + tid;
  int v = (idx < N_VARS) ? cnt[idx] : 0;
  __shared__ int sh[256];
  sh[tid] = v;
  __syncthreads();
#pragma unroll
  for (int o = 1; o < 256; o <<= 1){
    int add = (tid >= o) ? sh[tid - o] : 0;
    __syncthreads();
    sh[tid] += add;
    __syncthreads();
  }
  if (idx < N_VARS) pos[idx] = sh[tid] - v;
  if (tid == 255) blk_tot[blockIdx.x] = sh[255];
}
__global__ __launch_bounds__(256) void k_scan2(const int* __restrict__ blk_tot,
    int* __restrict__ blk_off){
  const int tid = threadIdx.x;
  int v = (tid < NB_STAT) ? blk_tot[tid] : 0;
  __shared__ int sh[256];
  sh[tid] = v;
  __syncthreads();
#pragma unroll
  for (int o = 1; o < 256; o <<= 1){
    int add = (tid >= o) ? sh[tid - o] : 0;
    __syncthreads();
    sh[tid] += add;
    __syncthreads();
  }
  if (tid < NB_STAT) blk_off[tid] = sh[tid] - v;
}
__global__ __launch_bounds__(256) void k_scan3(int* __restrict__ pos,
    const int* __restrict__ blk_off){
  const int idx = blockIdx.x*256 + threadIdx.x;
  if (idx < N_VARS) pos[idx] += blk_off[blockIdx.x];
}
__global__ __launch_bounds__(256) void k_fill(const int* __restrict__ idxL,
    const int* __restrict__ idxR, int* __restrict__ pos, int* __restrict__ mslot){
  int m = blockIdx.x*256 + threadIdx.x;
  if (m < N_MSG){
    int t = (m < N_EDGES) ? idxL[m] : idxR[m - N_EDGES];
    mslot[m] = atomicAdd(&pos[t], 1);
  }
}

// ---- pack W2 (128x128 f32) into B-fragment-ordered bf16 (8 ntiles) ----
__global__ __launch_bounds__(256) void k_prep(const float* __restrict__ W2,
                                              unsigned short* __restrict__ W2pack){
  int gid = blockIdx.x*256 + threadIdx.x;
  int lane = gid & 63;
  int ks = (gid >> 6) & 3;
  int ntg = gid >> 8;
  int kbase = ks*32 + (lane >> 4)*8;
  int n = ntg*16 + (lane & 15);
#pragma unroll
  for (int j = 0; j < 8; ++j)
    W2pack[gid*8 + j] = f2bf_rne(W2[(kbase + j)*FEAT + n]);
}
__global__ __launch_bounds__(256) void k_prep_w1(const float* __restrict__ W1,
                                                 unsigned short* __restrict__ W1pack){
  int gid = blockIdx.x*256 + threadIdx.x;
  int lane = gid & 63;
  int ks = (gid >> 6) & 3;
  int ntg = gid >> 8;
  int kbase = ks*32 + (lane >> 4)*8;
  int n = ntg*16 + (lane & 15);
#pragma unroll
  for (int j = 0; j < 8; ++j){
    int k = kbase + j;
    float v = (n < 128) ? W1[k*FEAT + n] : W1[(128 + k)*FEAT + (n - 128)];
    W1pack[gid*8 + j] = f2bf_rne(v);
  }
}

// ---- PQ = x @ [W1top | W1bot] via MFMA bf16 -> bf16 store; also zeroes red ----
#define X_STRIDE 136
__global__ __launch_bounds__(256) void k_pq(const float* __restrict__ xf,
                                            const unsigned short* __restrict__ xb,
                                            int src_f32,
                                            const unsigned short* __restrict__ W1pack,
                                            unsigned short* __restrict__ PQb,
                                            float* __restrict__ red){
  __shared__ __align__(16) unsigned short Xbf[32*X_STRIDE];
  const int tid = threadIdx.x;
  const int row0 = blockIdx.x * 32;
  if (blockIdx.x == 0) red[tid] = 0.f;   // zero BN-stat accumulator for this iter
  if (src_f32){
    const int c4 = (tid & 31)*4, g8 = tid >> 5;
#pragma unroll
    for (int r = 0; r < 4; ++r){
      int row = g8*4 + r;
      const float4 v = *(const float4*)&xf[(row0 + row)*FEAT + c4];
      ushort4v u;
      u.x = f2bf_rne(v.x); u.y = f2bf_rne(v.y);
      u.z = f2bf_rne(v.z); u.w = f2bf_rne(v.w);
      *(ushort4v*)&Xbf[row*X_STRIDE + c4] = u;
    }
  } else {
    const int c8 = (tid & 15)*8, g16 = tid >> 4;
#pragma unroll
    for (int r = 0; r < 2; ++r){
      int row = r*16 + g16;
      *(short8*)&Xbf[row*X_STRIDE + c8] = *(const short8*)&xb[(row0 + row)*FEAT + c8];
    }
  }
  __syncthreads();
  const int w = tid >> 6, lane = tid & 63;
  const int quad = lane >> 4, mcol = lane & 15;
#pragma unroll
  for (int mt = 0; mt < 2; ++mt){
    floatx4 a0 = {0.f,0.f,0.f,0.f};
    floatx4 a1 = {0.f,0.f,0.f,0.f};
    floatx4 a2 = {0.f,0.f,0.f,0.f};
    floatx4 a3 = {0.f,0.f,0.f,0.f};
#pragma unroll
    for (int ks = 0; ks < 4; ++ks){
      short8 a = *(const short8*)&Xbf[(mt*16 + mcol)*X_STRIDE + ks*32 + quad*8];
      const unsigned short* bp = W1pack + ((w*16 + ks)*64 + lane)*8;
      short8 b0 = *(const short8*)(bp);
      short8 b1 = *(const short8*)(bp + 2048);
      short8 b2 = *(const short8*)(bp + 4096);
      short8 b3 = *(const short8*)(bp + 6144);
      a0 = __builtin_amdgcn_mfma_f32_16x16x32_bf16(a, b0, a0, 0, 0, 0);
      a1 = __builtin_amdgcn_mfma_f32_16x16x32_bf16(a, b1, a1, 0, 0, 0);
      a2 = __builtin_amdgcn_mfma_f32_16x16x32_bf16(a, b2, a2, 0, 0, 0);
      a3 = __builtin_amdgcn_mfma_f32_16x16x32_bf16(a, b3, a3, 0, 0, 0);
    }
#pragma unroll
    for (int nt = 0; nt < 4; ++nt){
      floatx4 acc = (nt == 0) ? a0 : (nt == 1) ? a1 : (nt == 2) ? a2 : a3;
      int n = w*64 + nt*16 + mcol;
#pragma unroll
      for (int reg = 0; reg < 4; ++reg)
        PQb[(row0 + mt*16 + quad*4 + reg)*(2*FEAT) + n] = f2bf_rne(acc[reg]);
    }
  }
}

#define U_STRIDE 136   // bf16 elems

// ---- CSR phase 1: 64 msgs/block; each wave owns 16 complete rows (no cross-wave LN) ----
__global__ __launch_bounds__(256) void k_msg(const unsigned short* __restrict__ PQb,
    const unsigned short* __restrict__ W2pack, const float* __restrict__ b1v,
    const float* __restrict__ b2v, const float* __restrict__ ln_g, const float* __restrict__ ln_b,
    const int* __restrict__ idxL, const int* __restrict__ idxR,
    const int* __restrict__ mslot, unsigned short* __restrict__ msg){
  __shared__ __align__(16) unsigned short Ubf[64*U_STRIDE];
  __shared__ int sTa[64], sTb[64];
  const int tid = threadIdx.x;
  const int m0 = blockIdx.x * 64;
  if (tid < 64){
    int m = m0 + tid;
    int e = (m < N_EDGES) ? m : (m - N_EDGES);
    int l = idxL[e], r = idxR[e];
    sTa[tid] = (m < N_EDGES) ? l : r;
    sTb[tid] = (m < N_EDGES) ? r : l;
  }
  __syncthreads();
  {
    const int c8 = (tid & 15)*8, g16 = tid >> 4;
    const float4 b1a = *(const float4*)&b1v[c8];
    const float4 b1b = *(const float4*)&b1v[c8 + 4];
    short8 pb[4], qb[4];
#pragma unroll
    for (int r = 0; r < 4; ++r){
      int row = r*16 + g16;
      pb[r] = *(const short8*)&PQb[sTb[row]*(2*FEAT) + c8];
      qb[r] = *(const short8*)&PQb[sTa[row]*(2*FEAT) + FEAT + c8];
    }
#pragma unroll
    for (int r = 0; r < 4; ++r){
      int row = r*16 + g16;
      ushort4v u0, u1;
      u0.x = f2bf_rne(fmaxf(bf2f(pb[r][0]) + bf2f(qb[r][0]) + b1a.x, 0.f));
      u0.y = f2bf_rne(fmaxf(bf2f(pb[r][1]) + bf2f(qb[r][1]) + b1a.y, 0.f));
      u0.z = f2bf_rne(fmaxf(bf2f(pb[r][2]) + bf2f(qb[r][2]) + b1a.z, 0.f));
      u0.w = f2bf_rne(fmaxf(bf2f(pb[r][3]) + bf2f(qb[r][3]) + b1a.w, 0.f));
      u1.x = f2bf_rne(fmaxf(bf2f(pb[r][4]) + bf2f(qb[r][4]) + b1b.x, 0.f));
      u1.y = f2bf_rne(fmaxf(bf2f(pb[r][5]) + bf2f(qb[r][5]) + b1b.y, 0.f));
      u1.z = f2bf_rne(fmaxf(bf2f(pb[r][6]) + bf2f(qb[r][6]) + b1b.z, 0.f));
      u1.w = f2bf_rne(fmaxf(bf2f(pb[r][7]) + bf2f(qb[r][7]) + b1b.w, 0.f));
      *(ushort4v*)&Ubf[row*U_STRIDE + c8]     = u0;
      *(ushort4v*)&Ubf[row*U_STRIDE + c8 + 4] = u1;
    }
  }
  __syncthreads();
  const int w = tid >> 6, lane = tid & 63;
  const int quad = lane >> 4, mcol = lane & 15;
  const int rbase = w*16;
  floatx4 acc[8];
#pragma unroll
  for (int nt = 0; nt < 8; ++nt) acc[nt] = (floatx4){0.f,0.f,0.f,0.f};
#pragma unroll
  for (int ks = 0; ks < 4; ++ks){
    short8 a = *(const short8*)&Ubf[(rbase + mcol)*U_STRIDE + ks*32 + quad*8];
#pragma unroll
    for (int nt = 0; nt < 8; ++nt){
      short8 b = *(const short8*)(W2pack + ((nt*4 + ks)*64 + lane)*8);
      acc[nt] = __builtin_amdgcn_mfma_f32_16x16x32_bf16(a, b, acc[nt], 0, 0, 0);
    }
  }
  float z[8][4];
#pragma unroll
  for (int nt = 0; nt < 8; ++nt){
    float bb = b2v[nt*16 + mcol];
#pragma unroll
    for (int reg = 0; reg < 4; ++reg) z[nt][reg] = fmaxf(acc[nt][reg] + bb, 0.f);
  }
  float ps[4], pq[4];
#pragma unroll
  for (int reg = 0; reg < 4; ++reg){
    ps[reg] = 0.f; pq[reg] = 0.f;
#pragma unroll
    for (int nt = 0; nt < 8; ++nt){
      ps[reg] += z[nt][reg];
      pq[reg] += z[nt][reg]*z[nt][reg];
    }
  }
#pragma unroll
  for (int o = 1; o < 16; o <<= 1){
#pragma unroll
    for (int reg = 0; reg < 4; ++reg){
      ps[reg] += __shfl_xor(ps[reg], o);
      pq[reg] += __shfl_xor(pq[reg], o);
    }
  }
  float lgv[8], lbv[8];
#pragma unroll
  for (int nt = 0; nt < 8; ++nt){
    lgv[nt] = ln_g[nt*16 + mcol];
    lbv[nt] = ln_b[nt*16 + mcol];
  }
#pragma unroll
  for (int reg = 0; reg < 4; ++reg){
    int row = rbase + quad*4 + reg;
    float mu = ps[reg] * (1.f/FEAT);
    float var = fmaxf(pq[reg] * (1.f/FEAT) - mu*mu, 0.f);
    float rv = rsqrtf(var + EPSF);
    size_t base = (size_t)mslot[m0 + row]*FEAT;
#pragma unroll
    for (int nt = 0; nt < 8; ++nt){
      float o = scrub0(lgv[nt]*(z[nt][reg] - mu)*rv + lbv[nt]);
      msg[base + nt*16 + mcol] = f2bf_rne(o);
    }
  }
}

// ---- CSR phase 2: sequential span gather + fused BN-stat partials (atomic red) ----
__global__ __launch_bounds__(256) void k_gather(const unsigned short* __restrict__ msg,
    const int* __restrict__ pos, const float* __restrict__ degrees,
    float* __restrict__ rec, float* __restrict__ red){
  const int j = threadIdx.x & 127, sub = threadIdx.x >> 7;
  const int n0 = blockIdx.x * 32;
  float s1 = 0.f, s2 = 0.f;
  for (int i = 0; i < 16; ++i){
    int n = n0 + i*2 + sub;
    int a0 = (n == 0) ? 0 : pos[n-1];
    int a1 = pos[n];
    float acc = 0.f;
    for (int s = a0; s < a1; ++s)
      acc += bf2f(msg[(size_t)s*FEAT + j]);
    float v = acc / degrees[n];
    rec[n*FEAT + j] = v;
    s1 += v; s2 += v*v;
  }
  __shared__ float sh1[256], sh2[256];
  sh1[threadIdx.x] = s1; sh2[threadIdx.x] = s2;
  __syncthreads();
  if (sub == 0){
    atomicAdd(&red[j],       sh1[threadIdx.x] + sh1[threadIdx.x + 128]);
    atomicAdd(&red[128 + j], sh2[threadIdx.x] + sh2[threadIdx.x + 128]);
  }
}

// ================= fallback path (no CSR): R13 structure =================
#define FB_CORE() \
  __shared__ __align__(16) unsigned short Ubf[32*U_STRIDE]; \
  __shared__ float sS[64], sQ[64]; \
  __shared__ int sTa[32], sTb[32]; \
  const int tid = threadIdx.x; \
  const int m0 = blockIdx.x * 32; \
  if (tid < 32){ \
    int m = m0 + tid; \
    int e = (m < N_EDGES) ? m : (m - N_EDGES); \
    int l = idxL[e], r = idxR[e]; \
    sTa[tid] = (m < N_EDGES) ? l : r; \
    sTb[tid] = (m < N_EDGES) ? r : l; \
  } \
  __syncthreads(); \
  { \
    const int c8 = (tid & 15)*8, g16 = tid >> 4; \
    const float4 b1a = *(const float4*)&b1v[c8]; \
    const float4 b1b = *(const float4*)&b1v[c8 + 4]; \
    _Pragma("unroll") \
    for (int r = 0; r < 2; ++r){ \
      int row = r*16 + g16; \
      short8 pb = *(const short8*)&PQb[sTb[row]*(2*FEAT) + c8]; \
      short8 qb = *(const short8*)&PQb[sTa[row]*(2*FEAT) + FEAT + c8]; \
      ushort4v u0, u1; \
      u0.x = f2bf_rne(fmaxf(bf2f(pb[0]) + bf2f(qb[0]) + b1a.x, 0.f)); \
      u0.y = f2bf_rne(fmaxf(bf2f(pb[1]) + bf2f(qb[1]) + b1a.y, 0.f)); \
      u0.z = f2bf_rne(fmaxf(bf2f(pb[2]) + bf2f(qb[2]) + b1a.z, 0.f)); \
      u0.w = f2bf_rne(fmaxf(bf2f(pb[3]) + bf2f(qb[3]) + b1a.w, 0.f)); \
      u1.x = f2bf_rne(fmaxf(bf2f(pb[4]) + bf2f(qb[4]) + b1b.x, 0.f)); \
      u1.y = f2bf_rne(fmaxf(bf2f(pb[5]) + bf2f(qb[5]) + b1b.y, 0.f)); \
      u1.z = f2bf_rne(fmaxf(bf2f(pb[6]) + bf2f(qb[6]) + b1b.z, 0.f)); \
      u1.w = f2bf_rne(fmaxf(bf2f(pb[7]) + bf2f(qb[7]) + b1b.w, 0.f)); \
      *(ushort4v*)&Ubf[row*U_STRIDE + c8]     = u0; \
      *(ushort4v*)&Ubf[row*U_STRIDE + c8 + 4] = u1; \
    } \
  } \
  __syncthreads(); \
  const int w = tid >> 6, lane = tid & 63; \
  const int mt = w & 1, nhalf = w >> 1; \
  const int quad = lane >> 4, mcol = lane & 15; \
  floatx4 acc0 = {0.f,0.f,0.f,0.f}; \
  floatx4 acc1 = {0.f,0.f,0.f,0.f}; \
  floatx4 acc2 = {0.f,0.f,0.f,0.f}; \
  floatx4 acc3 = {0.f,0.f,0.f,0.f}; \
  _Pragma("unroll") \
  for (int ks = 0; ks < 4; ++ks){ \
    short8 a = *(const short8*)&Ubf[(mt*16 + mcol)*U_STRIDE + ks*32 + quad*8]; \
    const unsigned short* bp = W2pack + ((nhalf*4*256) + ks*64 + lane)*8; \
    short8 bq0 = *(const short8*)(bp); \
    short8 bq1 = *(const short8*)(bp + 2048); \
    short8 bq2 = *(const short8*)(bp + 4096); \
    short8 bq3 = *(const short8*)(bp + 6144); \
    acc0 = __builtin_amdgcn_mfma_f32_16x16x32_bf16(a, bq0, acc0, 0, 0, 0); \
    acc1 = __builtin_amdgcn_mfma_f32_16x16x32_bf16(a, bq1, acc1, 0, 0, 0); \
    acc2 = __builtin_amdgcn_mfma_f32_16x16x32_bf16(a, bq2, acc2, 0, 0, 0); \
    acc3 = __builtin_amdgcn_mfma_f32_16x16x32_bf16(a, bq3, acc3, 0, 0, 0); \
  } \
  float z[4][4]; \
  _Pragma("unroll") \
  for (int nt = 0; nt < 4; ++nt){ \
    floatx4 a4 = (nt == 0) ? acc0 : (nt == 1) ? acc1 : (nt == 2) ? acc2 : acc3; \
    float bb = b2v[nhalf*64 + nt*16 + mcol]; \
    _Pragma("unroll") \
    for (int reg = 0; reg < 4; ++reg) z[nt][reg] = fmaxf(a4[reg] + bb, 0.f); \
  } \
  float ps[4], pq[4]; \
  _Pragma("unroll") \
  for (int reg = 0; reg < 4; ++reg){ \
    ps[reg] = z[0][reg] + z[1][reg] + z[2][reg] + z[3][reg]; \
    pq[reg] = z[0][reg]*z[0][reg] + z[1][reg]*z[1][reg] + z[2][reg]*z[2][reg] + z[3][reg]*z[3][reg]; \
  } \
  _Pragma("unroll") \
  for (int o = 1; o < 16; o <<= 1){ \
    _Pragma("unroll") \
    for (int reg = 0; reg < 4; ++reg){ \
      ps[reg] += __shfl_xor(ps[reg], o); \
      pq[reg] += __shfl_xor(pq[reg], o); \
    } \
  } \
  if (mcol == 0){ \
    _Pragma("unroll") \
    for (int reg = 0; reg < 4; ++reg){ \
      int row = mt*16 + quad*4 + reg; \
      sS[nhalf*32 + row] = ps[reg]; \
      sQ[nhalf*32 + row] = pq[reg]; \
    } \
  } \
  __syncthreads(); \
  int colv[4]; float lgv[4], lbv[4]; \
  _Pragma("unroll") \
  for (int nt = 0; nt < 4; ++nt){ \
    colv[nt] = nhalf*64 + nt*16 + mcol; \
    lgv[nt] = ln_g[colv[nt]]; \
    lbv[nt] = ln_b[colv[nt]]; \
  } \
  float muv[4], rvv[4]; \
  _Pragma("unroll") \
  for (int reg = 0; reg < 4; ++reg){ \
    int row = mt*16 + quad*4 + reg; \
    float s = sS[row] + sS[32 + row]; \
    float q = sQ[row] + sQ[32 + row]; \
    float mu = s * (1.f/FEAT); \
    float var = fmaxf(q * (1.f/FEAT) - mu*mu, 0.f); \
    muv[reg] = mu; \
    rvv[reg] = rsqrtf(var + EPSF); \
  }

__global__ __launch_bounds__(256) void k_edge(const unsigned short* __restrict__ PQb,
    const unsigned short* __restrict__ W2pack, const float* __restrict__ b1v,
    const float* __restrict__ b2v, const float* __restrict__ ln_g, const float* __restrict__ ln_b,
    const int* __restrict__ idxL, const int* __restrict__ idxR,
    float* __restrict__ agg){
  FB_CORE()
#pragma unroll
  for (int reg = 0; reg < 4; ++reg){
    int row = mt*16 + quad*4 + reg;
    int a = sTa[row];
#pragma unroll
    for (int nt = 0; nt < 4; ++nt){
      float o = scrub0(lgv[nt]*(z[nt][reg] - muv[reg])*rvv[reg] + lbv[nt]);
      atomicAdd(&agg[a*FEAT + colv[nt]], o);
    }
  }
}

__global__ __launch_bounds__(256) void k_stats(const float* __restrict__ src,
    const float* __restrict__ degrees, float* __restrict__ red){
  const int tid = threadIdx.x;
  const int j = tid & 127, half_sel = tid >> 7;
  const int n0 = blockIdx.x * 256;
  float s1 = 0.f, s2 = 0.f;
  for (int i = half_sel; i < 256; i += 2){
    int n = n0 + i;
    if (n < N_VARS){
      float v = src[n*FEAT + j] / degrees[n];
      s1 += v;
      s2 += v*v;
    }
  }
  __shared__ float sh1[256], sh2[256];
  sh1[tid] = s1; sh2[tid] = s2;
  __syncthreads();
  if (half_sel == 0){
    atomicAdd(&red[j],       sh1[tid] + sh1[tid+128]);
    atomicAdd(&red[128 + j], sh2[tid] + sh2[tid+128]);
  }
}

// ---- BN apply + logits + softmax + argmax; bf16 state out ----
__global__ __launch_bounds__(256) void k_bn(const float* __restrict__ src,
    const float* __restrict__ degrees, int divide, const float* __restrict__ red,
    const float* __restrict__ bn_g, const float* __restrict__ bn_b,
    const float* __restrict__ Wd, const float* __restrict__ bd,
    unsigned short* __restrict__ state_bf, int* __restrict__ asg,
    float* __restrict__ out_phi, float* __restrict__ out_asg, int t){
  const int w = threadIdx.x >> 6, l = threadIdx.x & 63;
  const int n = blockIdx.x*4 + w;
  const float invN = 1.f / (float)N_VARS;
  float mu0 = red[l]*invN,     mu1 = red[l+64]*invN;
  float v0  = fmaxf(red[128+l]*invN    - mu0*mu0, 0.f);
  float v1  = fmaxf(red[128+l+64]*invN - mu1*mu1, 0.f);
  float rv0 = rsqrtf(v0 + EPSF);
  float rv1 = rsqrtf(v1 + EPSF);
  float dinv = divide ? (1.f / degrees[n]) : 1.f;
  float r0 = src[n*FEAT + l]    * dinv;
  float r1 = src[n*FEAT + l+64] * dinv;
  float s0 = scrub0(bn_g[l]   *(r0 - mu0)*rv0 + bn_b[l]);
  float s1 = scrub0(bn_g[l+64]*(r1 - mu1)*rv1 + bn_b[l+64]);
  state_bf[n*FEAT + l]    = f2bf_rne(s0);
  state_bf[n*FEAT + l+64] = f2bf_rne(s1);
  float p[4];
#pragma unroll
  for (int d = 0; d < 4; ++d)
    p[d] = s0*Wd[l*4 + d] + s1*Wd[(l+64)*4 + d];
#pragma unroll
  for (int o = 32; o > 0; o >>= 1){
#pragma unroll
    for (int d = 0; d < 4; ++d) p[d] += __shfl_xor(p[d], o);
  }
  if (l == 0){
    float lg[4];
#pragma unroll
    for (int d = 0; d < 4; ++d) lg[d] = scrub0(p[d] + bd[d]);
    float mx = fmaxf(fmaxf(lg[0],lg[1]), fmaxf(lg[2],lg[3]));
    float ex[4]; float ssum = 0.f;
#pragma unroll
    for (int d = 0; d < 4; ++d){ ex[d] = expf(lg[d] - mx); ssum += ex[d]; }
    float inv = 1.f / ssum;
    int am = 0; float bv = -1.f;
#pragma unroll
    for (int d = 0; d < 4; ++d){
      float pv = scrub0(ex[d]*inv);
      out_phi[n*12 + t*4 + d] = pv;
      if (pv > bv){ bv = pv; am = d; }
    }
    asg[n*3 + t] = am;
    if (t == 2) out_asg[n] = (float)am;
  }
}

// ---- merged pair-losses + edge-conflicts (blocks >= NB_LOSS do conf) ----
__global__ __launch_bounds__(256) void k_lossconf(const float* __restrict__ phi,
    const int* __restrict__ iL, const int* __restrict__ iR,
    const int* __restrict__ iLp, const int* __restrict__ iRp,
    const float* __restrict__ rel, const float* __restrict__ conf,
    const int* __restrict__ asg, float* __restrict__ out_ec,
    float* __restrict__ part_l1, float* __restrict__ part_l2,
    float* __restrict__ part_conf){
  if (blockIdx.x < NB_LOSS){
    const int m = blockIdx.x*256 + threadIdx.x;
    float p1 = 0.f, p2 = 0.f;
    if (m < N_EDGES*3){
      int e = m/3, tt = m - e*3;
      const float* pl = phi + iL[e]*12 + tt*4;
      const float* pr = phi + iR[e]*12 + tt*4;
      float s = 0.f;
#pragma unroll
      for (int j = 0; j < 4; ++j){
        float tj = 0.f;
#pragma unroll
        for (int i = 0; i < 4; ++i) tj += pl[i]*rel[i*4+j];
        s += tj*pr[j];
      }
      s = scrub0(s); s = fmaxf(s, 1e-35f);
      p1 = -logf(s);
    } else {
      int m2 = m - N_EDGES*3;
      if (m2 < N_CONFP*3){
        int e = m2/3, tt = m2 - e*3;
        const float* pl = phi + iLp[e]*12 + tt*4;
        const float* pr = phi + iRp[e]*12 + tt*4;
        float s = 0.f;
#pragma unroll
        for (int j = 0; j < 4; ++j){
          float tj = 0.f;
#pragma unroll
          for (int i = 0; i < 4; ++i) tj += pl[i]*conf[i*4+j];
          s += tj*pr[j];
        }
        s = scrub0(s); s = fmaxf(s, 1e-35f);
        p2 = -logf(s);
      }
    }
    __shared__ float sh1[256], sh2[256];
    sh1[threadIdx.x] = p1; sh2[threadIdx.x] = p2;
    __syncthreads();
    for (int k = 128; k > 0; k >>= 1){
      if (threadIdx.x < k){
        sh1[threadIdx.x] += sh1[threadIdx.x + k];
        sh2[threadIdx.x] += sh2[threadIdx.x + k];
      }
      __syncthreads();
    }
    if (threadIdx.x == 0){
      part_l1[blockIdx.x] = sh1[0];
      part_l2[blockIdx.x] = sh2[0];
    }
  } else {
    const int bid = blockIdx.x - NB_LOSS;
    const int e = bid*256 + threadIdx.x;
    float c2 = 0.f;
    if (e < N_EDGES){
      int l = iL[e], r = iR[e];
#pragma unroll
      for (int tt = 0; tt < 3; ++tt){
        int ai = asg[l*3+tt] & 3, bi = asg[r*3+tt] & 3;
        float c = scrub0(1.f - rel[ai*4 + bi]);
        out_ec[e*3 + tt] = c;
        if (tt == 2) c2 = c;
      }
    }
    __shared__ float sh[256];
    sh[threadIdx.x] = c2;
    __syncthreads();
    for (int k = 128; k > 0; k >>= 1){
      if (threadIdx.x < k) sh[threadIdx.x] += sh[threadIdx.x + k];
      __syncthreads();
    }
    if (threadIdx.x == 0) part_conf[bid] = sh[0];
  }
}

// ---- final scalar reduce -> out[0], out[1], out[NCONF_SLOT] ----
__global__ __launch_bounds__(256) void k_fin(const float* __restrict__ part_conf,
    const float* __restrict__ part_l1, const float* __restrict__ part_l2,
    float* __restrict__ out){
  const int tid = threadIdx.x;
  float a = 0.f, ca = 0.f, b = 0.f, cb = 0.f, c = 0.f;
  for (int i = tid; i < NB_LOSS; i += 256){
    float y = part_l1[i] - ca; float t = a + y; ca = (t - a) - y; a = t;
    float y2 = part_l2[i] - cb; float t2 = b + y2; cb = (t2 - b) - y2; b = t2;
  }
  for (int i = tid; i < NB_CONF; i += 256) c += part_conf[i];
  __shared__ float sh1[256], sh2[256], sh3[256];
  sh1[tid] = a; sh2[tid] = b; sh3[tid] = c;
  __syncthreads();
  for (int k = 128; k > 0; k >>= 1){
    if (tid < k){
      sh1[tid] += sh1[tid + k];
      sh2[tid] += sh2[tid + k];
      sh3[tid] += sh3[tid + k];
    }
    __syncthreads();
  }
  if (tid == 0){
    out[0] = sh1[0]/(float)N_EDGES + sh2[0]/(10.f*(float)N_CONFP);
    float nc = sh3[0];
    out[NCONF_SLOT] = nc;
    out[1] = nc / (float)N_EDGES;
  }
}

extern "C" void kernel_launch(void* const* d_in, const int* in_sizes, int n_in,
                              void* d_out, int out_size, void* d_ws, size_t ws_size,
                              hipStream_t stream){
  const float* state0  = (const float*)d_in[0];
  const float* W1      = (const float*)d_in[1];
  const float* b1v     = (const float*)d_in[2];
  const float* W2      = (const float*)d_in[3];
  const float* b2v     = (const float*)d_in[4];
  const float* ln_g    = (const float*)d_in[5];
  const float* ln_b    = (const float*)d_in[6];
  const float* bn_g    = (const float*)d_in[7];
  const float* bn_b    = (const float*)d_in[8];
  const float* Wd      = (const float*)d_in[9];
  const float* bd      = (const float*)d_in[10];
  const float* rel     = (const float*)d_in[11];
  const float* confm   = (const float*)d_in[12];
  const float* degrees = (const float*)d_in[13];
  const int* idxL = (const int*)d_in[14];
  const int* idxR = (const int*)d_in[15];
  const int* iLp  = (const int*)d_in[16];
  const int* iRp  = (const int*)d_in[17];

  char* ws = (char*)d_ws;
  unsigned short* state_bf = (unsigned short*)(ws);          // 10,240,000
  unsigned short* PQb  = (unsigned short*)(ws + 10240000);   // 20,480,000
  float*  recagg    = (float*)(ws + 30720000);               // 20,480,000
  int*    asg       = (int*)  (ws + 51200000);               //    480,000
  float*  red       = (float*)(ws + 51840768);               //      1,024
  float*  part_l1   = (float*)(ws + 51841792);               //     14,068
  float*  part_l2   = (float*)(ws + 51855860);               //     14,068
  float*  part_conf = (float*)(ws + 51869928);               //      3,128
  unsigned short* W2pack = (unsigned short*)(ws + 51873056); //     32,768
  unsigned short* W1pack = (unsigned short*)(ws + 51905824); //     65,536
  int*    pos       = (int*)(ws + 51971360);                 //    160,000
  int*    cnt       = (int*)(ws + 52131360);                 //    160,000
  int*    mslot     = (int*)(ws + 52291360);                 //  1,600,000
  int*    blk_tot   = (int*)(ws + 53891360);                 //      1,024
  int*    blk_off   = (int*)(ws + 53892384);                 //      1,024
  unsigned short* msg = (unsigned short*)(ws + 53893408);    // 102,400,000
  const int use_csr = (ws_size >= (size_t)156451376) ? 1 : 0;

  float* out     = (float*)d_out;
  float* out_phi = out + 2;
  float* out_ec  = out + 480002;
  float* out_asg = out + 1080002;

  k_prep<<<8, 256, 0, stream>>>(W2, W2pack);
  k_prep_w1<<<16, 256, 0, stream>>>(W1, W1pack);

  if (use_csr){
    k_zero_int<<<NB_STAT, 256, 0, stream>>>(cnt, N_VARS);
    k_hist<<<(N_MSG + 255)/256, 256, 0, stream>>>(idxL, idxR, cnt);
    k_scan1<<<NB_STAT, 256, 0, stream>>>(cnt, pos, blk_tot);
    k_scan2<<<1, 256, 0, stream>>>(blk_tot, blk_off);
    k_scan3<<<NB_STAT, 256, 0, stream>>>(pos, blk_off);
    k_fill<<<(N_MSG + 255)/256, 256, 0, stream>>>(idxL, idxR, pos, mslot);
  }

  for (int t = 0; t < T_ITERS; ++t){
    k_pq<<<N_VARS/32, 256, 0, stream>>>(state0, state_bf, (t == 0) ? 1 : 0, W1pack, PQb, red);
    if (use_csr){
      k_msg<<<N_MSG/64, 256, 0, stream>>>(PQb, W2pack, b1v, b2v, ln_g, ln_b, idxL, idxR, mslot, msg);
      k_gather<<<NB_GATH, 256, 0, stream>>>(msg, pos, degrees, recagg, red);
      k_bn<<<N_VARS/4, 256, 0, stream>>>(recagg, degrees, 0, red, bn_g, bn_b, Wd, bd,
                                         state_bf, asg, out_phi, out_asg, t);
    } else {
      k_zero_agg<<<5000, 256, 0, stream>>>((float4*)recagg);
      k_edge<<<N_MSG/32, 256, 0, stream>>>(PQb, W2pack, b1v, b2v, ln_g, ln_b, idxL, idxR, recagg);
      k_stats<<<NB_STAT, 256, 0, stream>>>(recagg, degrees, red);
      k_bn<<<N_VARS/4, 256, 0, stream>>>(recagg, degrees, 1, red, bn_g, bn_b, Wd, bd,
                                         state_bf, asg, out_phi, out_asg, t);
    }
  }
  k_lossconf<<<NB_LOSS + NB_CONF, 256, 0, stream>>>(out_phi, idxL, idxR, iLp, iRp, rel, confm,
                                                    asg, out_ec, part_l1, part_l2, part_conf);
  k_fin<<<1, 256, 0, stream>>>(part_conf, part_l1, part_l2, out);
}

// Round 15
// 670.146 us; speedup vs baseline: 1.4435x; 1.0367x over previous
//
#include <hip/hip_runtime.h>
#include <math.h>

#define N_VARS 40000
#define FEAT 128
#define N_EDGES 200000
#define N_MSG (2*N_EDGES)
#define N_CONFP 100000
#define T_ITERS 3
#define EPSF 1e-5f

#define NB_CONF 782              // ceil(200000/256)
#define NB_LOSS 3517             // ceil(900000/256)
#define NB_STAT 157              // ceil(40000/256)
#define NB_GATH 2500             // 40000 / (4 waves * 4 nodes)
#define OUT_TOTAL 1120003
#define NCONF_SLOT 1120002       // sequential carve: 1+1+480000+600000+40000

typedef short short8 __attribute__((ext_vector_type(8)));
typedef float floatx4 __attribute__((ext_vector_type(4)));
typedef unsigned short ushort4v __attribute__((ext_vector_type(4)));

__device__ __forceinline__ float scrub0(float x){
  unsigned u = __float_as_uint(x);
  return ((u & 0x7F800000u) == 0x7F800000u) ? 0.f : x;
}
__device__ __forceinline__ unsigned short f2bf_rne(float x){
  unsigned u = __float_as_uint(x);
  u += 0x7FFFu + ((u >> 16) & 1u);
  return (unsigned short)(u >> 16);
}
__device__ __forceinline__ float bf2f(unsigned short h){
  return __uint_as_float(((unsigned)h) << 16);
}

__global__ __launch_bounds__(256) void k_zero_agg(float4* __restrict__ p){
  p[blockIdx.x*256 + threadIdx.x] = make_float4(0.f,0.f,0.f,0.f);
}
__global__ __launch_bounds__(256) void k_zero_int(int* __restrict__ p, int n){
  int i = blockIdx.x*256 + threadIdx.x;
  if (i < n) p[i] = 0;
}

// ---- CSR build over message ids m in [0,2E): target = m<E ? idxL[m] : idxR[m-E]
__global__ __launch_bounds__(256) void k_hist(const int* __restrict__ idxL,
    const int* __restrict__ idxR, int* __restrict__ cnt){
  int m = blockIdx.x*256 + threadIdx.x;
  if (m < N_MSG){
    int t = (m < N_EDGES) ? idxL[m] : idxR[m - N_EDGES];
    atomicAdd(&cnt[t], 1);
  }
}
__global__ __launch_bounds__(256) void k_scan1(const int* __restrict__ cnt,
    int* __restrict__ pos, int* __restrict__ blk_tot){
  const int tid = threadIdx.x;
  const int idx = blockIdx.x*256 + tid;
  int v = (idx < N_VARS) ? cnt[idx] : 0;
  __shared__ int sh[256];
  sh[tid] = v;
  __syncthreads();
#pragma unroll
  for (int o = 1; o < 256; o <<= 1){
    int add = (tid >= o) ? sh[tid - o] : 0;
    __syncthreads();
    sh[tid] += add;
    __syncthreads();
  }
  if (idx < N_VARS) pos[idx] = sh[tid] - v;
  if (tid == 255) blk_tot[blockIdx.x] = sh[255];
}
__global__ __launch_bounds__(256) void k_scan2(const int* __restrict__ blk_tot,
    int* __restrict__ blk_off){
  const int tid = threadIdx.x;
  int v = (tid < NB_STAT) ? blk_tot[tid] : 0;
  __shared__ int sh[256];
  sh[tid] = v;
  __syncthreads();
#pragma unroll
  for (int o = 1; o < 256; o <<= 1){
    int add = (tid >= o) ? sh[tid - o] : 0;
    __syncthreads();
    sh[tid] += add;
    __syncthreads();
  }
  if (tid < NB_STAT) blk_off[tid] = sh[tid] - v;
}
__global__ __launch_bounds__(256) void k_scan3(int* __restrict__ pos,
    const int* __restrict__ blk_off){
  const int idx = blockIdx.x*256 + threadIdx.x;
  if (idx < N_VARS) pos[idx] += blk_off[blockIdx.x];
}
__global__ __launch_bounds__(256) void k_fill(const int* __restrict__ idxL,
    const int* __restrict__ idxR, int* __restrict__ pos, int* __restrict__ mslot){
  int m = blockIdx.x*256 + threadIdx.x;
  if (m < N_MSG){
    int t = (m < N_EDGES) ? idxL[m] : idxR[m - N_EDGES];
    mslot[m] = atomicAdd(&pos[t], 1);
  }
}

// ---- pack W2 (128x128 f32) into B-fragment-ordered bf16 (8 ntiles) ----
__global__ __launch_bounds__(256) void k_prep(const float* __restrict__ W2,
                                              unsigned short* __restrict__ W2pack){
  int gid = blockIdx.x*256 + threadIdx.x;
  int lane = gid & 63;
  int ks = (gid >> 6) & 3;
  int ntg = gid >> 8;
  int kbase = ks*32 + (lane >> 4)*8;
  int n = ntg*16 + (lane & 15);
#pragma unroll
  for (int j = 0; j < 8; ++j)
    W2pack[gid*8 + j] = f2bf_rne(W2[(kbase + j)*FEAT + n]);
}
__global__ __launch_bounds__(256) void k_prep_w1(const float* __restrict__ W1,
                                                 unsigned short* __restrict__ W1pack){
  int gid = blockIdx.x*256 + threadIdx.x;
  int lane = gid & 63;
  int ks = (gid >> 6) & 3;
  int ntg = gid >> 8;
  int kbase = ks*32 + (lane >> 4)*8;
  int n = ntg*16 + (lane & 15);
#pragma unroll
  for (int j = 0; j < 8; ++j){
    int k = kbase + j;
    float v = (n < 128) ? W1[k*FEAT + n] : W1[(128 + k)*FEAT + (n - 128)];
    W1pack[gid*8 + j] = f2bf_rne(v);
  }
}

// ---- PQ = x @ [W1top | W1bot] via MFMA bf16 -> bf16 store; also zeroes red ----
#define X_STRIDE 136
__global__ __launch_bounds__(256) void k_pq(const float* __restrict__ xf,
                                            const unsigned short* __restrict__ xb,
                                            int src_f32,
                                            const unsigned short* __restrict__ W1pack,
                                            unsigned short* __restrict__ PQb,
                                            float* __restrict__ red){
  __shared__ __align__(16) unsigned short Xbf[32*X_STRIDE];
  const int tid = threadIdx.x;
  const int row0 = blockIdx.x * 32;
  if (blockIdx.x == 0) red[tid] = 0.f;
  if (src_f32){
    const int c4 = (tid & 31)*4, g8 = tid >> 5;
#pragma unroll
    for (int r = 0; r < 4; ++r){
      int row = g8*4 + r;
      const float4 v = *(const float4*)&xf[(row0 + row)*FEAT + c4];
      ushort4v u;
      u.x = f2bf_rne(v.x); u.y = f2bf_rne(v.y);
      u.z = f2bf_rne(v.z); u.w = f2bf_rne(v.w);
      *(ushort4v*)&Xbf[row*X_STRIDE + c4] = u;
    }
  } else {
    const int c8 = (tid & 15)*8, g16 = tid >> 4;
#pragma unroll
    for (int r = 0; r < 2; ++r){
      int row = r*16 + g16;
      *(short8*)&Xbf[row*X_STRIDE + c8] = *(const short8*)&xb[(row0 + row)*FEAT + c8];
    }
  }
  __syncthreads();
  const int w = tid >> 6, lane = tid & 63;
  const int quad = lane >> 4, mcol = lane & 15;
#pragma unroll
  for (int mt = 0; mt < 2; ++mt){
    floatx4 a0 = {0.f,0.f,0.f,0.f};
    floatx4 a1 = {0.f,0.f,0.f,0.f};
    floatx4 a2 = {0.f,0.f,0.f,0.f};
    floatx4 a3 = {0.f,0.f,0.f,0.f};
#pragma unroll
    for (int ks = 0; ks < 4; ++ks){
      short8 a = *(const short8*)&Xbf[(mt*16 + mcol)*X_STRIDE + ks*32 + quad*8];
      const unsigned short* bp = W1pack + ((w*16 + ks)*64 + lane)*8;
      short8 b0 = *(const short8*)(bp);
      short8 b1 = *(const short8*)(bp + 2048);
      short8 b2 = *(const short8*)(bp + 4096);
      short8 b3 = *(const short8*)(bp + 6144);
      a0 = __builtin_amdgcn_mfma_f32_16x16x32_bf16(a, b0, a0, 0, 0, 0);
      a1 = __builtin_amdgcn_mfma_f32_16x16x32_bf16(a, b1, a1, 0, 0, 0);
      a2 = __builtin_amdgcn_mfma_f32_16x16x32_bf16(a, b2, a2, 0, 0, 0);
      a3 = __builtin_amdgcn_mfma_f32_16x16x32_bf16(a, b3, a3, 0, 0, 0);
    }
#pragma unroll
    for (int nt = 0; nt < 4; ++nt){
      floatx4 acc = (nt == 0) ? a0 : (nt == 1) ? a1 : (nt == 2) ? a2 : a3;
      int n = w*64 + nt*16 + mcol;
#pragma unroll
      for (int reg = 0; reg < 4; ++reg)
        PQb[(row0 + mt*16 + quad*4 + reg)*(2*FEAT) + n] = f2bf_rne(acc[reg]);
    }
  }
}

#define U_STRIDE 136   // bf16 elems

// ---- CSR phase 1: 64 msgs/block; each wave owns 16 complete rows ----
__global__ __launch_bounds__(256) void k_msg(const unsigned short* __restrict__ PQb,
    const unsigned short* __restrict__ W2pack, const float* __restrict__ b1v,
    const float* __restrict__ b2v, const float* __restrict__ ln_g, const float* __restrict__ ln_b,
    const int* __restrict__ idxL, const int* __restrict__ idxR,
    const int* __restrict__ mslot, unsigned short* __restrict__ msg){
  __shared__ __align__(16) unsigned short Ubf[64*U_STRIDE];
  __shared__ int sTa[64], sTb[64];
  const int tid = threadIdx.x;
  const int m0 = blockIdx.x * 64;
  if (tid < 64){
    int m = m0 + tid;
    int e = (m < N_EDGES) ? m : (m - N_EDGES);
    int l = idxL[e], r = idxR[e];
    sTa[tid] = (m < N_EDGES) ? l : r;
    sTb[tid] = (m < N_EDGES) ? r : l;
  }
  __syncthreads();
  {
    const int c8 = (tid & 15)*8, g16 = tid >> 4;
    const float4 b1a = *(const float4*)&b1v[c8];
    const float4 b1b = *(const float4*)&b1v[c8 + 4];
    short8 pb[4], qb[4];
#pragma unroll
    for (int r = 0; r < 4; ++r){
      int row = r*16 + g16;
      pb[r] = *(const short8*)&PQb[sTb[row]*(2*FEAT) + c8];
      qb[r] = *(const short8*)&PQb[sTa[row]*(2*FEAT) + FEAT + c8];
    }
#pragma unroll
    for (int r = 0; r < 4; ++r){
      int row = r*16 + g16;
      ushort4v u0, u1;
      u0.x = f2bf_rne(fmaxf(bf2f(pb[r][0]) + bf2f(qb[r][0]) + b1a.x, 0.f));
      u0.y = f2bf_rne(fmaxf(bf2f(pb[r][1]) + bf2f(qb[r][1]) + b1a.y, 0.f));
      u0.z = f2bf_rne(fmaxf(bf2f(pb[r][2]) + bf2f(qb[r][2]) + b1a.z, 0.f));
      u0.w = f2bf_rne(fmaxf(bf2f(pb[r][3]) + bf2f(qb[r][3]) + b1a.w, 0.f));
      u1.x = f2bf_rne(fmaxf(bf2f(pb[r][4]) + bf2f(qb[r][4]) + b1b.x, 0.f));
      u1.y = f2bf_rne(fmaxf(bf2f(pb[r][5]) + bf2f(qb[r][5]) + b1b.y, 0.f));
      u1.z = f2bf_rne(fmaxf(bf2f(pb[r][6]) + bf2f(qb[r][6]) + b1b.z, 0.f));
      u1.w = f2bf_rne(fmaxf(bf2f(pb[r][7]) + bf2f(qb[r][7]) + b1b.w, 0.f));
      *(ushort4v*)&Ubf[row*U_STRIDE + c8]     = u0;
      *(ushort4v*)&Ubf[row*U_STRIDE + c8 + 4] = u1;
    }
  }
  __syncthreads();
  const int w = tid >> 6, lane = tid & 63;
  const int quad = lane >> 4, mcol = lane & 15;
  const int rbase = w*16;
  floatx4 acc[8];
#pragma unroll
  for (int nt = 0; nt < 8; ++nt) acc[nt] = (floatx4){0.f,0.f,0.f,0.f};
#pragma unroll
  for (int ks = 0; ks < 4; ++ks){
    short8 a = *(const short8*)&Ubf[(rbase + mcol)*U_STRIDE + ks*32 + quad*8];
#pragma unroll
    for (int nt = 0; nt < 8; ++nt){
      short8 b = *(const short8*)(W2pack + ((nt*4 + ks)*64 + lane)*8);
      acc[nt] = __builtin_amdgcn_mfma_f32_16x16x32_bf16(a, b, acc[nt], 0, 0, 0);
    }
  }
  float z[8][4];
#pragma unroll
  for (int nt = 0; nt < 8; ++nt){
    float bb = b2v[nt*16 + mcol];
#pragma unroll
    for (int reg = 0; reg < 4; ++reg) z[nt][reg] = fmaxf(acc[nt][reg] + bb, 0.f);
  }
  float ps[4], pq[4];
#pragma unroll
  for (int reg = 0; reg < 4; ++reg){
    ps[reg] = 0.f; pq[reg] = 0.f;
#pragma unroll
    for (int nt = 0; nt < 8; ++nt){
      ps[reg] += z[nt][reg];
      pq[reg] += z[nt][reg]*z[nt][reg];
    }
  }
#pragma unroll
  for (int o = 1; o < 16; o <<= 1){
#pragma unroll
    for (int reg = 0; reg < 4; ++reg){
      ps[reg] += __shfl_xor(ps[reg], o);
      pq[reg] += __shfl_xor(pq[reg], o);
    }
  }
  float lgv[8], lbv[8];
#pragma unroll
  for (int nt = 0; nt < 8; ++nt){
    lgv[nt] = ln_g[nt*16 + mcol];
    lbv[nt] = ln_b[nt*16 + mcol];
  }
#pragma unroll
  for (int reg = 0; reg < 4; ++reg){
    int row = rbase + quad*4 + reg;
    float mu = ps[reg] * (1.f/FEAT);
    float var = fmaxf(pq[reg] * (1.f/FEAT) - mu*mu, 0.f);
    float rv = rsqrtf(var + EPSF);
    size_t base = (size_t)mslot[m0 + row]*FEAT;
#pragma unroll
    for (int nt = 0; nt < 8; ++nt){
      float o = scrub0(lgv[nt]*(z[nt][reg] - mu)*rv + lbv[nt]);
      msg[base + nt*16 + mcol] = f2bf_rne(o);
    }
  }
}

// ---- CSR phase 2: one wave per 4 nodes; 16B short8 loads, 4 span rows in flight ----
// lane = srow(0..3)*16 + jg(0..15); jg covers features jg*8..jg*8+7
__global__ __launch_bounds__(256) void k_gather(const unsigned short* __restrict__ msg,
    const int* __restrict__ pos, const float* __restrict__ degrees,
    float* __restrict__ rec, float* __restrict__ red){
  const int wv = threadIdx.x >> 6, lane = threadIdx.x & 63;
  const int srow = lane >> 4, jg = lane & 15;
  const int gw = blockIdx.x*4 + wv;     // global wave id, 0..9999
  float s1[8], s2[8];
#pragma unroll
  for (int k = 0; k < 8; ++k){ s1[k] = 0.f; s2[k] = 0.f; }
#pragma unroll
  for (int i = 0; i < 4; ++i){
    int n = gw*4 + i;
    int a0 = (n == 0) ? 0 : pos[n-1];
    int a1 = pos[n];
    float acc[8];
#pragma unroll
    for (int k = 0; k < 8; ++k) acc[k] = 0.f;
    for (int s = a0 + srow; s < a1; s += 4){
      short8 row = *(const short8*)&msg[(size_t)s*FEAT + jg*8];
#pragma unroll
      for (int k = 0; k < 8; ++k) acc[k] += bf2f((unsigned short)row[k]);
    }
#pragma unroll
    for (int k = 0; k < 8; ++k){
      acc[k] += __shfl_xor(acc[k], 16);
      acc[k] += __shfl_xor(acc[k], 32);
    }
    if (srow == 0){
      float dinv = 1.f / degrees[n];
      float4 v0, v1;
      v0.x = acc[0]*dinv; v0.y = acc[1]*dinv; v0.z = acc[2]*dinv; v0.w = acc[3]*dinv;
      v1.x = acc[4]*dinv; v1.y = acc[5]*dinv; v1.z = acc[6]*dinv; v1.w = acc[7]*dinv;
      *(float4*)&rec[n*FEAT + jg*8]     = v0;
      *(float4*)&rec[n*FEAT + jg*8 + 4] = v1;
      s1[0] += v0.x; s2[0] += v0.x*v0.x;
      s1[1] += v0.y; s2[1] += v0.y*v0.y;
      s1[2] += v0.z; s2[2] += v0.z*v0.z;
      s1[3] += v0.w; s2[3] += v0.w*v0.w;
      s1[4] += v1.x; s2[4] += v1.x*v1.x;
      s1[5] += v1.y; s2[5] += v1.y*v1.y;
      s1[6] += v1.z; s2[6] += v1.z*v1.z;
      s1[7] += v1.w; s2[7] += v1.w*v1.w;
    }
  }
  __shared__ float shs[4][128], shq[4][128];
  if (srow == 0){
#pragma unroll
    for (int k = 0; k < 8; ++k){
      shs[wv][jg*8 + k] = s1[k];
      shq[wv][jg*8 + k] = s2[k];
    }
  }
  __syncthreads();
  if (threadIdx.x < 128){
    int j = threadIdx.x;
    atomicAdd(&red[j],       shs[0][j] + shs[1][j] + shs[2][j] + shs[3][j]);
    atomicAdd(&red[128 + j], shq[0][j] + shq[1][j] + shq[2][j] + shq[3][j]);
  }
}

// ================= fallback path (no CSR): R13 structure =================
#define FB_CORE() \
  __shared__ __align__(16) unsigned short Ubf[32*U_STRIDE]; \
  __shared__ float sS[64], sQ[64]; \
  __shared__ int sTa[32], sTb[32]; \
  const int tid = threadIdx.x; \
  const int m0 = blockIdx.x * 32; \
  if (tid < 32){ \
    int m = m0 + tid; \
    int e = (m < N_EDGES) ? m : (m - N_EDGES); \
    int l = idxL[e], r = idxR[e]; \
    sTa[tid] = (m < N_EDGES) ? l : r; \
    sTb[tid] = (m < N_EDGES) ? r : l; \
  } \
  __syncthreads(); \
  { \
    const int c8 = (tid & 15)*8, g16 = tid >> 4; \
    const float4 b1a = *(const float4*)&b1v[c8]; \
    const float4 b1b = *(const float4*)&b1v[c8 + 4]; \
    _Pragma("unroll") \
    for (int r = 0; r < 2; ++r){ \
      int row = r*16 + g16; \
      short8 pb = *(const short8*)&PQb[sTb[row]*(2*FEAT) + c8]; \
      short8 qb = *(const short8*)&PQb[sTa[row]*(2*FEAT) + FEAT + c8]; \
      ushort4v u0, u1; \
      u0.x = f2bf_rne(fmaxf(bf2f(pb[0]) + bf2f(qb[0]) + b1a.x, 0.f)); \
      u0.y = f2bf_rne(fmaxf(bf2f(pb[1]) + bf2f(qb[1]) + b1a.y, 0.f)); \
      u0.z = f2bf_rne(fmaxf(bf2f(pb[2]) + bf2f(qb[2]) + b1a.z, 0.f)); \
      u0.w = f2bf_rne(fmaxf(bf2f(pb[3]) + bf2f(qb[3]) + b1a.w, 0.f)); \
      u1.x = f2bf_rne(fmaxf(bf2f(pb[4]) + bf2f(qb[4]) + b1b.x, 0.f)); \
      u1.y = f2bf_rne(fmaxf(bf2f(pb[5]) + bf2f(qb[5]) + b1b.y, 0.f)); \
      u1.z = f2bf_rne(fmaxf(bf2f(pb[6]) + bf2f(qb[6]) + b1b.z, 0.f)); \
      u1.w = f2bf_rne(fmaxf(bf2f(pb[7]) + bf2f(qb[7]) + b1b.w, 0.f)); \
      *(ushort4v*)&Ubf[row*U_STRIDE + c8]     = u0; \
      *(ushort4v*)&Ubf[row*U_STRIDE + c8 + 4] = u1; \
    } \
  } \
  __syncthreads(); \
  const int w = tid >> 6, lane = tid & 63; \
  const int mt = w & 1, nhalf = w >> 1; \
  const int quad = lane >> 4, mcol = lane & 15; \
  floatx4 acc0 = {0.f,0.f,0.f,0.f}; \
  floatx4 acc1 = {0.f,0.f,0.f,0.f}; \
  floatx4 acc2 = {0.f,0.f,0.f,0.f}; \
  floatx4 acc3 = {0.f,0.f,0.f,0.f}; \
  _Pragma("unroll") \
  for (int ks = 0; ks < 4; ++ks){ \
    short8 a = *(const short8*)&Ubf[(mt*16 + mcol)*U_STRIDE + ks*32 + quad*8]; \
    const unsigned short* bp = W2pack + ((nhalf*4*256) + ks*64 + lane)*8; \
    short8 bq0 = *(const short8*)(bp); \
    short8 bq1 = *(const short8*)(bp + 2048); \
    short8 bq2 = *(const short8*)(bp + 4096); \
    short8 bq3 = *(const short8*)(bp + 6144); \
    acc0 = __builtin_amdgcn_mfma_f32_16x16x32_bf16(a, bq0, acc0, 0, 0, 0); \
    acc1 = __builtin_amdgcn_mfma_f32_16x16x32_bf16(a, bq1, acc1, 0, 0, 0); \
    acc2 = __builtin_amdgcn_mfma_f32_16x16x32_bf16(a, bq2, acc2, 0, 0, 0); \
    acc3 = __builtin_amdgcn_mfma_f32_16x16x32_bf16(a, bq3, acc3, 0, 0, 0); \
  } \
  float z[4][4]; \
  _Pragma("unroll") \
  for (int nt = 0; nt < 4; ++nt){ \
    floatx4 a4 = (nt == 0) ? acc0 : (nt == 1) ? acc1 : (nt == 2) ? acc2 : acc3; \
    float bb = b2v[nhalf*64 + nt*16 + mcol]; \
    _Pragma("unroll") \
    for (int reg = 0; reg < 4; ++reg) z[nt][reg] = fmaxf(a4[reg] + bb, 0.f); \
  } \
  float ps[4], pq[4]; \
  _Pragma("unroll") \
  for (int reg = 0; reg < 4; ++reg){ \
    ps[reg] = z[0][reg] + z[1][reg] + z[2][reg] + z[3][reg]; \
    pq[reg] = z[0][reg]*z[0][reg] + z[1][reg]*z[1][reg] + z[2][reg]*z[2][reg] + z[3][reg]*z[3][reg]; \
  } \
  _Pragma("unroll") \
  for (int o = 1; o < 16; o <<= 1){ \
    _Pragma("unroll") \
    for (int reg = 0; reg < 4; ++reg){ \
      ps[reg] += __shfl_xor(ps[reg], o); \
      pq[reg] += __shfl_xor(pq[reg], o); \
    } \
  } \
  if (mcol == 0){ \
    _Pragma("unroll") \
    for (int reg = 0; reg < 4; ++reg){ \
      int row = mt*16 + quad*4 + reg; \
      sS[nhalf*32 + row] = ps[reg]; \
      sQ[nhalf*32 + row] = pq[reg]; \
    } \
  } \
  __syncthreads(); \
  int colv[4]; float lgv[4], lbv[4]; \
  _Pragma("unroll") \
  for (int nt = 0; nt < 4; ++nt){ \
    colv[nt] = nhalf*64 + nt*16 + mcol; \
    lgv[nt] = ln_g[colv[nt]]; \
    lbv[nt] = ln_b[colv[nt]]; \
  } \
  float muv[4], rvv[4]; \
  _Pragma("unroll") \
  for (int reg = 0; reg < 4; ++reg){ \
    int row = mt*16 + quad*4 + reg; \
    float s = sS[row] + sS[32 + row]; \
    float q = sQ[row] + sQ[32 + row]; \
    float mu = s * (1.f/FEAT); \
    float var = fmaxf(q * (1.f/FEAT) - mu*mu, 0.f); \
    muv[reg] = mu; \
    rvv[reg] = rsqrtf(var + EPSF); \
  }

__global__ __launch_bounds__(256) void k_edge(const unsigned short* __restrict__ PQb,
    const unsigned short* __restrict__ W2pack, const float* __restrict__ b1v,
    const float* __restrict__ b2v, const float* __restrict__ ln_g, const float* __restrict__ ln_b,
    const int* __restrict__ idxL, const int* __restrict__ idxR,
    float* __restrict__ agg){
  FB_CORE()
#pragma unroll
  for (int reg = 0; reg < 4; ++reg){
    int row = mt*16 + quad*4 + reg;
    int a = sTa[row];
#pragma unroll
    for (int nt = 0; nt < 4; ++nt){
      float o = scrub0(lgv[nt]*(z[nt][reg] - muv[reg])*rvv[reg] + lbv[nt]);
      atomicAdd(&agg[a*FEAT + colv[nt]], o);
    }
  }
}

__global__ __launch_bounds__(256) void k_stats(const float* __restrict__ src,
    const float* __restrict__ degrees, float* __restrict__ red){
  const int tid = threadIdx.x;
  const int j = tid & 127, half_sel = tid >> 7;
  const int n0 = blockIdx.x * 256;
  float s1 = 0.f, s2 = 0.f;
  for (int i = half_sel; i < 256; i += 2){
    int n = n0 + i;
    if (n < N_VARS){
      float v = src[n*FEAT + j] / degrees[n];
      s1 += v;
      s2 += v*v;
    }
  }
  __shared__ float sh1[256], sh2[256];
  sh1[tid] = s1; sh2[tid] = s2;
  __syncthreads();
  if (half_sel == 0){
    atomicAdd(&red[j],       sh1[tid] + sh1[tid+128]);
    atomicAdd(&red[128 + j], sh2[tid] + sh2[tid+128]);
  }
}

// ---- BN apply + logits + softmax + argmax; bf16 state out ----
__global__ __launch_bounds__(256) void k_bn(const float* __restrict__ src,
    const float* __restrict__ degrees, int divide, const float* __restrict__ red,
    const float* __restrict__ bn_g, const float* __restrict__ bn_b,
    const float* __restrict__ Wd, const float* __restrict__ bd,
    unsigned short* __restrict__ state_bf, int* __restrict__ asg,
    float* __restrict__ out_phi, float* __restrict__ out_asg, int t){
  const int w = threadIdx.x >> 6, l = threadIdx.x & 63;
  const int n = blockIdx.x*4 + w;
  const float invN = 1.f / (float)N_VARS;
  float mu0 = red[l]*invN,     mu1 = red[l+64]*invN;
  float v0  = fmaxf(red[128+l]*invN    - mu0*mu0, 0.f);
  float v1  = fmaxf(red[128+l+64]*invN - mu1*mu1, 0.f);
  float rv0 = rsqrtf(v0 + EPSF);
  float rv1 = rsqrtf(v1 + EPSF);
  float dinv = divide ? (1.f / degrees[n]) : 1.f;
  float r0 = src[n*FEAT + l]    * dinv;
  float r1 = src[n*FEAT + l+64] * dinv;
  float s0 = scrub0(bn_g[l]   *(r0 - mu0)*rv0 + bn_b[l]);
  float s1 = scrub0(bn_g[l+64]*(r1 - mu1)*rv1 + bn_b[l+64]);
  state_bf[n*FEAT + l]    = f2bf_rne(s0);
  state_bf[n*FEAT + l+64] = f2bf_rne(s1);
  float p[4];
#pragma unroll
  for (int d = 0; d < 4; ++d)
    p[d] = s0*Wd[l*4 + d] + s1*Wd[(l+64)*4 + d];
#pragma unroll
  for (int o = 32; o > 0; o >>= 1){
#pragma unroll
    for (int d = 0; d < 4; ++d) p[d] += __shfl_xor(p[d], o);
  }
  if (l == 0){
    float lg[4];
#pragma unroll
    for (int d = 0; d < 4; ++d) lg[d] = scrub0(p[d] + bd[d]);
    float mx = fmaxf(fmaxf(lg[0],lg[1]), fmaxf(lg[2],lg[3]));
    float ex[4]; float ssum = 0.f;
#pragma unroll
    for (int d = 0; d < 4; ++d){ ex[d] = expf(lg[d] - mx); ssum += ex[d]; }
    float inv = 1.f / ssum;
    int am = 0; float bv = -1.f;
#pragma unroll
    for (int d = 0; d < 4; ++d){
      float pv = scrub0(ex[d]*inv);
      out_phi[n*12 + t*4 + d] = pv;
      if (pv > bv){ bv = pv; am = d; }
    }
    asg[n*3 + t] = am;
    if (t == 2) out_asg[n] = (float)am;
  }
}

// ---- merged pair-losses + edge-conflicts (blocks >= NB_LOSS do conf) ----
__global__ __launch_bounds__(256) void k_lossconf(const float* __restrict__ phi,
    const int* __restrict__ iL, const int* __restrict__ iR,
    const int* __restrict__ iLp, const int* __restrict__ iRp,
    const float* __restrict__ rel, const float* __restrict__ conf,
    const int* __restrict__ asg, float* __restrict__ out_ec,
    float* __restrict__ part_l1, float* __restrict__ part_l2,
    float* __restrict__ part_conf){
  if (blockIdx.x < NB_LOSS){
    const int m = blockIdx.x*256 + threadIdx.x;
    float p1 = 0.f, p2 = 0.f;
    if (m < N_EDGES*3){
      int e = m/3, tt = m - e*3;
      const float* pl = phi + iL[e]*12 + tt*4;
      const float* pr = phi + iR[e]*12 + tt*4;
      float s = 0.f;
#pragma unroll
      for (int j = 0; j < 4; ++j){
        float tj = 0.f;
#pragma unroll
        for (int i = 0; i < 4; ++i) tj += pl[i]*rel[i*4+j];
        s += tj*pr[j];
      }
      s = scrub0(s); s = fmaxf(s, 1e-35f);
      p1 = -logf(s);
    } else {
      int m2 = m - N_EDGES*3;
      if (m2 < N_CONFP*3){
        int e = m2/3, tt = m2 - e*3;
        const float* pl = phi + iLp[e]*12 + tt*4;
        const float* pr = phi + iRp[e]*12 + tt*4;
        float s = 0.f;
#pragma unroll
        for (int j = 0; j < 4; ++j){
          float tj = 0.f;
#pragma unroll
          for (int i = 0; i < 4; ++i) tj += pl[i]*conf[i*4+j];
          s += tj*pr[j];
        }
        s = scrub0(s); s = fmaxf(s, 1e-35f);
        p2 = -logf(s);
      }
    }
    __shared__ float sh1[256], sh2[256];
    sh1[threadIdx.x] = p1; sh2[threadIdx.x] = p2;
    __syncthreads();
    for (int k = 128; k > 0; k >>= 1){
      if (threadIdx.x < k){
        sh1[threadIdx.x] += sh1[threadIdx.x + k];
        sh2[threadIdx.x] += sh2[threadIdx.x + k];
      }
      __syncthreads();
    }
    if (threadIdx.x == 0){
      part_l1[blockIdx.x] = sh1[0];
      part_l2[blockIdx.x] = sh2[0];
    }
  } else {
    const int bid = blockIdx.x - NB_LOSS;
    const int e = bid*256 + threadIdx.x;
    float c2 = 0.f;
    if (e < N_EDGES){
      int l = iL[e], r = iR[e];
#pragma unroll
      for (int tt = 0; tt < 3; ++tt){
        int ai = asg[l*3+tt] & 3, bi = asg[r*3+tt] & 3;
        float c = scrub0(1.f - rel[ai*4 + bi]);
        out_ec[e*3 + tt] = c;
        if (tt == 2) c2 = c;
      }
    }
    __shared__ float sh[256];
    sh[threadIdx.x] = c2;
    __syncthreads();
    for (int k = 128; k > 0; k >>= 1){
      if (threadIdx.x < k) sh[threadIdx.x] += sh[threadIdx.x + k];
      __syncthreads();
    }
    if (threadIdx.x == 0) part_conf[bid] = sh[0];
  }
}

// ---- final scalar reduce -> out[0], out[1], out[NCONF_SLOT] ----
__global__ __launch_bounds__(256) void k_fin(const float* __restrict__ part_conf,
    const float* __restrict__ part_l1, const float* __restrict__ part_l2,
    float* __restrict__ out){
  const int tid = threadIdx.x;
  float a = 0.f, ca = 0.f, b = 0.f, cb = 0.f, c = 0.f;
  for (int i = tid; i < NB_LOSS; i += 256){
    float y = part_l1[i] - ca; float t = a + y; ca = (t - a) - y; a = t;
    float y2 = part_l2[i] - cb; float t2 = b + y2; cb = (t2 - b) - y2; b = t2;
  }
  for (int i = tid; i < NB_CONF; i += 256) c += part_conf[i];
  __shared__ float sh1[256], sh2[256], sh3[256];
  sh1[tid] = a; sh2[tid] = b; sh3[tid] = c;
  __syncthreads();
  for (int k = 128; k > 0; k >>= 1){
    if (tid < k){
      sh1[tid] += sh1[tid + k];
      sh2[tid] += sh2[tid + k];
      sh3[tid] += sh3[tid + k];
    }
    __syncthreads();
  }
  if (tid == 0){
    out[0] = sh1[0]/(float)N_EDGES + sh2[0]/(10.f*(float)N_CONFP);
    float nc = sh3[0];
    out[NCONF_SLOT] = nc;
    out[1] = nc / (float)N_EDGES;
  }
}

extern "C" void kernel_launch(void* const* d_in, const int* in_sizes, int n_in,
                              void* d_out, int out_size, void* d_ws, size_t ws_size,
                              hipStream_t stream){
  const float* state0  = (const float*)d_in[0];
  const float* W1      = (const float*)d_in[1];
  const float* b1v     = (const float*)d_in[2];
  const float* W2      = (const float*)d_in[3];
  const float* b2v     = (const float*)d_in[4];
  const float* ln_g    = (const float*)d_in[5];
  const float* ln_b    = (const float*)d_in[6];
  const float* bn_g    = (const float*)d_in[7];
  const float* bn_b    = (const float*)d_in[8];
  const float* Wd      = (const float*)d_in[9];
  const float* bd      = (const float*)d_in[10];
  const float* rel     = (const float*)d_in[11];
  const float* confm   = (const float*)d_in[12];
  const float* degrees = (const float*)d_in[13];
  const int* idxL = (const int*)d_in[14];
  const int* idxR = (const int*)d_in[15];
  const int* iLp  = (const int*)d_in[16];
  const int* iRp  = (const int*)d_in[17];

  char* ws = (char*)d_ws;
  unsigned short* state_bf = (unsigned short*)(ws);          // 10,240,000
  unsigned short* PQb  = (unsigned short*)(ws + 10240000);   // 20,480,000
  float*  recagg    = (float*)(ws + 30720000);               // 20,480,000
  int*    asg       = (int*)  (ws + 51200000);               //    480,000
  float*  red       = (float*)(ws + 51840768);               //      1,024
  float*  part_l1   = (float*)(ws + 51841792);               //     14,068
  float*  part_l2   = (float*)(ws + 51855860);               //     14,068
  float*  part_conf = (float*)(ws + 51869928);               //      3,128
  unsigned short* W2pack = (unsigned short*)(ws + 51873056); //     32,768
  unsigned short* W1pack = (unsigned short*)(ws + 51905824); //     65,536
  int*    pos       = (int*)(ws + 51971360);                 //    160,000
  int*    cnt       = (int*)(ws + 52131360);                 //    160,000
  int*    mslot     = (int*)(ws + 52291360);                 //  1,600,000
  int*    blk_tot   = (int*)(ws + 53891360);                 //      1,024
  int*    blk_off   = (int*)(ws + 53892384);                 //      1,024
  unsigned short* msg = (unsigned short*)(ws + 53893408);    // 102,400,000
  const int use_csr = (ws_size >= (size_t)156451376) ? 1 : 0;

  float* out     = (float*)d_out;
  float* out_phi = out + 2;
  float* out_ec  = out + 480002;
  float* out_asg = out + 1080002;

  k_prep<<<8, 256, 0, stream>>>(W2, W2pack);
  k_prep_w1<<<16, 256, 0, stream>>>(W1, W1pack);

  if (use_csr){
    k_zero_int<<<NB_STAT, 256, 0, stream>>>(cnt, N_VARS);
    k_hist<<<(N_MSG + 255)/256, 256, 0, stream>>>(idxL, idxR, cnt);
    k_scan1<<<NB_STAT, 256, 0, stream>>>(cnt, pos, blk_tot);
    k_scan2<<<1, 256, 0, stream>>>(blk_tot, blk_off);
    k_scan3<<<NB_STAT, 256, 0, stream>>>(pos, blk_off);
    k_fill<<<(N_MSG + 255)/256, 256, 0, stream>>>(idxL, idxR, pos, mslot);
  }

  for (int t = 0; t < T_ITERS; ++t){
    k_pq<<<N_VARS/32, 256, 0, stream>>>(state0, state_bf, (t == 0) ? 1 : 0, W1pack, PQb, red);
    if (use_csr){
      k_msg<<<N_MSG/64, 256, 0, stream>>>(PQb, W2pack, b1v, b2v, ln_g, ln_b, idxL, idxR, mslot, msg);
      k_gather<<<NB_GATH, 256, 0, stream>>>(msg, pos, degrees, recagg, red);
      k_bn<<<N_VARS/4, 256, 0, stream>>>(recagg, degrees, 0, red, bn_g, bn_b, Wd, bd,
                                         state_bf, asg, out_phi, out_asg, t);
    } else {
      k_zero_agg<<<5000, 256, 0, stream>>>((float4*)recagg);
      k_edge<<<N_MSG/32, 256, 0, stream>>>(PQb, W2pack, b1v, b2v, ln_g, ln_b, idxL, idxR, recagg);
      k_stats<<<NB_STAT, 256, 0, stream>>>(recagg, degrees, red);
      k_bn<<<N_VARS/4, 256, 0, stream>>>(recagg, degrees, 1, red, bn_g, bn_b, Wd, bd,
                                         state_bf, asg, out_phi, out_asg, t);
    }
  }
  k_lossconf<<<NB_LOSS + NB_CONF, 256, 0, stream>>>(out_phi, idxL, idxR, iLp, iRp, rel, confm,
                                                    asg, out_ec, part_l1, part_l2, part_conf);
  k_fin<<<1, 256, 0, stream>>>(part_conf, part_l1, part_l2, out);
}

// Round 16
// 667.616 us; speedup vs baseline: 1.4490x; 1.0038x over previous
//
#include <hip/hip_runtime.h>
#include <math.h>

#define N_VARS 40000
#define FEAT 128
#define N_EDGES 200000
#define N_MSG (2*N_EDGES)
#define N_CONFP 100000
#define T_ITERS 3
#define EPSF 1e-5f

#define NB_CONF 782              // ceil(200000/256)
#define NB_LOSS 3517             // ceil(900000/256)
#define NB_STAT 157              // ceil(40000/256)
#define NB_GATH 2500             // 40000 / (4 waves * 4 nodes)
#define OUT_TOTAL 1120003
#define NCONF_SLOT 1120002       // sequential carve: 1+1+480000+600000+40000

typedef short short8 __attribute__((ext_vector_type(8)));
typedef float floatx4 __attribute__((ext_vector_type(4)));
typedef unsigned short ushort4v __attribute__((ext_vector_type(4)));

__device__ __forceinline__ float scrub0(float x){
  unsigned u = __float_as_uint(x);
  return ((u & 0x7F800000u) == 0x7F800000u) ? 0.f : x;
}
__device__ __forceinline__ unsigned short f2bf_rne(float x){
  unsigned u = __float_as_uint(x);
  u += 0x7FFFu + ((u >> 16) & 1u);
  return (unsigned short)(u >> 16);
}
__device__ __forceinline__ float bf2f(unsigned short h){
  return __uint_as_float(((unsigned)h) << 16);
}

__global__ __launch_bounds__(256) void k_zero_agg(float4* __restrict__ p){
  p[blockIdx.x*256 + threadIdx.x] = make_float4(0.f,0.f,0.f,0.f);
}
__global__ __launch_bounds__(256) void k_zero_int(int* __restrict__ p, int n){
  int i = blockIdx.x*256 + threadIdx.x;
  if (i < n) p[i] = 0;
}

// ---- CSR build over message ids m in [0,2E): target = m<E ? idxL[m] : idxR[m-E]
__global__ __launch_bounds__(256) void k_hist(const int* __restrict__ idxL,
    const int* __restrict__ idxR, int* __restrict__ cnt){
  int m = blockIdx.x*256 + threadIdx.x;
  if (m < N_MSG){
    int t = (m < N_EDGES) ? idxL[m] : idxR[m - N_EDGES];
    atomicAdd(&cnt[t], 1);
  }
}
__global__ __launch_bounds__(256) void k_scan1(const int* __restrict__ cnt,
    int* __restrict__ pos, int* __restrict__ blk_tot){
  const int tid = threadIdx.x;
  const int idx = blockIdx.x*256 + tid;
  int v = (idx < N_VARS) ? cnt[idx] : 0;
  __shared__ int sh[256];
  sh[tid] = v;
  __syncthreads();
#pragma unroll
  for (int o = 1; o < 256; o <<= 1){
    int add = (tid >= o) ? sh[tid - o] : 0;
    __syncthreads();
    sh[tid] += add;
    __syncthreads();
  }
  if (idx < N_VARS) pos[idx] = sh[tid] - v;
  if (tid == 255) blk_tot[blockIdx.x] = sh[255];
}
__global__ __launch_bounds__(256) void k_scan2(const int* __restrict__ blk_tot,
    int* __restrict__ blk_off){
  const int tid = threadIdx.x;
  int v = (tid < NB_STAT) ? blk_tot[tid] : 0;
  __shared__ int sh[256];
  sh[tid] = v;
  __syncthreads();
#pragma unroll
  for (int o = 1; o < 256; o <<= 1){
    int add = (tid >= o) ? sh[tid - o] : 0;
    __syncthreads();
    sh[tid] += add;
    __syncthreads();
  }
  if (tid < NB_STAT) blk_off[tid] = sh[tid] - v;
}
__global__ __launch_bounds__(256) void k_scan3(int* __restrict__ pos,
    const int* __restrict__ blk_off){
  const int idx = blockIdx.x*256 + threadIdx.x;
  if (idx < N_VARS) pos[idx] += blk_off[blockIdx.x];
}
__global__ __launch_bounds__(256) void k_fill(const int* __restrict__ idxL,
    const int* __restrict__ idxR, int* __restrict__ pos, int* __restrict__ mslot){
  int m = blockIdx.x*256 + threadIdx.x;
  if (m < N_MSG){
    int t = (m < N_EDGES) ? idxL[m] : idxR[m - N_EDGES];
    mslot[m] = atomicAdd(&pos[t], 1);
  }
}

// ---- pack W2 (128x128 f32) into B-fragment-ordered bf16 (8 ntiles) ----
__global__ __launch_bounds__(256) void k_prep(const float* __restrict__ W2,
                                              unsigned short* __restrict__ W2pack){
  int gid = blockIdx.x*256 + threadIdx.x;
  int lane = gid & 63;
  int ks = (gid >> 6) & 3;
  int ntg = gid >> 8;
  int kbase = ks*32 + (lane >> 4)*8;
  int n = ntg*16 + (lane & 15);
#pragma unroll
  for (int j = 0; j < 8; ++j)
    W2pack[gid*8 + j] = f2bf_rne(W2[(kbase + j)*FEAT + n]);
}
__global__ __launch_bounds__(256) void k_prep_w1(const float* __restrict__ W1,
                                                 unsigned short* __restrict__ W1pack){
  int gid = blockIdx.x*256 + threadIdx.x;
  int lane = gid & 63;
  int ks = (gid >> 6) & 3;
  int ntg = gid >> 8;
  int kbase = ks*32 + (lane >> 4)*8;
  int n = ntg*16 + (lane & 15);
#pragma unroll
  for (int j = 0; j < 8; ++j){
    int k = kbase + j;
    float v = (n < 128) ? W1[k*FEAT + n] : W1[(128 + k)*FEAT + (n - 128)];
    W1pack[gid*8 + j] = f2bf_rne(v);
  }
}

// ---- PQ = x @ [W1top | W1bot] via MFMA bf16 -> bf16 store; also zeroes red ----
#define X_STRIDE 136
__global__ __launch_bounds__(256) void k_pq(const float* __restrict__ xf,
                                            const unsigned short* __restrict__ xb,
                                            int src_f32,
                                            const unsigned short* __restrict__ W1pack,
                                            unsigned short* __restrict__ PQb,
                                            float* __restrict__ red){
  __shared__ __align__(16) unsigned short Xbf[32*X_STRIDE];
  const int tid = threadIdx.x;
  const int row0 = blockIdx.x * 32;
  if (blockIdx.x == 0) red[tid] = 0.f;
  if (src_f32){
    const int c4 = (tid & 31)*4, g8 = tid >> 5;
#pragma unroll
    for (int r = 0; r < 4; ++r){
      int row = g8*4 + r;
      const float4 v = *(const float4*)&xf[(row0 + row)*FEAT + c4];
      ushort4v u;
      u.x = f2bf_rne(v.x); u.y = f2bf_rne(v.y);
      u.z = f2bf_rne(v.z); u.w = f2bf_rne(v.w);
      *(ushort4v*)&Xbf[row*X_STRIDE + c4] = u;
    }
  } else {
    const int c8 = (tid & 15)*8, g16 = tid >> 4;
#pragma unroll
    for (int r = 0; r < 2; ++r){
      int row = r*16 + g16;
      *(short8*)&Xbf[row*X_STRIDE + c8] = *(const short8*)&xb[(row0 + row)*FEAT + c8];
    }
  }
  __syncthreads();
  const int w = tid >> 6, lane = tid & 63;
  const int quad = lane >> 4, mcol = lane & 15;
#pragma unroll
  for (int mt = 0; mt < 2; ++mt){
    floatx4 a0 = {0.f,0.f,0.f,0.f};
    floatx4 a1 = {0.f,0.f,0.f,0.f};
    floatx4 a2 = {0.f,0.f,0.f,0.f};
    floatx4 a3 = {0.f,0.f,0.f,0.f};
#pragma unroll
    for (int ks = 0; ks < 4; ++ks){
      short8 a = *(const short8*)&Xbf[(mt*16 + mcol)*X_STRIDE + ks*32 + quad*8];
      const unsigned short* bp = W1pack + ((w*16 + ks)*64 + lane)*8;
      short8 b0 = *(const short8*)(bp);
      short8 b1 = *(const short8*)(bp + 2048);
      short8 b2 = *(const short8*)(bp + 4096);
      short8 b3 = *(const short8*)(bp + 6144);
      a0 = __builtin_amdgcn_mfma_f32_16x16x32_bf16(a, b0, a0, 0, 0, 0);
      a1 = __builtin_amdgcn_mfma_f32_16x16x32_bf16(a, b1, a1, 0, 0, 0);
      a2 = __builtin_amdgcn_mfma_f32_16x16x32_bf16(a, b2, a2, 0, 0, 0);
      a3 = __builtin_amdgcn_mfma_f32_16x16x32_bf16(a, b3, a3, 0, 0, 0);
    }
#pragma unroll
    for (int nt = 0; nt < 4; ++nt){
      floatx4 acc = (nt == 0) ? a0 : (nt == 1) ? a1 : (nt == 2) ? a2 : a3;
      int n = w*64 + nt*16 + mcol;
#pragma unroll
      for (int reg = 0; reg < 4; ++reg)
        PQb[(row0 + mt*16 + quad*4 + reg)*(2*FEAT) + n] = f2bf_rne(acc[reg]);
    }
  }
}

#define U_STRIDE 136   // bf16 elems

// ---- CSR phase 1: 64 msgs/block; each wave owns 16 complete rows ----
__global__ __launch_bounds__(256) void k_msg(const unsigned short* __restrict__ PQb,
    const unsigned short* __restrict__ W2pack, const float* __restrict__ b1v,
    const float* __restrict__ b2v, const float* __restrict__ ln_g, const float* __restrict__ ln_b,
    const int* __restrict__ idxL, const int* __restrict__ idxR,
    const int* __restrict__ mslot, unsigned short* __restrict__ msg){
  __shared__ __align__(16) unsigned short Ubf[64*U_STRIDE];
  __shared__ int sTa[64], sTb[64];
  const int tid = threadIdx.x;
  const int m0 = blockIdx.x * 64;
  if (tid < 64){
    int m = m0 + tid;
    int e = (m < N_EDGES) ? m : (m - N_EDGES);
    int l = idxL[e], r = idxR[e];
    sTa[tid] = (m < N_EDGES) ? l : r;
    sTb[tid] = (m < N_EDGES) ? r : l;
  }
  __syncthreads();
  {
    const int c8 = (tid & 15)*8, g16 = tid >> 4;
    const float4 b1a = *(const float4*)&b1v[c8];
    const float4 b1b = *(const float4*)&b1v[c8 + 4];
    short8 pb[4], qb[4];
#pragma unroll
    for (int r = 0; r < 4; ++r){
      int row = r*16 + g16;
      pb[r] = *(const short8*)&PQb[sTb[row]*(2*FEAT) + c8];
      qb[r] = *(const short8*)&PQb[sTa[row]*(2*FEAT) + FEAT + c8];
    }
#pragma unroll
    for (int r = 0; r < 4; ++r){
      int row = r*16 + g16;
      ushort4v u0, u1;
      u0.x = f2bf_rne(fmaxf(bf2f(pb[r][0]) + bf2f(qb[r][0]) + b1a.x, 0.f));
      u0.y = f2bf_rne(fmaxf(bf2f(pb[r][1]) + bf2f(qb[r][1]) + b1a.y, 0.f));
      u0.z = f2bf_rne(fmaxf(bf2f(pb[r][2]) + bf2f(qb[r][2]) + b1a.z, 0.f));
      u0.w = f2bf_rne(fmaxf(bf2f(pb[r][3]) + bf2f(qb[r][3]) + b1a.w, 0.f));
      u1.x = f2bf_rne(fmaxf(bf2f(pb[r][4]) + bf2f(qb[r][4]) + b1b.x, 0.f));
      u1.y = f2bf_rne(fmaxf(bf2f(pb[r][5]) + bf2f(qb[r][5]) + b1b.y, 0.f));
      u1.z = f2bf_rne(fmaxf(bf2f(pb[r][6]) + bf2f(qb[r][6]) + b1b.z, 0.f));
      u1.w = f2bf_rne(fmaxf(bf2f(pb[r][7]) + bf2f(qb[r][7]) + b1b.w, 0.f));
      *(ushort4v*)&Ubf[row*U_STRIDE + c8]     = u0;
      *(ushort4v*)&Ubf[row*U_STRIDE + c8 + 4] = u1;
    }
  }
  __syncthreads();
  const int w = tid >> 6, lane = tid & 63;
  const int quad = lane >> 4, mcol = lane & 15;
  const int rbase = w*16;
  floatx4 acc[8];
#pragma unroll
  for (int nt = 0; nt < 8; ++nt) acc[nt] = (floatx4){0.f,0.f,0.f,0.f};
#pragma unroll
  for (int ks = 0; ks < 4; ++ks){
    short8 a = *(const short8*)&Ubf[(rbase + mcol)*U_STRIDE + ks*32 + quad*8];
#pragma unroll
    for (int nt = 0; nt < 8; ++nt){
      short8 b = *(const short8*)(W2pack + ((nt*4 + ks)*64 + lane)*8);
      acc[nt] = __builtin_amdgcn_mfma_f32_16x16x32_bf16(a, b, acc[nt], 0, 0, 0);
    }
  }
  float z[8][4];
#pragma unroll
  for (int nt = 0; nt < 8; ++nt){
    float bb = b2v[nt*16 + mcol];
#pragma unroll
    for (int reg = 0; reg < 4; ++reg) z[nt][reg] = fmaxf(acc[nt][reg] + bb, 0.f);
  }
  float ps[4], pq[4];
#pragma unroll
  for (int reg = 0; reg < 4; ++reg){
    ps[reg] = 0.f; pq[reg] = 0.f;
#pragma unroll
    for (int nt = 0; nt < 8; ++nt){
      ps[reg] += z[nt][reg];
      pq[reg] += z[nt][reg]*z[nt][reg];
    }
  }
#pragma unroll
  for (int o = 1; o < 16; o <<= 1){
#pragma unroll
    for (int reg = 0; reg < 4; ++reg){
      ps[reg] += __shfl_xor(ps[reg], o);
      pq[reg] += __shfl_xor(pq[reg], o);
    }
  }
  float lgv[8], lbv[8];
#pragma unroll
  for (int nt = 0; nt < 8; ++nt){
    lgv[nt] = ln_g[nt*16 + mcol];
    lbv[nt] = ln_b[nt*16 + mcol];
  }
#pragma unroll
  for (int reg = 0; reg < 4; ++reg){
    int row = rbase + quad*4 + reg;
    float mu = ps[reg] * (1.f/FEAT);
    float var = fmaxf(pq[reg] * (1.f/FEAT) - mu*mu, 0.f);
    float rv = rsqrtf(var + EPSF);
    size_t base = (size_t)mslot[m0 + row]*FEAT;
#pragma unroll
    for (int nt = 0; nt < 8; ++nt){
      float o = scrub0(lgv[nt]*(z[nt][reg] - mu)*rv + lbv[nt]);
      msg[base + nt*16 + mcol] = f2bf_rne(o);
    }
  }
}

// ---- CSR phase 2: one wave per 4 nodes; 4 interleaved span streams (MLP=4) ----
__global__ __launch_bounds__(256) void k_gather(const unsigned short* __restrict__ msg,
    const int* __restrict__ pos, const float* __restrict__ degrees,
    float* __restrict__ rec, float* __restrict__ red){
  const int wv = threadIdx.x >> 6, lane = threadIdx.x & 63;
  const int srow = lane >> 4, jg = lane & 15;
  const int gw = blockIdx.x*4 + wv;     // 0..9999
  const int nb = gw*4;
  int a1[4], s[4];
  int prev = (nb == 0) ? 0 : pos[nb-1];
#pragma unroll
  for (int i = 0; i < 4; ++i){
    a1[i] = pos[nb + i];
    s[i] = prev + srow;
    prev = a1[i];
  }
  float acc[4][8];
#pragma unroll
  for (int i = 0; i < 4; ++i)
#pragma unroll
    for (int k = 0; k < 8; ++k) acc[i][k] = 0.f;
  // lock-step rounds: issue 4 independent loads, then consume
  while ((s[0] < a1[0]) | (s[1] < a1[1]) | (s[2] < a1[2]) | (s[3] < a1[3])){
    short8 row[4];
    bool act[4];
#pragma unroll
    for (int i = 0; i < 4; ++i){
      act[i] = (s[i] < a1[i]);
      if (act[i]) row[i] = *(const short8*)&msg[(size_t)s[i]*FEAT + jg*8];
    }
#pragma unroll
    for (int i = 0; i < 4; ++i){
      if (act[i]){
#pragma unroll
        for (int k = 0; k < 8; ++k) acc[i][k] += bf2f((unsigned short)row[i][k]);
        s[i] += 4;
      }
    }
  }
  float s1[8], s2[8];
#pragma unroll
  for (int k = 0; k < 8; ++k){ s1[k] = 0.f; s2[k] = 0.f; }
#pragma unroll
  for (int i = 0; i < 4; ++i){
#pragma unroll
    for (int k = 0; k < 8; ++k){
      acc[i][k] += __shfl_xor(acc[i][k], 16);
      acc[i][k] += __shfl_xor(acc[i][k], 32);
    }
    if (srow == 0){
      int n = nb + i;
      float dinv = 1.f / degrees[n];
      float4 v0, v1;
      v0.x = acc[i][0]*dinv; v0.y = acc[i][1]*dinv; v0.z = acc[i][2]*dinv; v0.w = acc[i][3]*dinv;
      v1.x = acc[i][4]*dinv; v1.y = acc[i][5]*dinv; v1.z = acc[i][6]*dinv; v1.w = acc[i][7]*dinv;
      *(float4*)&rec[n*FEAT + jg*8]     = v0;
      *(float4*)&rec[n*FEAT + jg*8 + 4] = v1;
      s1[0] += v0.x; s2[0] += v0.x*v0.x;
      s1[1] += v0.y; s2[1] += v0.y*v0.y;
      s1[2] += v0.z; s2[2] += v0.z*v0.z;
      s1[3] += v0.w; s2[3] += v0.w*v0.w;
      s1[4] += v1.x; s2[4] += v1.x*v1.x;
      s1[5] += v1.y; s2[5] += v1.y*v1.y;
      s1[6] += v1.z; s2[6] += v1.z*v1.z;
      s1[7] += v1.w; s2[7] += v1.w*v1.w;
    }
  }
  __shared__ float shs[4][128], shq[4][128];
  if (srow == 0){
#pragma unroll
    for (int k = 0; k < 8; ++k){
      shs[wv][jg*8 + k] = s1[k];
      shq[wv][jg*8 + k] = s2[k];
    }
  }
  __syncthreads();
  if (threadIdx.x < 128){
    int j = threadIdx.x;
    atomicAdd(&red[j],       shs[0][j] + shs[1][j] + shs[2][j] + shs[3][j]);
    atomicAdd(&red[128 + j], shq[0][j] + shq[1][j] + shq[2][j] + shq[3][j]);
  }
}

// ================= fallback path (no CSR) =================
__global__ __launch_bounds__(256) void k_edge(const unsigned short* __restrict__ PQb,
    const unsigned short* __restrict__ W2pack, const float* __restrict__ b1v,
    const float* __restrict__ b2v, const float* __restrict__ ln_g, const float* __restrict__ ln_b,
    const int* __restrict__ idxL, const int* __restrict__ idxR,
    float* __restrict__ agg){
  __shared__ __align__(16) unsigned short Ubf[32*U_STRIDE];
  __shared__ float sS[64], sQ[64];
  __shared__ int sTa[32], sTb[32];
  const int tid = threadIdx.x;
  const int m0 = blockIdx.x * 32;
  if (tid < 32){
    int m = m0 + tid;
    int e = (m < N_EDGES) ? m : (m - N_EDGES);
    int l = idxL[e], r = idxR[e];
    sTa[tid] = (m < N_EDGES) ? l : r;
    sTb[tid] = (m < N_EDGES) ? r : l;
  }
  __syncthreads();
  {
    const int c8 = (tid & 15)*8, g16 = tid >> 4;
    const float4 b1a = *(const float4*)&b1v[c8];
    const float4 b1b = *(const float4*)&b1v[c8 + 4];
#pragma unroll
    for (int r = 0; r < 2; ++r){
      int row = r*16 + g16;
      short8 pb = *(const short8*)&PQb[sTb[row]*(2*FEAT) + c8];
      short8 qb = *(const short8*)&PQb[sTa[row]*(2*FEAT) + FEAT + c8];
      ushort4v u0, u1;
      u0.x = f2bf_rne(fmaxf(bf2f(pb[0]) + bf2f(qb[0]) + b1a.x, 0.f));
      u0.y = f2bf_rne(fmaxf(bf2f(pb[1]) + bf2f(qb[1]) + b1a.y, 0.f));
      u0.z = f2bf_rne(fmaxf(bf2f(pb[2]) + bf2f(qb[2]) + b1a.z, 0.f));
      u0.w = f2bf_rne(fmaxf(bf2f(pb[3]) + bf2f(qb[3]) + b1a.w, 0.f));
      u1.x = f2bf_rne(fmaxf(bf2f(pb[4]) + bf2f(qb[4]) + b1b.x, 0.f));
      u1.y = f2bf_rne(fmaxf(bf2f(pb[5]) + bf2f(qb[5]) + b1b.y, 0.f));
      u1.z = f2bf_rne(fmaxf(bf2f(pb[6]) + bf2f(qb[6]) + b1b.z, 0.f));
      u1.w = f2bf_rne(fmaxf(bf2f(pb[7]) + bf2f(qb[7]) + b1b.w, 0.f));
      *(ushort4v*)&Ubf[row*U_STRIDE + c8]     = u0;
      *(ushort4v*)&Ubf[row*U_STRIDE + c8 + 4] = u1;
    }
  }
  __syncthreads();
  const int w = tid >> 6, lane = tid & 63;
  const int mt = w & 1, nhalf = w >> 1;
  const int quad = lane >> 4, mcol = lane & 15;
  floatx4 acc0 = {0.f,0.f,0.f,0.f};
  floatx4 acc1 = {0.f,0.f,0.f,0.f};
  floatx4 acc2 = {0.f,0.f,0.f,0.f};
  floatx4 acc3 = {0.f,0.f,0.f,0.f};
#pragma unroll
  for (int ks = 0; ks < 4; ++ks){
    short8 a = *(const short8*)&Ubf[(mt*16 + mcol)*U_STRIDE + ks*32 + quad*8];
    const unsigned short* bp = W2pack + ((nhalf*4*256) + ks*64 + lane)*8;
    short8 bq0 = *(const short8*)(bp);
    short8 bq1 = *(const short8*)(bp + 2048);
    short8 bq2 = *(const short8*)(bp + 4096);
    short8 bq3 = *(const short8*)(bp + 6144);
    acc0 = __builtin_amdgcn_mfma_f32_16x16x32_bf16(a, bq0, acc0, 0, 0, 0);
    acc1 = __builtin_amdgcn_mfma_f32_16x16x32_bf16(a, bq1, acc1, 0, 0, 0);
    acc2 = __builtin_amdgcn_mfma_f32_16x16x32_bf16(a, bq2, acc2, 0, 0, 0);
    acc3 = __builtin_amdgcn_mfma_f32_16x16x32_bf16(a, bq3, acc3, 0, 0, 0);
  }
  float z[4][4];
#pragma unroll
  for (int nt = 0; nt < 4; ++nt){
    floatx4 a4 = (nt == 0) ? acc0 : (nt == 1) ? acc1 : (nt == 2) ? acc2 : acc3;
    float bb = b2v[nhalf*64 + nt*16 + mcol];
#pragma unroll
    for (int reg = 0; reg < 4; ++reg) z[nt][reg] = fmaxf(a4[reg] + bb, 0.f);
  }
  float ps[4], pq[4];
#pragma unroll
  for (int reg = 0; reg < 4; ++reg){
    ps[reg] = z[0][reg] + z[1][reg] + z[2][reg] + z[3][reg];
    pq[reg] = z[0][reg]*z[0][reg] + z[1][reg]*z[1][reg] + z[2][reg]*z[2][reg] + z[3][reg]*z[3][reg];
  }
#pragma unroll
  for (int o = 1; o < 16; o <<= 1){
#pragma unroll
    for (int reg = 0; reg < 4; ++reg){
      ps[reg] += __shfl_xor(ps[reg], o);
      pq[reg] += __shfl_xor(pq[reg], o);
    }
  }
  if (mcol == 0){
#pragma unroll
    for (int reg = 0; reg < 4; ++reg){
      int row = mt*16 + quad*4 + reg;
      sS[nhalf*32 + row] = ps[reg];
      sQ[nhalf*32 + row] = pq[reg];
    }
  }
  __syncthreads();
  int colv[4]; float lgv[4], lbv[4];
#pragma unroll
  for (int nt = 0; nt < 4; ++nt){
    colv[nt] = nhalf*64 + nt*16 + mcol;
    lgv[nt] = ln_g[colv[nt]];
    lbv[nt] = ln_b[colv[nt]];
  }
#pragma unroll
  for (int reg = 0; reg < 4; ++reg){
    int row = mt*16 + quad*4 + reg;
    float s = sS[row] + sS[32 + row];
    float q = sQ[row] + sQ[32 + row];
    float mu = s * (1.f/FEAT);
    float var = fmaxf(q * (1.f/FEAT) - mu*mu, 0.f);
    float rv = rsqrtf(var + EPSF);
    int a = sTa[row];
#pragma unroll
    for (int nt = 0; nt < 4; ++nt){
      float o = scrub0(lgv[nt]*(z[nt][reg] - mu)*rv + lbv[nt]);
      atomicAdd(&agg[a*FEAT + colv[nt]], o);
    }
  }
}

__global__ __launch_bounds__(256) void k_stats(const float* __restrict__ src,
    const float* __restrict__ degrees, float* __restrict__ red){
  const int tid = threadIdx.x;
  const int j = tid & 127, half_sel = tid >> 7;
  const int n0 = blockIdx.x * 256;
  float s1 = 0.f, s2 = 0.f;
  for (int i = half_sel; i < 256; i += 2){
    int n = n0 + i;
    if (n < N_VARS){
      float v = src[n*FEAT + j] / degrees[n];
      s1 += v;
      s2 += v*v;
    }
  }
  __shared__ float sh1[256], sh2[256];
  sh1[tid] = s1; sh2[tid] = s2;
  __syncthreads();
  if (half_sel == 0){
    atomicAdd(&red[j],       sh1[tid] + sh1[tid+128]);
    atomicAdd(&red[128 + j], sh2[tid] + sh2[tid+128]);
  }
}

// ---- BN apply + logits + softmax + argmax; bf16 state out ----
__global__ __launch_bounds__(256) void k_bn(const float* __restrict__ src,
    const float* __restrict__ degrees, int divide, const float* __restrict__ red,
    const float* __restrict__ bn_g, const float* __restrict__ bn_b,
    const float* __restrict__ Wd, const float* __restrict__ bd,
    unsigned short* __restrict__ state_bf, int* __restrict__ asg,
    float* __restrict__ out_phi, float* __restrict__ out_asg, int t){
  const int w = threadIdx.x >> 6, l = threadIdx.x & 63;
  const int n = blockIdx.x*4 + w;
  const float invN = 1.f / (float)N_VARS;
  float mu0 = red[l]*invN,     mu1 = red[l+64]*invN;
  float v0  = fmaxf(red[128+l]*invN    - mu0*mu0, 0.f);
  float v1  = fmaxf(red[128+l+64]*invN - mu1*mu1, 0.f);
  float rv0 = rsqrtf(v0 + EPSF);
  float rv1 = rsqrtf(v1 + EPSF);
  float dinv = divide ? (1.f / degrees[n]) : 1.f;
  float r0 = src[n*FEAT + l]    * dinv;
  float r1 = src[n*FEAT + l+64] * dinv;
  float s0 = scrub0(bn_g[l]   *(r0 - mu0)*rv0 + bn_b[l]);
  float s1 = scrub0(bn_g[l+64]*(r1 - mu1)*rv1 + bn_b[l+64]);
  state_bf[n*FEAT + l]    = f2bf_rne(s0);
  state_bf[n*FEAT + l+64] = f2bf_rne(s1);
  float p[4];
#pragma unroll
  for (int d = 0; d < 4; ++d)
    p[d] = s0*Wd[l*4 + d] + s1*Wd[(l+64)*4 + d];
#pragma unroll
  for (int o = 32; o > 0; o >>= 1){
#pragma unroll
    for (int d = 0; d < 4; ++d) p[d] += __shfl_xor(p[d], o);
  }
  if (l == 0){
    float lg[4];
#pragma unroll
    for (int d = 0; d < 4; ++d) lg[d] = scrub0(p[d] + bd[d]);
    float mx = fmaxf(fmaxf(lg[0],lg[1]), fmaxf(lg[2],lg[3]));
    float ex[4]; float ssum = 0.f;
#pragma unroll
    for (int d = 0; d < 4; ++d){ ex[d] = expf(lg[d] - mx); ssum += ex[d]; }
    float inv = 1.f / ssum;
    int am = 0; float bv = -1.f;
#pragma unroll
    for (int d = 0; d < 4; ++d){
      float pv = scrub0(ex[d]*inv);
      out_phi[n*12 + t*4 + d] = pv;
      if (pv > bv){ bv = pv; am = d; }
    }
    asg[n*3 + t] = am;
    if (t == 2) out_asg[n] = (float)am;
  }
}

// ---- merged pair-losses + edge-conflicts (blocks >= NB_LOSS do conf) ----
__global__ __launch_bounds__(256) void k_lossconf(const float* __restrict__ phi,
    const int* __restrict__ iL, const int* __restrict__ iR,
    const int* __restrict__ iLp, const int* __restrict__ iRp,
    const float* __restrict__ rel, const float* __restrict__ conf,
    const int* __restrict__ asg, float* __restrict__ out_ec,
    float* __restrict__ part_l1, float* __restrict__ part_l2,
    float* __restrict__ part_conf){
  if (blockIdx.x < NB_LOSS){
    const int m = blockIdx.x*256 + threadIdx.x;
    float p1 = 0.f, p2 = 0.f;
    if (m < N_EDGES*3){
      int e = m/3, tt = m - e*3;
      const float* pl = phi + iL[e]*12 + tt*4;
      const float* pr = phi + iR[e]*12 + tt*4;
      float s = 0.f;
#pragma unroll
      for (int j = 0; j < 4; ++j){
        float tj = 0.f;
#pragma unroll
        for (int i = 0; i < 4; ++i) tj += pl[i]*rel[i*4+j];
        s += tj*pr[j];
      }
      s = scrub0(s); s = fmaxf(s, 1e-35f);
      p1 = -logf(s);
    } else {
      int m2 = m - N_EDGES*3;
      if (m2 < N_CONFP*3){
        int e = m2/3, tt = m2 - e*3;
        const float* pl = phi + iLp[e]*12 + tt*4;
        const float* pr = phi + iRp[e]*12 + tt*4;
        float s = 0.f;
#pragma unroll
        for (int j = 0; j < 4; ++j){
          float tj = 0.f;
#pragma unroll
          for (int i = 0; i < 4; ++i) tj += pl[i]*conf[i*4+j];
          s += tj*pr[j];
        }
        s = scrub0(s); s = fmaxf(s, 1e-35f);
        p2 = -logf(s);
      }
    }
    __shared__ float sh1[256], sh2[256];
    sh1[threadIdx.x] = p1; sh2[threadIdx.x] = p2;
    __syncthreads();
    for (int k = 128; k > 0; k >>= 1){
      if (threadIdx.x < k){
        sh1[threadIdx.x] += sh1[threadIdx.x + k];
        sh2[threadIdx.x] += sh2[threadIdx.x + k];
      }
      __syncthreads();
    }
    if (threadIdx.x == 0){
      part_l1[blockIdx.x] = sh1[0];
      part_l2[blockIdx.x] = sh2[0];
    }
  } else {
    const int bid = blockIdx.x - NB_LOSS;
    const int e = bid*256 + threadIdx.x;
    float c2 = 0.f;
    if (e < N_EDGES){
      int l = iL[e], r = iR[e];
#pragma unroll
      for (int tt = 0; tt < 3; ++tt){
        int ai = asg[l*3+tt] & 3, bi = asg[r*3+tt] & 3;
        float c = scrub0(1.f - rel[ai*4 + bi]);
        out_ec[e*3 + tt] = c;
        if (tt == 2) c2 = c;
      }
    }
    __shared__ float sh[256];
    sh[threadIdx.x] = c2;
    __syncthreads();
    for (int k = 128; k > 0; k >>= 1){
      if (threadIdx.x < k) sh[threadIdx.x] += sh[threadIdx.x + k];
      __syncthreads();
    }
    if (threadIdx.x == 0) part_conf[bid] = sh[0];
  }
}

// ---- final scalar reduce -> out[0], out[1], out[NCONF_SLOT] ----
__global__ __launch_bounds__(256) void k_fin(const float* __restrict__ part_conf,
    const float* __restrict__ part_l1, const float* __restrict__ part_l2,
    float* __restrict__ out){
  const int tid = threadIdx.x;
  float a = 0.f, ca = 0.f, b = 0.f, cb = 0.f, c = 0.f;
  for (int i = tid; i < NB_LOSS; i += 256){
    float y = part_l1[i] - ca; float t = a + y; ca = (t - a) - y; a = t;
    float y2 = part_l2[i] - cb; float t2 = b + y2; cb = (t2 - b) - y2; b = t2;
  }
  for (int i = tid; i < NB_CONF; i += 256) c += part_conf[i];
  __shared__ float sh1[256], sh2[256], sh3[256];
  sh1[tid] = a; sh2[tid] = b; sh3[tid] = c;
  __syncthreads();
  for (int k = 128; k > 0; k >>= 1){
    if (tid < k){
      sh1[tid] += sh1[tid + k];
      sh2[tid] += sh2[tid + k];
      sh3[tid] += sh3[tid + k];
    }
    __syncthreads();
  }
  if (tid == 0){
    out[0] = sh1[0]/(float)N_EDGES + sh2[0]/(10.f*(float)N_CONFP);
    float nc = sh3[0];
    out[NCONF_SLOT] = nc;
    out[1] = nc / (float)N_EDGES;
  }
}

extern "C" void kernel_launch(void* const* d_in, const int* in_sizes, int n_in,
                              void* d_out, int out_size, void* d_ws, size_t ws_size,
                              hipStream_t stream){
  const float* state0  = (const float*)d_in[0];
  const float* W1      = (const float*)d_in[1];
  const float* b1v     = (const float*)d_in[2];
  const float* W2      = (const float*)d_in[3];
  const float* b2v     = (const float*)d_in[4];
  const float* ln_g    = (const float*)d_in[5];
  const float* ln_b    = (const float*)d_in[6];
  const float* bn_g    = (const float*)d_in[7];
  const float* bn_b    = (const float*)d_in[8];
  const float* Wd      = (const float*)d_in[9];
  const float* bd      = (const float*)d_in[10];
  const float* rel     = (const float*)d_in[11];
  const float* confm   = (const float*)d_in[12];
  const float* degrees = (const float*)d_in[13];
  const int* idxL = (const int*)d_in[14];
  const int* idxR = (const int*)d_in[15];
  const int* iLp  = (const int*)d_in[16];
  const int* iRp  = (const int*)d_in[17];

  char* ws = (char*)d_ws;
  unsigned short* state_bf = (unsigned short*)(ws);          // 10,240,000
  unsigned short* PQb  = (unsigned short*)(ws + 10240000);   // 20,480,000
  float*  recagg    = (float*)(ws + 30720000);               // 20,480,000
  int*    asg       = (int*)  (ws + 51200000);               //    480,000
  float*  red       = (float*)(ws + 51840768);               //      1,024
  float*  part_l1   = (float*)(ws + 51841792);               //     14,068
  float*  part_l2   = (float*)(ws + 51855860);               //     14,068
  float*  part_conf = (float*)(ws + 51869928);               //      3,128
  unsigned short* W2pack = (unsigned short*)(ws + 51873056); //     32,768
  unsigned short* W1pack = (unsigned short*)(ws + 51905824); //     65,536
  int*    pos       = (int*)(ws + 51971360);                 //    160,000
  int*    cnt       = (int*)(ws + 52131360);                 //    160,000
  int*    mslot     = (int*)(ws + 52291360);                 //  1,600,000
  int*    blk_tot   = (int*)(ws + 53891360);                 //      1,024
  int*    blk_off   = (int*)(ws + 53892384);                 //      1,024
  unsigned short* msg = (unsigned short*)(ws + 53893408);    // 102,400,000
  const int use_csr = (ws_size >= (size_t)156451376) ? 1 : 0;

  float* out     = (float*)d_out;
  float* out_phi = out + 2;
  float* out_ec  = out + 480002;
  float* out_asg = out + 1080002;

  k_prep<<<8, 256, 0, stream>>>(W2, W2pack);
  k_prep_w1<<<16, 256, 0, stream>>>(W1, W1pack);

  if (use_csr){
    k_zero_int<<<NB_STAT, 256, 0, stream>>>(cnt, N_VARS);
    k_hist<<<(N_MSG + 255)/256, 256, 0, stream>>>(idxL, idxR, cnt);
    k_scan1<<<NB_STAT, 256, 0, stream>>>(cnt, pos, blk_tot);
    k_scan2<<<1, 256, 0, stream>>>(blk_tot, blk_off);
    k_scan3<<<NB_STAT, 256, 0, stream>>>(pos, blk_off);
    k_fill<<<(N_MSG + 255)/256, 256, 0, stream>>>(idxL, idxR, pos, mslot);
  }

  for (int t = 0; t < T_ITERS; ++t){
    k_pq<<<N_VARS/32, 256, 0, stream>>>(state0, state_bf, (t == 0) ? 1 : 0, W1pack, PQb, red);
    if (use_csr){
      k_msg<<<N_MSG/64, 256, 0, stream>>>(PQb, W2pack, b1v, b2v, ln_g, ln_b, idxL, idxR, mslot, msg);
      k_gather<<<NB_GATH, 256, 0, stream>>>(msg, pos, degrees, recagg, red);
      k_bn<<<N_VARS/4, 256, 0, stream>>>(recagg, degrees, 0, red, bn_g, bn_b, Wd, bd,
                                         state_bf, asg, out_phi, out_asg, t);
    } else {
      k_zero_agg<<<5000, 256, 0, stream>>>((float4*)recagg);
      k_edge<<<N_MSG/32, 256, 0, stream>>>(PQb, W2pack, b1v, b2v, ln_g, ln_b, idxL, idxR, recagg);
      k_stats<<<NB_STAT, 256, 0, stream>>>(recagg, degrees, red);
      k_bn<<<N_VARS/4, 256, 0, stream>>>(recagg, degrees, 1, red, bn_g, bn_b, Wd, bd,
                                         state_bf, asg, out_phi, out_asg, t);
    }
  }
  k_lossconf<<<NB_LOSS + NB_CONF, 256, 0, stream>>>(out_phi, idxL, idxR, iLp, iRp, rel, confm,
                                                    asg, out_ec, part_l1, part_l2, part_conf);
  k_fin<<<1, 256, 0, stream>>>(part_conf, part_l1, part_l2, out);
}